// Round 5
// baseline (994.929 us; speedup 1.0000x reference)
//
#include <hip/hip_runtime.h>

#define R_ 3
#define T_ 3
#define N_ 50000
#define OPS_ 24
#define E_ 400000
#define B_ 32
#define MAXDEG_ 8
#define QD_ 128
#define ED_ 128
#define H_ 128
#define G4_ (4*H_)   /* 512 */
#define HPAD 168     /* padded LDS h-row (bf16): 128 h + 25 one-hot + pad, 336 B */
#define PSLOTS 64    /* partial row-sum slots */
#define RB_ 96       /* 3 rounds x 32 batch */

typedef unsigned short u16;
typedef __attribute__((ext_vector_type(8))) short bf16x8;     // 8 bf16 = 4 VGPRs
typedef __attribute__((ext_vector_type(8))) _Float16 f16x8;   // 8 f16  = 4 VGPRs
typedef __attribute__((ext_vector_type(4))) float f32x4;

#define BF16_ONE ((short)0x3F80)
#define LOG2E_  1.44269504f
#define LOG2E2_ 2.88539008f

__device__ __forceinline__ short f2bf(float f){
  union { float f; unsigned u; } v; v.f = f;
  unsigned r = v.u + 0x7fffu + ((v.u >> 16) & 1u);
  return (short)(r >> 16);
}
__device__ __forceinline__ float bf2f(u16 u){
  union { unsigned u; float f; } v; v.u = ((unsigned)u) << 16; return v.f;
}
__device__ __forceinline__ float frcp(float x){ return __builtin_amdgcn_rcpf(x); }
__device__ __forceinline__ float fsig(float x){ return frcp(1.0f + __expf(-x)); }
// tanh(x) = 2*sigmoid(2x) - 1
__device__ __forceinline__ float ftanh(float x){
  return __builtin_fmaf(2.0f, fsig(2.0f * x), -1.0f);
}
// 2^x via v_exp_f32 (guarded fallback keeps semantics if builtin missing)
__device__ __forceinline__ float fexp2(float x){
#if __has_builtin(__builtin_amdgcn_exp2f)
  return __builtin_amdgcn_exp2f(x);
#else
  return __expf(x * 0.6931471806f);
#endif
}

// ---------------- query BiLSTM + attention: one block per (r,b) ----------------
__global__ void qattn_kernel(const int* __restrict__ queries, const float* __restrict__ qemb,
    const float* __restrict__ qWih, const float* __restrict__ qWhh,
    const float* __restrict__ qbih, const float* __restrict__ qbhh,
    const float* __restrict__ qlinW, const float* __restrict__ qlinb,
    float* __restrict__ query_attn /* R,T,B,25 */)
{
  int r = blockIdx.x / B_;
  int b = blockIdx.x % B_;
  int tid = threadIdx.x;   // 256
  __shared__ float x[QD_];
  __shared__ float gx[G4_];
  __shared__ float h[H_], c[H_];
  __shared__ float gtmp[G4_];
  __shared__ float hh[2][T_][H_];
  __shared__ float lg[OPS_ + 1];

  int q = queries[b];
  if (tid < QD_) x[tid] = qemb[q * QD_ + tid];
  __syncthreads();

  for (int dir = 0; dir < 2; ++dir){
    const float* Wih = qWih + (size_t)(r * 2 + dir) * G4_ * QD_;
    const float* Whh = qWhh + (size_t)(r * 2 + dir) * G4_ * H_;
    const float* bih = qbih + (r * 2 + dir) * G4_;
    const float* bhh = qbhh + (r * 2 + dir) * G4_;
    for (int j = tid; j < G4_; j += 256){
      const float4* wr = (const float4*)(Wih + (size_t)j * QD_);
      float s = bih[j] + bhh[j];
      for (int k = 0; k < QD_ / 4; ++k){
        float4 wv = wr[k];
        s += wv.x * x[4*k] + wv.y * x[4*k+1] + wv.z * x[4*k+2] + wv.w * x[4*k+3];
      }
      gx[j] = s;
    }
    if (tid < H_){ h[tid] = 0.f; c[tid] = 0.f; }
    __syncthreads();
    for (int t = 0; t < T_; ++t){
      for (int j = tid; j < G4_; j += 256){
        const float4* wr = (const float4*)(Whh + (size_t)j * H_);
        float s = 0.f;
        for (int k = 0; k < H_ / 4; ++k){
          float4 wv = wr[k];
          s += wv.x * h[4*k] + wv.y * h[4*k+1] + wv.z * h[4*k+2] + wv.w * h[4*k+3];
        }
        gtmp[j] = gx[j] + s;
      }
      __syncthreads();
      if (tid < H_){
        float gi = gtmp[tid], gf = gtmp[tid + H_], gg = gtmp[tid + 2*H_], go = gtmp[tid + 3*H_];
        float cn = fsig(gf) * c[tid] + fsig(gi) * ftanh(gg);
        float hn = fsig(go) * ftanh(cn);
        c[tid] = cn; h[tid] = hn;
        hh[dir][t][tid] = hn;
      }
      __syncthreads();
    }
  }

  for (int t = 0; t < T_; ++t){
    if (tid < OPS_ + 1){
      const float* wr = qlinW + tid * (2 * H_);
      float s = qlinb[tid];
      for (int k = 0; k < H_; ++k) s += wr[k] * hh[0][t][k];
      for (int k = 0; k < H_; ++k) s += wr[H_ + k] * hh[1][T_ - 1 - t][k];
      lg[tid] = s;
    }
    __syncthreads();
    if (tid == 0){
      float m = -1e30f;
      for (int o = 0; o < OPS_ + 1; ++o) m = fmaxf(m, lg[o]);
      float sum = 0.f;
      for (int o = 0; o < OPS_ + 1; ++o){ float e = __expf(lg[o] - m); lg[o] = e; sum += e; }
      float inv = frcp(sum);
      for (int o = 0; o < OPS_ + 1; ++o) lg[o] *= inv;
    }
    __syncthreads();
    if (tid < OPS_ + 1) query_attn[((size_t)(r * T_ + t) * B_ + b) * (OPS_ + 1) + tid] = lg[tid];
    __syncthreads();
  }
}

// ---- build B-operand buffers in MFMA-fragment order (eproj folded in) ----
// Gate rows are PRE-SCALED by log2(e) (gates i,f,o) / 2*log2(e) (gate g) so the
// LSTM activation can use raw v_exp_f32 (=2^x) without per-exp ln2 muls.
__global__ void wbuild_kernel(const float* __restrict__ eWhh,
                              const float* __restrict__ eemb, const float* __restrict__ eWih,
                              const float* __restrict__ ebih, const float* __restrict__ ebhh,
                              u16* __restrict__ wtile, u16* __restrict__ wonehot)
{
  int idx = blockIdx.x * 256 + threadIdx.x;    // 2*32*5*64*8 = 163840
  if (idx >= 2 * 32 * 5 * 64 * 8) return;
  int jj = idx & 7;
  int lane = (idx >> 3) & 63;
  int kc = (idx >> 9) % 5;
  int gtile = (idx / (8 * 64 * 5)) & 31;
  int dir = idx / (8 * 64 * 5 * 32);
  int row = lane >> 4, col = lane & 15;
  int j = gtile * 16 + col;
  float sc = ((gtile >> 3) == 2) ? LOG2E2_ : LOG2E_;   // gate g rows get 2*log2e
  if (kc < 4){
    int k = kc * 32 + row * 8 + jj;
    float v = eWhh[((size_t)dir * G4_ + j) * H_ + k] * sc;
    wtile[((((size_t)dir * 32 + gtile) * 4 + kc) * 64 + lane) * 8 + jj] = (u16)f2bf(v);
  } else {
    int vdeg = row * 8 + jj;   // 0..31
    float v = 0.f;
    if (vdeg <= OPS_){
      const float4* wr = (const float4*)(eWih + (size_t)(dir * G4_ + j) * ED_);
      const float4* er = (const float4*)(eemb + (size_t)vdeg * ED_);
      float s = ebih[dir * G4_ + j] + ebhh[dir * G4_ + j];
      for (int k = 0; k < ED_ / 4; ++k){
        float4 wv = wr[k], ev = er[k];
        s += wv.x * ev.x + wv.y * ev.y + wv.z * ev.z + wv.w * ev.w;
      }
      v = s * sc;
    }
    wonehot[(((size_t)dir * 32 + gtile) * 64 + lane) * 8 + jj] = (u16)f2bf(v);
  }
}

// ------ entity BiLSTM: 1024 threads / 16 waves / 32 entities per block.
// BOTH DIRECTIONS RUN CONCURRENTLY: waves 0-7 = dir0, waves 8-15 = dir1, each dir
// with its own double-buffered hl. Serial barrier phases per block: 16 -> 8, and
// 32 waves/CU (100% occupancy) at 2 blocks/CU, so one dir-group's MFMA overlaps
// another's transcendental phase. Per-wave code = round-3's 60-VGPR version
// (acc[8], cst[8], kc unroll 1) -> fits the 64-reg cap of launch_bounds(1024,8).
// Weights stream from global (288 KB, L2-resident); per-gate bases wave-uniform.
// Round-4 lesson: caps that force the allocator below ~64 arch regs with deeper
// unroll spill catastrophically (WRITE_SIZE 146 MB); watch WRITE_SIZE ~25 MB here.
__global__ __launch_bounds__(1024, 8) void elstm_kernel(
    const int* __restrict__ degs,
    const u16* __restrict__ wtile, const u16* __restrict__ wonehot,
    u16* __restrict__ houts /* 2,N,128 f16 */)
{
  int tid = threadIdx.x;
  int lane = tid & 63;
  int w = tid >> 6;                                  // wave 0..15
  int wuF = __builtin_amdgcn_readfirstlane(w);       // wave-uniform
  int dirw = wuF >> 3;                               // 0: fwd, 1: bwd
  int wu   = wuF & 7;                                // wave-within-dir 0..7
  int row = lane >> 4, col = lane & 15;
  int ebase = blockIdx.x * 32;

  __shared__ __align__(16) short hl[2][2][32 * HPAD];  // [dir][buf], 4 x 10.5 KB
  __shared__ int degl[MAXDEG_ * 32];                   // [d][e] 1 KB

  for (int i = tid; i < 2 * 2 * 32 * HPAD; i += 1024) ((short*)hl)[i] = 0;
  if (tid < MAXDEG_ * 32){
    int e = tid & 31, d = tid >> 5;
    int eg = ebase + e; if (eg >= N_) eg = N_ - 1;
    degl[d * 32 + e] = degs[(size_t)eg * MAXDEG_ + d];
  }
  __syncthreads();
  if (tid < 64){
    int e = tid & 31, ds = tid >> 5;
    int d0 = ds ? (MAXDEG_ - 1) : 0;
    hl[ds][0][e * HPAD + H_ + degl[d0 * 32 + e]] = BF16_ONE;
  }
  __syncthreads();

  const u16* Wt  = wtile   + (size_t)dirw * 32 * 4 * 64 * 8;
  const u16* Woh = wonehot + (size_t)dirw * 32 * 64 * 8;
  // per-gate scalar bases (gtile = g*8 + wu)
  const u16* W0 = Wt + (size_t)((0 * 8 + wu) * 4 * 64) * 8;
  const u16* W1 = Wt + (size_t)((1 * 8 + wu) * 4 * 64) * 8;
  const u16* W2 = Wt + (size_t)((2 * 8 + wu) * 4 * 64) * 8;
  const u16* W3 = Wt + (size_t)((3 * 8 + wu) * 4 * 64) * 8;
  const u16* O0 = Woh + (size_t)((0 * 8 + wu) * 64) * 8;
  const u16* O1 = Woh + (size_t)((1 * 8 + wu) * 64) * 8;
  const u16* O2 = Woh + (size_t)((2 * 8 + wu) * 64) * 8;
  const u16* O3 = Woh + (size_t)((3 * 8 + wu) * 64) * 8;

  float cst[8];
  #pragma unroll
  for (int i = 0; i < 8; ++i) cst[i] = 0.f;

  for (int t = 0; t < MAXDEG_; ++t){
    const short* hb = hl[dirw][t & 1];          // holds h_t (+ one-hot for step t)
    short*       hw = hl[dirw][(t + 1) & 1];    // receives h_{t+1}
    f32x4 acc[8];
    #pragma unroll
    for (int i = 0; i < 8; ++i) acc[i] = (f32x4){0.f, 0.f, 0.f, 0.f};

    #pragma unroll 1
    for (int kc = 0; kc < 4; ++kc){
      bf16x8 af0 = *(const bf16x8*)&hb[(col) * HPAD + kc * 32 + row * 8];
      bf16x8 af1 = *(const bf16x8*)&hb[(16 + col) * HPAD + kc * 32 + row * 8];
      int lo = (kc * 64 + lane) * 8;
      bf16x8 b0 = *(const bf16x8*)(W0 + lo);
      bf16x8 b1 = *(const bf16x8*)(W1 + lo);
      bf16x8 b2 = *(const bf16x8*)(W2 + lo);
      bf16x8 b3 = *(const bf16x8*)(W3 + lo);
      acc[0] = __builtin_amdgcn_mfma_f32_16x16x32_bf16(af0, b0, acc[0], 0, 0, 0);
      acc[1] = __builtin_amdgcn_mfma_f32_16x16x32_bf16(af1, b0, acc[1], 0, 0, 0);
      acc[2] = __builtin_amdgcn_mfma_f32_16x16x32_bf16(af0, b1, acc[2], 0, 0, 0);
      acc[3] = __builtin_amdgcn_mfma_f32_16x16x32_bf16(af1, b1, acc[3], 0, 0, 0);
      acc[4] = __builtin_amdgcn_mfma_f32_16x16x32_bf16(af0, b2, acc[4], 0, 0, 0);
      acc[5] = __builtin_amdgcn_mfma_f32_16x16x32_bf16(af1, b2, acc[5], 0, 0, 0);
      acc[6] = __builtin_amdgcn_mfma_f32_16x16x32_bf16(af0, b3, acc[6], 0, 0, 0);
      acc[7] = __builtin_amdgcn_mfma_f32_16x16x32_bf16(af1, b3, acc[7], 0, 0, 0);
    }
    {
      bf16x8 af0 = *(const bf16x8*)&hb[(col) * HPAD + H_ + row * 8];
      bf16x8 af1 = *(const bf16x8*)&hb[(16 + col) * HPAD + H_ + row * 8];
      int lo = lane * 8;
      bf16x8 b0 = *(const bf16x8*)(O0 + lo);
      bf16x8 b1 = *(const bf16x8*)(O1 + lo);
      bf16x8 b2 = *(const bf16x8*)(O2 + lo);
      bf16x8 b3 = *(const bf16x8*)(O3 + lo);
      acc[0] = __builtin_amdgcn_mfma_f32_16x16x32_bf16(af0, b0, acc[0], 0, 0, 0);
      acc[1] = __builtin_amdgcn_mfma_f32_16x16x32_bf16(af1, b0, acc[1], 0, 0, 0);
      acc[2] = __builtin_amdgcn_mfma_f32_16x16x32_bf16(af0, b1, acc[2], 0, 0, 0);
      acc[3] = __builtin_amdgcn_mfma_f32_16x16x32_bf16(af1, b1, acc[3], 0, 0, 0);
      acc[4] = __builtin_amdgcn_mfma_f32_16x16x32_bf16(af0, b2, acc[4], 0, 0, 0);
      acc[5] = __builtin_amdgcn_mfma_f32_16x16x32_bf16(af1, b2, acc[5], 0, 0, 0);
      acc[6] = __builtin_amdgcn_mfma_f32_16x16x32_bf16(af0, b3, acc[6], 0, 0, 0);
      acc[7] = __builtin_amdgcn_mfma_f32_16x16x32_bf16(af1, b3, acc[7], 0, 0, 0);
    }

    // activation (gates pre-scaled by log2e / 2log2e):
    // cn = [cst*(1+ea)(1+eb) + (1-eb)(1+ef)] / [(1+ef)(1+ea)(1+eb)]
    // hn = (1-ed) / [(1+eo)(1+ed)],  ed = 2^(-2*log2e*cn)
    #pragma unroll
    for (int mt = 0; mt < 2; ++mt){
      #pragma unroll
      for (int reg = 0; reg < 4; ++reg){
        int e = mt * 16 + row * 4 + reg;
        int j = wu * 16 + col;
        float Gi = acc[0 + mt][reg];
        float Gf = acc[2 + mt][reg];
        float Gg = acc[4 + mt][reg];
        float Go = acc[6 + mt][reg];
        int ci = mt * 4 + reg;
        float ea = fexp2(-Gi);
        float ef = fexp2(-Gf);
        float eb = fexp2(-Gg);
        float eo = fexp2(-Go);
        float t1 = 1.f + ef, t2 = 1.f + ea, t3 = 1.f + eb;
        float p = t2 * t3;
        float num = __builtin_fmaf(cst[ci], p, (1.f - eb) * t1);
        float cn = num * frcp(t1 * p);
        float ed = fexp2(cn * (-LOG2E2_));
        float hn = (1.f - ed) * frcp((1.f + eo) * (1.f + ed));
        cst[ci] = cn;
        hw[e * HPAD + j] = f2bf(hn);
      }
    }
    // one-hot maintenance on each dir's write buffer: clear the slot set 2 steps
    // ago, set the slot step t+1 will read (clear BEFORE set handles repeats).
    if (tid < 64){
      int e = tid & 31, ds = tid >> 5;
      short* hwd = hl[ds][(t + 1) & 1];
      if (t >= 1)
        hwd[e * HPAD + H_ + degl[(ds ? (MAXDEG_ - t) : (t - 1)) * 32 + e]] = 0;
      if (t < MAXDEG_ - 1)
        hwd[e * HPAD + H_ + degl[(ds ? (MAXDEG_ - 2 - t) : (t + 1)) * 32 + e]] = BF16_ONE;
    }
    __syncthreads();
  }

  // MAXDEG_ even -> final h of each dir sits in hl[dir][0]. Store as F16 bits.
  for (int i = tid; i < 2 * 32 * H_; i += 1024){
    int ds = i >> 12;            // 32*128 = 4096 per dir
    int e = (i >> 7) & 31, k = i & 127;
    int n = ebase + e;
    if (n < N_){
      _Float16 hv = (_Float16)bf2f((u16)hl[ds][0][e * HPAD + k]);
      houts[(size_t)ds * N_ * H_ + (size_t)n * H_ + k] = *(const u16*)&hv;
    }
  }
}

// ------------- entity attention: f16 MFMA GEMM (N x 24 = hq(N x 256) @ W^T) -------------
// One wave per 16-node group; B frags (2 op-tiles x 8 ksteps, 64 VGPR) persist per wave.
// C/D layout (verified): col = lane&15 (=op), row = (lane>>4)*4+reg (=node-in-group).
// Softmax over 24 ops = 16-lane shfl_xor reduce across the two op-tiles.
__global__ void eattn_kernel(const u16* __restrict__ hq /* f16 bits, 2 x N x 128 */,
                             const float* __restrict__ elinW, const float* __restrict__ elinb,
                             float* __restrict__ attn /* N,24 */)
{
  int tid = threadIdx.x;
  int lane = tid & 63;
  int col = lane & 15;
  int krow = lane >> 4;   // 0..3

  f16x8 Bf[2][8];
  #pragma unroll
  for (int ot = 0; ot < 2; ++ot){
    int o = ot * 16 + col;
    #pragma unroll
    for (int ks = 0; ks < 8; ++ks){
      f16x8 bv;
      if (o < OPS_){
        const float* src = elinW + (size_t)o * (2 * H_) + ks * 32 + krow * 8;
        #pragma unroll
        for (int jj = 0; jj < 8; ++jj) bv[jj] = (_Float16)src[jj];
      } else {
        #pragma unroll
        for (int jj = 0; jj < 8; ++jj) bv[jj] = (_Float16)0.f;
      }
      Bf[ot][ks] = bv;
    }
  }
  float b0 = elinb[col];
  float b1 = (col < 8) ? elinb[16 + col] : -1e30f;

  int wid = blockIdx.x * 4 + (tid >> 6);
  for (int g = wid; g < N_ / 16; g += 256 * 4){
    f16x8 Af[8];
    #pragma unroll
    for (int ks = 0; ks < 8; ++ks){
      const u16* src = hq + (size_t)(ks >> 2) * N_ * H_
                          + (size_t)(g * 16 + col) * H_ + (ks & 3) * 32 + krow * 8;
      Af[ks] = *(const f16x8*)src;
    }
    f32x4 ac0 = (f32x4){0.f, 0.f, 0.f, 0.f};
    f32x4 ac1 = (f32x4){0.f, 0.f, 0.f, 0.f};
    #pragma unroll
    for (int ks = 0; ks < 8; ++ks){
      ac0 = __builtin_amdgcn_mfma_f32_16x16x32_f16(Af[ks], Bf[0][ks], ac0, 0, 0, 0);
      ac1 = __builtin_amdgcn_mfma_f32_16x16x32_f16(Af[ks], Bf[1][ks], ac1, 0, 0, 0);
    }
    #pragma unroll
    for (int reg = 0; reg < 4; ++reg){
      int node = g * 16 + krow * 4 + reg;
      float v0 = ac0[reg] + b0;
      float v1 = (col < 8) ? (ac1[reg] + b1) : -1e30f;
      float m = fmaxf(v0, v1);
      m = fmaxf(m, __shfl_xor(m, 1));
      m = fmaxf(m, __shfl_xor(m, 2));
      m = fmaxf(m, __shfl_xor(m, 4));
      m = fmaxf(m, __shfl_xor(m, 8));
      float e0 = __expf(v0 - m);
      float e1 = (col < 8) ? __expf(v1 - m) : 0.f;
      float s = e0 + e1;
      s += __shfl_xor(s, 1);
      s += __shfl_xor(s, 2);
      s += __shfl_xor(s, 4);
      s += __shfl_xor(s, 8);
      float inv = frcp(s);
      attn[(size_t)node * OPS_ + col] = e0 * inv;
      if (col < 8) attn[(size_t)node * OPS_ + 16 + col] = e1 * inv;
    }
  }
}

// ---------------- CSR build: per-node in-edge AND out-edge lists ----------------
__global__ void csr_count_kernel(const int* __restrict__ theads, const int* __restrict__ ttails,
                                 int* __restrict__ counts)
{
  int e = blockIdx.x * 256 + threadIdx.x;
  if (e < E_){
    atomicAdd(&counts[ttails[e]], 1);
    atomicAdd(&counts[theads[e]], 1);
  }
}

__global__ void csr_scan_kernel(const int* __restrict__ counts, int* __restrict__ rowptr,
                                int* __restrict__ cursor, int* __restrict__ cursor2)
{
  __shared__ int lsum[1024];
  int t = threadIdx.x;
  const int CH = (N_ + 1023) / 1024;   // 49
  int base = t * CH;
  int s = 0;
  for (int i = 0; i < CH; ++i){
    int idx = base + i;
    if (idx < N_) s += counts[idx];
  }
  lsum[t] = s;
  __syncthreads();
  for (int o = 1; o < 1024; o <<= 1){
    int u = (t >= o) ? lsum[t - o] : 0;
    __syncthreads();
    lsum[t] += u;
    __syncthreads();
  }
  int run = lsum[t] - s;
  for (int i = 0; i < CH; ++i){
    int idx = base + i;
    if (idx < N_){
      rowptr[idx] = run;
      cursor[idx] = run;
      cursor2[idx] = run;
      run += counts[idx];
    }
  }
  if (t == 1023) rowptr[N_] = run;
}

__global__ void csr_fill_kernel(const int* __restrict__ rels, const int* __restrict__ theads,
                                const int* __restrict__ ttails, const float* __restrict__ attn,
                                int* __restrict__ cursor, int* __restrict__ cursor2,
                                uint2* __restrict__ ents, uint2* __restrict__ ents2)
{
  int e = blockIdx.x * 256 + threadIdx.x;
  if (e < E_){
    int hh = theads[e], tt = ttails[e], rel = rels[e];
    unsigned wb = __float_as_uint(attn[(size_t)hh * OPS_ + rel]);
    uint2 v1; v1.x = (unsigned)hh | ((unsigned)rel << 16);            v1.y = wb;
    uint2 v2; v2.x = (unsigned)tt | ((unsigned)(rel + OPS_/2) << 16); v2.y = wb;
    ents[atomicAdd(&cursor[tt], 1)] = v1;
    ents[atomicAdd(&cursor[hh], 1)] = v2;
    uint2 w1; w1.x = (unsigned)tt | ((unsigned)rel << 16);            w1.y = wb;
    uint2 w2; w2.x = (unsigned)hh | ((unsigned)(rel + OPS_/2) << 16); w2.y = wb;
    ents2[atomicAdd(&cursor2[hh], 1)] = w1;
    ents2[atomicAdd(&cursor2[tt], 1)] = w2;
  }
}

// ---- t=0 sparse step: u0 is one-hot(heads) -> u1 from out-edges of 32 head nodes ----
__global__ void t0_kernel(const int* __restrict__ heads, const float* __restrict__ query_attn,
                          const int* __restrict__ rowptr, const uint2* __restrict__ ents2,
                          float* __restrict__ u1 /* N x 96 */)
{
  int tid = threadIdx.x;
  if (tid >= RB_) return;
  int r = tid >> 5, b = tid & 31;
  const float* qa = query_attn + ((size_t)(r * T_ + 0) * B_ + b) * (OPS_ + 1);
  int hn = heads[b];
  int rb = r * 32 + b;
  u1[(size_t)hn * RB_ + rb] += qa[OPS_];
  int beg = rowptr[hn], end = rowptr[hn + 1];
  for (int i = beg; i < end; ++i){
    uint2 e = ents2[i];
    int dst = (int)(e.x & 0xFFFFu);
    int rl  = (int)(e.x >> 16);
    u1[(size_t)dst * RB_ + rb] += qa[rl] * __uint_as_float(e.y);
  }
}

// ---- t=1 dense self-term: u2 = qa1_24 (.) u1 (elementwise; replaces memset) ----
__global__ void u2init_kernel(const float* __restrict__ query_attn,
                              const float* __restrict__ u1, float* __restrict__ u2)
{
  __shared__ float q24[RB_];
  int tid = threadIdx.x;
  if (tid < RB_){
    int r = tid >> 5, b = tid & 31;
    q24[tid] = query_attn[((size_t)(r * T_ + 1) * B_ + b) * (OPS_ + 1) + OPS_];
  }
  __syncthreads();
  int idx = blockIdx.x * 256 + tid;
  if (idx < N_ * RB_) u2[idx] = u1[idx] * q24[idx % RB_];
}

// ---- t=1 sparse pushes: u1 nonzero only at {head} U outNbr(head) per column.
__global__ void t1push_kernel(const int* __restrict__ heads, const float* __restrict__ query_attn,
                              const int* __restrict__ rowptr, const uint2* __restrict__ ents2,
                              const float* __restrict__ u1, float* __restrict__ u2)
{
  __shared__ float qa0[OPS_ + 1], qa1[OPS_ + 1];
  int blk = blockIdx.x;   // 0..95
  int r = blk >> 5, b = blk & 31;
  int rb = r * 32 + b;
  int tid = threadIdx.x;  // 64
  if (tid < OPS_ + 1){
    qa0[tid] = query_attn[((size_t)(r * T_ + 0) * B_ + b) * (OPS_ + 1) + tid];
    qa1[tid] = query_attn[((size_t)(r * T_ + 1) * B_ + b) * (OPS_ + 1) + tid];
  }
  __syncthreads();
  int hd = heads[b];
  int beg = rowptr[hd], end = rowptr[hd + 1];
  float q024 = qa0[OPS_];
  for (int i = beg + tid; i < end; i += 64){
    uint2 e1 = ents2[i];
    int s  = (int)(e1.x & 0xFFFFu);
    int r1 = (int)(e1.x >> 16);
    float w1 = __uint_as_float(e1.y);
    atomicAdd(&u2[(size_t)s * RB_ + rb], qa1[r1] * w1 * q024);
    float v1 = qa0[r1] * w1;      // this path's share of u1[s]
    int b2 = rowptr[s], e2e = rowptr[s + 1];
    for (int jj = b2; jj < e2e; ++jj){
      uint2 e2 = ents2[jj];
      int d2 = (int)(e2.x & 0xFFFFu);
      int r2 = (int)(e2.x >> 16);
      atomicAdd(&u2[(size_t)d2 * RB_ + rb], qa1[r2] * __uint_as_float(e2.y) * v1);
    }
  }
}

// ---- batched dense gather (t=2): ONE WAVE per node, halves split 4-edge chunks ----
__global__ __launch_bounds__(256) void gather3_kernel(
    const float* __restrict__ ucur, float* __restrict__ unxt,
    const float* __restrict__ query_attn, int t,
    const int* __restrict__ rowptr, const uint2* __restrict__ ents,
    float* __restrict__ partial /* PSLOTS x 96 */)
{
  __shared__ float qas[3 * B_ * (OPS_ + 1)];  // [r][b][o]
  __shared__ float red[RB_];
  int tid = threadIdx.x;
  for (int i = tid; i < 3 * B_ * (OPS_ + 1); i += 256){
    int r = i / (B_ * (OPS_ + 1));
    int rem = i - r * (B_ * (OPS_ + 1));
    qas[i] = query_attn[(size_t)(r * T_ + t) * B_ * (OPS_ + 1) + rem];
  }
  if (tid < RB_) red[tid] = 0.f;
  __syncthreads();
  int b  = tid & 31;
  int h  = (tid >> 5) & 1;              // half within wave
  int n = blockIdx.x * 4 + (tid >> 6);  // one wave per node; grid*4 == N_
  const float* q0 = &qas[0 * 800 + b * (OPS_ + 1)];
  const float* q1 = &qas[1 * 800 + b * (OPS_ + 1)];
  const float* q2 = &qas[2 * 800 + b * (OPS_ + 1)];
  size_t nb = (size_t)n * RB_;
  float a0 = 0.f, a1 = 0.f, a2 = 0.f;
  if (h == 0){
    a0 = ucur[nb + b]      * q0[OPS_];
    a1 = ucur[nb + 32 + b] * q1[OPS_];
    a2 = ucur[nb + 64 + b] * q2[OPS_];
  }
  int beg = rowptr[n], end = rowptr[n + 1];
  int cnt = end - beg;
  int nq = cnt >> 2;                 // full 4-edge chunks
  for (int c = h; c < nq; c += 2){
    int i0 = beg + 4 * c;
    uint2 e0 = ents[i0 + 0];
    uint2 e1 = ents[i0 + 1];
    uint2 e2 = ents[i0 + 2];
    uint2 e3 = ents[i0 + 3];
    size_t s0 = (size_t)(e0.x & 0xFFFFu) * RB_;
    size_t s1 = (size_t)(e1.x & 0xFFFFu) * RB_;
    size_t s2 = (size_t)(e2.x & 0xFFFFu) * RB_;
    size_t s3 = (size_t)(e3.x & 0xFFFFu) * RB_;
    float u00 = ucur[s0 + b], u01 = ucur[s0 + 32 + b], u02 = ucur[s0 + 64 + b];
    float u10 = ucur[s1 + b], u11 = ucur[s1 + 32 + b], u12 = ucur[s1 + 64 + b];
    float u20 = ucur[s2 + b], u21 = ucur[s2 + 32 + b], u22 = ucur[s2 + 64 + b];
    float u30 = ucur[s3 + b], u31 = ucur[s3 + 32 + b], u32 = ucur[s3 + 64 + b];
    int r0 = (int)(e0.x >> 16), r1 = (int)(e1.x >> 16);
    int r2 = (int)(e2.x >> 16), r3 = (int)(e3.x >> 16);
    float w0 = __uint_as_float(e0.y), w1 = __uint_as_float(e1.y);
    float w2 = __uint_as_float(e2.y), w3 = __uint_as_float(e3.y);
    a0 += q0[r0]*w0*u00 + q0[r1]*w1*u10 + q0[r2]*w2*u20 + q0[r3]*w3*u30;
    a1 += q1[r0]*w0*u01 + q1[r1]*w1*u11 + q1[r2]*w2*u21 + q1[r3]*w3*u31;
    a2 += q2[r0]*w0*u02 + q2[r1]*w1*u12 + q2[r2]*w2*u22 + q2[r3]*w3*u32;
  }
  if (h == 1){
    for (int i = beg + 4 * nq; i < end; ++i){
      uint2 e0 = ents[i];
      size_t s0 = (size_t)(e0.x & 0xFFFFu) * RB_;
      int r0 = (int)(e0.x >> 16);
      float w0 = __uint_as_float(e0.y);
      a0 += q0[r0] * w0 * ucur[s0 + b];
      a1 += q1[r0] * w0 * ucur[s0 + 32 + b];
      a2 += q2[r0] * w0 * ucur[s0 + 64 + b];
    }
  }
  a0 += __shfl_xor(a0, 32);
  a1 += __shfl_xor(a1, 32);
  a2 += __shfl_xor(a2, 32);
  if (h == 0){
    unxt[nb + b]      = a0;
    unxt[nb + 32 + b] = a1;
    unxt[nb + 64 + b] = a2;
    atomicAdd(&red[b], a0);
    atomicAdd(&red[32 + b], a1);
    atomicAdd(&red[64 + b], a2);
  }
  __syncthreads();
  if (tid < RB_)
    atomicAdd(&partial[(blockIdx.x & (PSLOTS - 1)) * RB_ + tid], red[tid]);
}

// ---- finalize + transpose: out[b][n] = sum_r u[n][r*32+b] / rowsum_r ----
__global__ void fintrans_kernel(const float* __restrict__ u, const float* __restrict__ partial,
                                float* __restrict__ out)
{
  __shared__ float sinv[RB_];
  __shared__ float t[B_][72];
  int tid = threadIdx.x;   // 256
  if (tid < RB_){
    float s = 0.f;
    #pragma unroll 8
    for (int k = 0; k < PSLOTS; ++k) s += partial[k * RB_ + tid];
    sinv[tid] = frcp(fmaxf(1e-20f, s));
  }
  __syncthreads();
  int n0 = blockIdx.x * 64;
  for (int i = tid; i < 64 * B_; i += 256){
    int nl = i >> 5, b = i & 31;
    int n = n0 + nl;
    float v = 0.f;
    if (n < N_){
      size_t nb = (size_t)n * RB_;
      v = u[nb + b] * sinv[b] + u[nb + 32 + b] * sinv[32 + b] + u[nb + 64 + b] * sinv[64 + b];
    }
    t[b][nl] = v;
  }
  __syncthreads();
  for (int i = tid; i < 64 * B_; i += 256){
    int b = i >> 6, nl = i & 63;
    int n = n0 + nl;
    if (n < N_) out[(size_t)b * N_ + n] = t[b][nl];
  }
}

extern "C" void kernel_launch(void* const* d_in, const int* in_sizes, int n_in,
                              void* d_out, int out_size, void* d_ws, size_t ws_size,
                              hipStream_t stream)
{
  const int*   queries = (const int*)d_in[0];
  const int*   heads   = (const int*)d_in[1];
  const int*   rels    = (const int*)d_in[2];
  const int*   t_heads = (const int*)d_in[3];
  const int*   t_tails = (const int*)d_in[4];
  const int*   edeg    = (const int*)d_in[5];
  const float* qemb    = (const float*)d_in[6];
  const float* eemb    = (const float*)d_in[7];
  const float* qWih    = (const float*)d_in[8];
  const float* qWhh    = (const float*)d_in[9];
  const float* qbih    = (const float*)d_in[10];
  const float* qbhh    = (const float*)d_in[11];
  const float* eWih    = (const float*)d_in[12];
  const float* eWhh    = (const float*)d_in[13];
  const float* ebih    = (const float*)d_in[14];
  const float* ebhh    = (const float*)d_in[15];
  const float* qlinW   = (const float*)d_in[16];
  const float* qlinb   = (const float*)d_in[17];
  const float* elinW   = (const float*)d_in[18];
  const float* elinb   = (const float*)d_in[19];
  float* out = (float*)d_out;

  char* ws = (char*)d_ws;
  size_t off = 0;
  auto alloc = [&](size_t bytes){ void* p = ws + off; off += (bytes + 255) & ~(size_t)255; return p; };
  // bigA (25.6 MB): houts during [elstm, eattn]; after eattn dead ->
  //   ents (6.4 MB, csr_fill) at +0, u2 (19.2 MB) at +6.4 MB.
  char*  bigA  = (char*)alloc((size_t)2 * N_ * H_ * 2);               // 25,600,000
  u16*   houts = (u16*)bigA;                                          // f16 bits
  uint2* ents  = (uint2*)bigA;                                        // in-CSR, 6.4 MB
  float* u2    = (float*)(bigA + (size_t)2 * E_ * 8);                 // 19.2 MB
  // bigB (19.2 MB): attn (4.8 MB) during [eattn, csr_fill]; then u1; then u3.
  char*  bigB  = (char*)alloc((size_t)N_ * RB_ * 4);
  float* attn  = (float*)bigB;
  float* u1    = (float*)bigB;
  float* u3    = (float*)bigB;
  uint2* ents2      = (uint2*)alloc((size_t)2 * E_ * 8);              // out-CSR, 6.4 MB
  float* query_attn = (float*)alloc((size_t)R_ * T_ * B_ * (OPS_ + 1) * 4);
  u16*   wtile      = (u16*)  alloc((size_t)2 * 32 * 4 * 64 * 8 * 2);
  u16*   wonehot    = (u16*)  alloc((size_t)2 * 32 * 64 * 8 * 2);
  int*   counts     = (int*)  alloc((size_t)(N_ + 1) * 4);
  int*   rowptr     = (int*)  alloc((size_t)(N_ + 1) * 4);
  int*   cursor     = (int*)  alloc((size_t)(N_ + 1) * 4);
  int*   cursor2    = (int*)  alloc((size_t)(N_ + 1) * 4);
  float* sumsP      = (float*)alloc((size_t)PSLOTS * RB_ * 4);        // t2 partials only
  // total ~52 MB

  hipMemsetAsync(sumsP, 0, (size_t)PSLOTS * RB_ * 4, stream);
  hipMemsetAsync(counts, 0, (size_t)(N_ + 1) * 4, stream);

  qattn_kernel<<<R_ * B_, 256, 0, stream>>>(queries, qemb, qWih, qWhh, qbih, qbhh,
                                            qlinW, qlinb, query_attn);
  wbuild_kernel<<<(2 * 32 * 5 * 64 * 8 + 255) / 256, 256, 0, stream>>>(
      eWhh, eemb, eWih, ebih, ebhh, wtile, wonehot);
  csr_count_kernel<<<(E_ + 255) / 256, 256, 0, stream>>>(t_heads, t_tails, counts);
  csr_scan_kernel<<<1, 1024, 0, stream>>>(counts, rowptr, cursor, cursor2);
  elstm_kernel<<<(N_ + 31) / 32, 1024, 0, stream>>>(edeg, wtile, wonehot, houts);
  eattn_kernel<<<256, 256, 0, stream>>>(houts, elinW, elinb, attn);
  // houts dead -> ents may take bigA[0:6.4M]; attn still live (read by csr_fill):
  csr_fill_kernel<<<(E_ + 255) / 256, 256, 0, stream>>>(rels, t_heads, t_tails, attn,
                                                        cursor, cursor2, ents, ents2);
  // attn dead -> u1 takes bigB
  hipMemsetAsync(u1, 0, (size_t)N_ * RB_ * 4, stream);
  t0_kernel<<<1, 128, 0, stream>>>(heads, query_attn, rowptr, ents2, u1);
  // t=1: dense self-term + sparse 2-hop pushes (replaces a full dense gather)
  u2init_kernel<<<(N_ * RB_ + 255) / 256, 256, 0, stream>>>(query_attn, u1, u2);
  t1push_kernel<<<RB_, 64, 0, stream>>>(heads, query_attn, rowptr, ents2, u1, u2);
  // t=2: dense gather (u1 dead; u3 overwrites bigB)
  gather3_kernel<<<N_ / 4, 256, 0, stream>>>(u2, u3, query_attn, 2, rowptr, ents, sumsP);
  fintrans_kernel<<<(N_ + 63) / 64, 256, 0, stream>>>(u3, sumsP, out);
}

// Round 6
// 782.868 us; speedup vs baseline: 1.2709x; 1.2709x over previous
//
#include <hip/hip_runtime.h>

#define R_ 3
#define T_ 3
#define N_ 50000
#define OPS_ 24
#define E_ 400000
#define B_ 32
#define MAXDEG_ 8
#define QD_ 128
#define ED_ 128
#define H_ 128
#define G4_ (4*H_)   /* 512 */
#define HPAD 168     /* padded LDS h-row (bf16): 128 h + 25 one-hot + pad, 336 B */
#define PSLOTS 64    /* partial row-sum slots */
#define RB_ 96       /* 3 rounds x 32 batch */

/* front fat-kernel block ranges */
#define QB_ (R_ * B_)                          /* 96  qattn blocks  */
#define WB_ ((2*32*5*64*8 + 255) / 256)        /* 640 wbuild blocks */
#define CB_ ((E_ + 255) / 256)                 /* 1563 csr_count    */

typedef unsigned short u16;
typedef __attribute__((ext_vector_type(8))) short bf16x8;     // 8 bf16 = 4 VGPRs
typedef __attribute__((ext_vector_type(8))) _Float16 f16x8;   // 8 f16  = 4 VGPRs
typedef __attribute__((ext_vector_type(4))) float f32x4;

#define BF16_ONE ((short)0x3F80)
#define LOG2E_  1.44269504f
#define LOG2E2_ 2.88539008f

__device__ __forceinline__ short f2bf(float f){
  union { float f; unsigned u; } v; v.f = f;
  unsigned r = v.u + 0x7fffu + ((v.u >> 16) & 1u);
  return (short)(r >> 16);
}
__device__ __forceinline__ float bf2f(u16 u){
  union { unsigned u; float f; } v; v.u = ((unsigned)u) << 16; return v.f;
}
__device__ __forceinline__ float frcp(float x){ return __builtin_amdgcn_rcpf(x); }
__device__ __forceinline__ float fsig(float x){ return frcp(1.0f + __expf(-x)); }
// tanh(x) = 2*sigmoid(2x) - 1
__device__ __forceinline__ float ftanh(float x){
  return __builtin_fmaf(2.0f, fsig(2.0f * x), -1.0f);
}
// 2^x via v_exp_f32 (guarded fallback keeps semantics if builtin missing)
__device__ __forceinline__ float fexp2(float x){
#if __has_builtin(__builtin_amdgcn_exp2f)
  return __builtin_amdgcn_exp2f(x);
#else
  return __expf(x * 0.6931471806f);
#endif
}

// ---------------- query BiLSTM + attention: one virtual block per (r,b) ----------------
__device__ void qattn_body(int bid, const int* __restrict__ queries, const float* __restrict__ qemb,
    const float* __restrict__ qWih, const float* __restrict__ qWhh,
    const float* __restrict__ qbih, const float* __restrict__ qbhh,
    const float* __restrict__ qlinW, const float* __restrict__ qlinb,
    float* __restrict__ query_attn /* R,T,B,25 */)
{
  int r = bid / B_;
  int b = bid % B_;
  int tid = threadIdx.x;   // 256
  __shared__ float x[QD_];
  __shared__ float gx[G4_];
  __shared__ float h[H_], c[H_];
  __shared__ float gtmp[G4_];
  __shared__ float hh[2][T_][H_];
  __shared__ float lg[OPS_ + 1];

  int q = queries[b];
  if (tid < QD_) x[tid] = qemb[q * QD_ + tid];
  __syncthreads();

  for (int dir = 0; dir < 2; ++dir){
    const float* Wih = qWih + (size_t)(r * 2 + dir) * G4_ * QD_;
    const float* Whh = qWhh + (size_t)(r * 2 + dir) * G4_ * H_;
    const float* bih = qbih + (r * 2 + dir) * G4_;
    const float* bhh = qbhh + (r * 2 + dir) * G4_;
    for (int j = tid; j < G4_; j += 256){
      const float4* wr = (const float4*)(Wih + (size_t)j * QD_);
      float s = bih[j] + bhh[j];
      for (int k = 0; k < QD_ / 4; ++k){
        float4 wv = wr[k];
        s += wv.x * x[4*k] + wv.y * x[4*k+1] + wv.z * x[4*k+2] + wv.w * x[4*k+3];
      }
      gx[j] = s;
    }
    if (tid < H_){ h[tid] = 0.f; c[tid] = 0.f; }
    __syncthreads();
    for (int t = 0; t < T_; ++t){
      for (int j = tid; j < G4_; j += 256){
        const float4* wr = (const float4*)(Whh + (size_t)j * H_);
        float s = 0.f;
        for (int k = 0; k < H_ / 4; ++k){
          float4 wv = wr[k];
          s += wv.x * h[4*k] + wv.y * h[4*k+1] + wv.z * h[4*k+2] + wv.w * h[4*k+3];
        }
        gtmp[j] = gx[j] + s;
      }
      __syncthreads();
      if (tid < H_){
        float gi = gtmp[tid], gf = gtmp[tid + H_], gg = gtmp[tid + 2*H_], go = gtmp[tid + 3*H_];
        float cn = fsig(gf) * c[tid] + fsig(gi) * ftanh(gg);
        float hn = fsig(go) * ftanh(cn);
        c[tid] = cn; h[tid] = hn;
        hh[dir][t][tid] = hn;
      }
      __syncthreads();
    }
  }

  for (int t = 0; t < T_; ++t){
    if (tid < OPS_ + 1){
      const float* wr = qlinW + tid * (2 * H_);
      float s = qlinb[tid];
      for (int k = 0; k < H_; ++k) s += wr[k] * hh[0][t][k];
      for (int k = 0; k < H_; ++k) s += wr[H_ + k] * hh[1][T_ - 1 - t][k];
      lg[tid] = s;
    }
    __syncthreads();
    if (tid == 0){
      float m = -1e30f;
      for (int o = 0; o < OPS_ + 1; ++o) m = fmaxf(m, lg[o]);
      float sum = 0.f;
      for (int o = 0; o < OPS_ + 1; ++o){ float e = __expf(lg[o] - m); lg[o] = e; sum += e; }
      float inv = frcp(sum);
      for (int o = 0; o < OPS_ + 1; ++o) lg[o] *= inv;
    }
    __syncthreads();
    if (tid < OPS_ + 1) query_attn[((size_t)(r * T_ + t) * B_ + b) * (OPS_ + 1) + tid] = lg[tid];
    __syncthreads();
  }
}

// ---- build B-operand buffers in MFMA-fragment order (eproj folded in) ----
// Gate rows are PRE-SCALED by log2(e) (gates i,f,o) / 2*log2(e) (gate g) so the
// LSTM activation can use raw v_exp_f32 (=2^x) without per-exp ln2 muls.
__device__ void wbuild_body(int bid, const float* __restrict__ eWhh,
                            const float* __restrict__ eemb, const float* __restrict__ eWih,
                            const float* __restrict__ ebih, const float* __restrict__ ebhh,
                            u16* __restrict__ wtile, u16* __restrict__ wonehot)
{
  int idx = bid * 256 + threadIdx.x;    // 2*32*5*64*8 = 163840
  if (idx >= 2 * 32 * 5 * 64 * 8) return;
  int jj = idx & 7;
  int lane = (idx >> 3) & 63;
  int kc = (idx >> 9) % 5;
  int gtile = (idx / (8 * 64 * 5)) & 31;
  int dir = idx / (8 * 64 * 5 * 32);
  int row = lane >> 4, col = lane & 15;
  int j = gtile * 16 + col;
  float sc = ((gtile >> 3) == 2) ? LOG2E2_ : LOG2E_;   // gate g rows get 2*log2e
  if (kc < 4){
    int k = kc * 32 + row * 8 + jj;
    float v = eWhh[((size_t)dir * G4_ + j) * H_ + k] * sc;
    wtile[((((size_t)dir * 32 + gtile) * 4 + kc) * 64 + lane) * 8 + jj] = (u16)f2bf(v);
  } else {
    int vdeg = row * 8 + jj;   // 0..31
    float v = 0.f;
    if (vdeg <= OPS_){
      const float4* wr = (const float4*)(eWih + (size_t)(dir * G4_ + j) * ED_);
      const float4* er = (const float4*)(eemb + (size_t)vdeg * ED_);
      float s = ebih[dir * G4_ + j] + ebhh[dir * G4_ + j];
      for (int k = 0; k < ED_ / 4; ++k){
        float4 wv = wr[k], ev = er[k];
        s += wv.x * ev.x + wv.y * ev.y + wv.z * ev.z + wv.w * ev.w;
      }
      v = s * sc;
    }
    wonehot[(((size_t)dir * 32 + gtile) * 64 + lane) * 8 + jj] = (u16)f2bf(v);
  }
}

__device__ void csr_count_body(int bid, const int* __restrict__ theads,
                               const int* __restrict__ ttails, int* __restrict__ counts)
{
  int e = bid * 256 + threadIdx.x;
  if (e < E_){
    atomicAdd(&counts[ttails[e]], 1);
    atomicAdd(&counts[theads[e]], 1);
  }
}

// ---- front fat-kernel: qattn | wbuild | csr_count are mutually independent but were
// serialized on the stream (qattn alone uses 96/256 CUs). One launch, block-range split.
__global__ __launch_bounds__(256) void front_kernel(
    const int* queries, const float* qemb,
    const float* qWih, const float* qWhh, const float* qbih, const float* qbhh,
    const float* qlinW, const float* qlinb, float* query_attn,
    const float* eWhh, const float* eemb, const float* eWih,
    const float* ebih, const float* ebhh, u16* wtile, u16* wonehot,
    const int* theads, const int* ttails, int* counts)
{
  int bid = blockIdx.x;
  if (bid < QB_){
    qattn_body(bid, queries, qemb, qWih, qWhh, qbih, qbhh, qlinW, qlinb, query_attn);
  } else if (bid < QB_ + WB_){
    wbuild_body(bid - QB_, eWhh, eemb, eWih, ebih, ebhh, wtile, wonehot);
  } else {
    csr_count_body(bid - QB_ - WB_, theads, ttails, counts);
  }
}

// ------ entity BiLSTM: 512 threads / 8 waves / 32 entities per block (r3-exact).
// Weights stream from global (288 KB, L2-resident); per-gate bases wave-uniform.
// launch_bounds(512,4): cap 128 regs -> 60 VGPR + 32 AGPR = 92 combined, no spill.
// Occupancy ladder is BINARY (r4/r5 lesson): <=64 combined -> 8 waves/SIMD
// (infeasible, demand 92), <=128 -> 4 waves/SIMD. This is the operating point;
// 74% issue-busy (50 VALU + 24 MFMA), remainder is barrier drain.
__global__ __launch_bounds__(512, 4) void elstm_kernel(
    const int* __restrict__ degs,
    const u16* __restrict__ wtile, const u16* __restrict__ wonehot,
    u16* __restrict__ houts /* 2,N,128 f16 */)
{
  int tid = threadIdx.x;
  int lane = tid & 63;
  int w = tid >> 6;          // wave 0..7
  int wu = __builtin_amdgcn_readfirstlane(w);   // provably wave-uniform
  int row = lane >> 4, col = lane & 15;
  int ebase = blockIdx.x * 32;

  __shared__ __align__(16) short hl[2][32 * HPAD];   // 2 x 10.5 KB ping-pong

  int eg0 = ebase + tid; if (eg0 >= N_) eg0 = N_ - 1;   // valid for tid<32 use

  for (int i = tid; i < 2 * 32 * HPAD; i += 512) ((short*)hl)[i] = 0;
  __syncthreads();
  if (tid < 32) hl[0][tid * HPAD + H_ + degs[(size_t)eg0 * MAXDEG_ + 0]] = BF16_ONE;
  __syncthreads();

  for (int dir = 0; dir < 2; ++dir){
    const u16* Wt  = wtile   + (size_t)dir * 32 * 4 * 64 * 8;
    const u16* Woh = wonehot + (size_t)dir * 32 * 64 * 8;
    // per-gate scalar bases (gtile = g*8 + wu)
    const u16* W0 = Wt + (size_t)((0 * 8 + wu) * 4 * 64) * 8;
    const u16* W1 = Wt + (size_t)((1 * 8 + wu) * 4 * 64) * 8;
    const u16* W2 = Wt + (size_t)((2 * 8 + wu) * 4 * 64) * 8;
    const u16* W3 = Wt + (size_t)((3 * 8 + wu) * 4 * 64) * 8;
    const u16* O0 = Woh + (size_t)((0 * 8 + wu) * 64) * 8;
    const u16* O1 = Woh + (size_t)((1 * 8 + wu) * 64) * 8;
    const u16* O2 = Woh + (size_t)((2 * 8 + wu) * 64) * 8;
    const u16* O3 = Woh + (size_t)((3 * 8 + wu) * 64) * 8;
    float cst[8];
    #pragma unroll
    for (int i = 0; i < 8; ++i) cst[i] = 0.f;

    for (int t = 0; t < MAXDEG_; ++t){
      const short* hb = hl[t & 1];          // holds h_t (+ one-hot for step t)
      short*       hw = hl[(t + 1) & 1];    // receives h_{t+1}
      f32x4 acc[8];
      #pragma unroll
      for (int i = 0; i < 8; ++i) acc[i] = (f32x4){0.f, 0.f, 0.f, 0.f};

      #pragma unroll 2
      for (int kc = 0; kc < 4; ++kc){
        bf16x8 af0 = *(const bf16x8*)&hb[(col) * HPAD + kc * 32 + row * 8];
        bf16x8 af1 = *(const bf16x8*)&hb[(16 + col) * HPAD + kc * 32 + row * 8];
        int lo = (kc * 64 + lane) * 8;
        bf16x8 b0 = *(const bf16x8*)(W0 + lo);
        bf16x8 b1 = *(const bf16x8*)(W1 + lo);
        bf16x8 b2 = *(const bf16x8*)(W2 + lo);
        bf16x8 b3 = *(const bf16x8*)(W3 + lo);
        acc[0] = __builtin_amdgcn_mfma_f32_16x16x32_bf16(af0, b0, acc[0], 0, 0, 0);
        acc[1] = __builtin_amdgcn_mfma_f32_16x16x32_bf16(af1, b0, acc[1], 0, 0, 0);
        acc[2] = __builtin_amdgcn_mfma_f32_16x16x32_bf16(af0, b1, acc[2], 0, 0, 0);
        acc[3] = __builtin_amdgcn_mfma_f32_16x16x32_bf16(af1, b1, acc[3], 0, 0, 0);
        acc[4] = __builtin_amdgcn_mfma_f32_16x16x32_bf16(af0, b2, acc[4], 0, 0, 0);
        acc[5] = __builtin_amdgcn_mfma_f32_16x16x32_bf16(af1, b2, acc[5], 0, 0, 0);
        acc[6] = __builtin_amdgcn_mfma_f32_16x16x32_bf16(af0, b3, acc[6], 0, 0, 0);
        acc[7] = __builtin_amdgcn_mfma_f32_16x16x32_bf16(af1, b3, acc[7], 0, 0, 0);
      }
      {
        bf16x8 af0 = *(const bf16x8*)&hb[(col) * HPAD + H_ + row * 8];
        bf16x8 af1 = *(const bf16x8*)&hb[(16 + col) * HPAD + H_ + row * 8];
        int lo = lane * 8;
        bf16x8 b0 = *(const bf16x8*)(O0 + lo);
        bf16x8 b1 = *(const bf16x8*)(O1 + lo);
        bf16x8 b2 = *(const bf16x8*)(O2 + lo);
        bf16x8 b3 = *(const bf16x8*)(O3 + lo);
        acc[0] = __builtin_amdgcn_mfma_f32_16x16x32_bf16(af0, b0, acc[0], 0, 0, 0);
        acc[1] = __builtin_amdgcn_mfma_f32_16x16x32_bf16(af1, b0, acc[1], 0, 0, 0);
        acc[2] = __builtin_amdgcn_mfma_f32_16x16x32_bf16(af0, b1, acc[2], 0, 0, 0);
        acc[3] = __builtin_amdgcn_mfma_f32_16x16x32_bf16(af1, b1, acc[3], 0, 0, 0);
        acc[4] = __builtin_amdgcn_mfma_f32_16x16x32_bf16(af0, b2, acc[4], 0, 0, 0);
        acc[5] = __builtin_amdgcn_mfma_f32_16x16x32_bf16(af1, b2, acc[5], 0, 0, 0);
        acc[6] = __builtin_amdgcn_mfma_f32_16x16x32_bf16(af0, b3, acc[6], 0, 0, 0);
        acc[7] = __builtin_amdgcn_mfma_f32_16x16x32_bf16(af1, b3, acc[7], 0, 0, 0);
      }

      // activation (gates pre-scaled by log2e / 2log2e):
      // cn = [cst*(1+ea)(1+eb) + (1-eb)(1+ef)] / [(1+ef)(1+ea)(1+eb)]
      // hn = (1-ed) / [(1+eo)(1+ed)],  ed = 2^(-2*log2e*cn)
      #pragma unroll
      for (int mt = 0; mt < 2; ++mt){
        #pragma unroll
        for (int reg = 0; reg < 4; ++reg){
          int e = mt * 16 + row * 4 + reg;
          int j = wu * 16 + col;
          float Gi = acc[0 + mt][reg];
          float Gf = acc[2 + mt][reg];
          float Gg = acc[4 + mt][reg];
          float Go = acc[6 + mt][reg];
          int ci = mt * 4 + reg;
          float ea = fexp2(-Gi);
          float ef = fexp2(-Gf);
          float eb = fexp2(-Gg);
          float eo = fexp2(-Go);
          float t1 = 1.f + ef, t2 = 1.f + ea, t3 = 1.f + eb;
          float p = t2 * t3;
          float num = __builtin_fmaf(cst[ci], p, (1.f - eb) * t1);
          float cn = num * frcp(t1 * p);
          float ed = fexp2(cn * (-LOG2E2_));
          float hn = (1.f - ed) * frcp((1.f + eo) * (1.f + ed));
          cst[ci] = cn;
          hw[e * HPAD + j] = f2bf(hn);
        }
      }
      // one-hot maintenance on the write buffer: clear the slot set 2 steps ago,
      // set the slot step t+1 will read (clear BEFORE set handles repeated degrees).
      if (tid < 32){
        const int* dr = degs + (size_t)eg0 * MAXDEG_;
        if (t >= 1)
          hw[tid * HPAD + H_ + dr[dir ? (MAXDEG_ - t) : (t - 1)]] = 0;
        if (t < MAXDEG_ - 1)
          hw[tid * HPAD + H_ + dr[dir ? (MAXDEG_ - 2 - t) : (t + 1)]] = BF16_ONE;
      }
      __syncthreads();
    }

    // MAXDEG_ even -> final h sits in hl[0]. Store as F16 (exact from bf16).
    for (int i = tid; i < 32 * H_; i += 512){
      int e = i >> 7, k = i & 127;
      int n = ebase + e;
      if (n < N_){
        _Float16 hv = (_Float16)bf2f((u16)hl[0][e * HPAD + k]);
        houts[(size_t)dir * N_ * H_ + (size_t)n * H_ + k] = *(const u16*)&hv;
      }
    }
    if (dir == 0){
      __syncthreads();
      for (int i = tid; i < 2 * 32 * HPAD; i += 512) ((short*)hl)[i] = 0;
      __syncthreads();
      if (tid < 32) hl[0][tid * HPAD + H_ + degs[(size_t)eg0 * MAXDEG_ + (MAXDEG_ - 1)]] = BF16_ONE;
      __syncthreads();
    }
  }
}

// ------------- entity attention: f16 MFMA GEMM (N x 24 = hq(N x 256) @ W^T) -------------
// One wave per 16-node group; B frags (2 op-tiles x 8 ksteps, 64 VGPR) persist per wave.
// C/D layout (verified): col = lane&15 (=op), row = (lane>>4)*4+reg (=node-in-group).
// Softmax over 24 ops = 16-lane shfl_xor reduce across the two op-tiles.
__global__ void eattn_kernel(const u16* __restrict__ hq /* f16 bits, 2 x N x 128 */,
                             const float* __restrict__ elinW, const float* __restrict__ elinb,
                             float* __restrict__ attn /* N,24 */)
{
  int tid = threadIdx.x;
  int lane = tid & 63;
  int col = lane & 15;
  int krow = lane >> 4;   // 0..3

  f16x8 Bf[2][8];
  #pragma unroll
  for (int ot = 0; ot < 2; ++ot){
    int o = ot * 16 + col;
    #pragma unroll
    for (int ks = 0; ks < 8; ++ks){
      f16x8 bv;
      if (o < OPS_){
        const float* src = elinW + (size_t)o * (2 * H_) + ks * 32 + krow * 8;
        #pragma unroll
        for (int jj = 0; jj < 8; ++jj) bv[jj] = (_Float16)src[jj];
      } else {
        #pragma unroll
        for (int jj = 0; jj < 8; ++jj) bv[jj] = (_Float16)0.f;
      }
      Bf[ot][ks] = bv;
    }
  }
  float b0 = elinb[col];
  float b1 = (col < 8) ? elinb[16 + col] : -1e30f;

  int wid = blockIdx.x * 4 + (tid >> 6);
  for (int g = wid; g < N_ / 16; g += 256 * 4){
    f16x8 Af[8];
    #pragma unroll
    for (int ks = 0; ks < 8; ++ks){
      const u16* src = hq + (size_t)(ks >> 2) * N_ * H_
                          + (size_t)(g * 16 + col) * H_ + (ks & 3) * 32 + krow * 8;
      Af[ks] = *(const f16x8*)src;
    }
    f32x4 ac0 = (f32x4){0.f, 0.f, 0.f, 0.f};
    f32x4 ac1 = (f32x4){0.f, 0.f, 0.f, 0.f};
    #pragma unroll
    for (int ks = 0; ks < 8; ++ks){
      ac0 = __builtin_amdgcn_mfma_f32_16x16x32_f16(Af[ks], Bf[0][ks], ac0, 0, 0, 0);
      ac1 = __builtin_amdgcn_mfma_f32_16x16x32_f16(Af[ks], Bf[1][ks], ac1, 0, 0, 0);
    }
    #pragma unroll
    for (int reg = 0; reg < 4; ++reg){
      int node = g * 16 + krow * 4 + reg;
      float v0 = ac0[reg] + b0;
      float v1 = (col < 8) ? (ac1[reg] + b1) : -1e30f;
      float m = fmaxf(v0, v1);
      m = fmaxf(m, __shfl_xor(m, 1));
      m = fmaxf(m, __shfl_xor(m, 2));
      m = fmaxf(m, __shfl_xor(m, 4));
      m = fmaxf(m, __shfl_xor(m, 8));
      float e0 = __expf(v0 - m);
      float e1 = (col < 8) ? __expf(v1 - m) : 0.f;
      float s = e0 + e1;
      s += __shfl_xor(s, 1);
      s += __shfl_xor(s, 2);
      s += __shfl_xor(s, 4);
      s += __shfl_xor(s, 8);
      float inv = frcp(s);
      attn[(size_t)node * OPS_ + col] = e0 * inv;
      if (col < 8) attn[(size_t)node * OPS_ + 16 + col] = e1 * inv;
    }
  }
}

__global__ void csr_scan_kernel(const int* __restrict__ counts, int* __restrict__ rowptr,
                                int* __restrict__ cursor, int* __restrict__ cursor2)
{
  __shared__ int lsum[1024];
  int t = threadIdx.x;
  const int CH = (N_ + 1023) / 1024;   // 49
  int base = t * CH;
  int s = 0;
  for (int i = 0; i < CH; ++i){
    int idx = base + i;
    if (idx < N_) s += counts[idx];
  }
  lsum[t] = s;
  __syncthreads();
  for (int o = 1; o < 1024; o <<= 1){
    int u = (t >= o) ? lsum[t - o] : 0;
    __syncthreads();
    lsum[t] += u;
    __syncthreads();
  }
  int run = lsum[t] - s;
  for (int i = 0; i < CH; ++i){
    int idx = base + i;
    if (idx < N_){
      rowptr[idx] = run;
      cursor[idx] = run;
      cursor2[idx] = run;
      run += counts[idx];
    }
  }
  if (t == 1023) rowptr[N_] = run;
}

__global__ void csr_fill_kernel(const int* __restrict__ rels, const int* __restrict__ theads,
                                const int* __restrict__ ttails, const float* __restrict__ attn,
                                int* __restrict__ cursor, int* __restrict__ cursor2,
                                uint2* __restrict__ ents, uint2* __restrict__ ents2)
{
  int e = blockIdx.x * 256 + threadIdx.x;
  if (e < E_){
    int hh = theads[e], tt = ttails[e], rel = rels[e];
    unsigned wb = __float_as_uint(attn[(size_t)hh * OPS_ + rel]);
    uint2 v1; v1.x = (unsigned)hh | ((unsigned)rel << 16);            v1.y = wb;
    uint2 v2; v2.x = (unsigned)tt | ((unsigned)(rel + OPS_/2) << 16); v2.y = wb;
    ents[atomicAdd(&cursor[tt], 1)] = v1;
    ents[atomicAdd(&cursor[hh], 1)] = v2;
    uint2 w1; w1.x = (unsigned)tt | ((unsigned)rel << 16);            w1.y = wb;
    uint2 w2; w2.x = (unsigned)hh | ((unsigned)(rel + OPS_/2) << 16); w2.y = wb;
    ents2[atomicAdd(&cursor2[hh], 1)] = w1;
    ents2[atomicAdd(&cursor2[tt], 1)] = w2;
  }
}

// ---- t=0 sparse step: u0 is one-hot(heads) -> u1 from out-edges of 32 head nodes ----
__global__ void t0_kernel(const int* __restrict__ heads, const float* __restrict__ query_attn,
                          const int* __restrict__ rowptr, const uint2* __restrict__ ents2,
                          float* __restrict__ u1 /* N x 96 */)
{
  int tid = threadIdx.x;
  if (tid >= RB_) return;
  int r = tid >> 5, b = tid & 31;
  const float* qa = query_attn + ((size_t)(r * T_ + 0) * B_ + b) * (OPS_ + 1);
  int hn = heads[b];
  int rb = r * 32 + b;
  u1[(size_t)hn * RB_ + rb] += qa[OPS_];
  int beg = rowptr[hn], end = rowptr[hn + 1];
  for (int i = beg; i < end; ++i){
    uint2 e = ents2[i];
    int dst = (int)(e.x & 0xFFFFu);
    int rl  = (int)(e.x >> 16);
    u1[(size_t)dst * RB_ + rb] += qa[rl] * __uint_as_float(e.y);
  }
}

// ---- t=1 dense self-term: u2 = qa1_24 (.) u1 (elementwise; replaces memset) ----
__global__ void u2init_kernel(const float* __restrict__ query_attn,
                              const float* __restrict__ u1, float* __restrict__ u2)
{
  __shared__ float q24[RB_];
  int tid = threadIdx.x;
  if (tid < RB_){
    int r = tid >> 5, b = tid & 31;
    q24[tid] = query_attn[((size_t)(r * T_ + 1) * B_ + b) * (OPS_ + 1) + OPS_];
  }
  __syncthreads();
  int idx = blockIdx.x * 256 + tid;
  if (idx < N_ * RB_) u2[idx] = u1[idx] * q24[idx % RB_];
}

// ---- t=1 sparse pushes: u1 nonzero only at {head} U outNbr(head) per column.
__global__ void t1push_kernel(const int* __restrict__ heads, const float* __restrict__ query_attn,
                              const int* __restrict__ rowptr, const uint2* __restrict__ ents2,
                              const float* __restrict__ u1, float* __restrict__ u2)
{
  __shared__ float qa0[OPS_ + 1], qa1[OPS_ + 1];
  int blk = blockIdx.x;   // 0..95
  int r = blk >> 5, b = blk & 31;
  int rb = r * 32 + b;
  int tid = threadIdx.x;  // 64
  if (tid < OPS_ + 1){
    qa0[tid] = query_attn[((size_t)(r * T_ + 0) * B_ + b) * (OPS_ + 1) + tid];
    qa1[tid] = query_attn[((size_t)(r * T_ + 1) * B_ + b) * (OPS_ + 1) + tid];
  }
  __syncthreads();
  int hd = heads[b];
  int beg = rowptr[hd], end = rowptr[hd + 1];
  float q024 = qa0[OPS_];
  for (int i = beg + tid; i < end; i += 64){
    uint2 e1 = ents2[i];
    int s  = (int)(e1.x & 0xFFFFu);
    int r1 = (int)(e1.x >> 16);
    float w1 = __uint_as_float(e1.y);
    atomicAdd(&u2[(size_t)s * RB_ + rb], qa1[r1] * w1 * q024);
    float v1 = qa0[r1] * w1;      // this path's share of u1[s]
    int b2 = rowptr[s], e2e = rowptr[s + 1];
    for (int jj = b2; jj < e2e; ++jj){
      uint2 e2 = ents2[jj];
      int d2 = (int)(e2.x & 0xFFFFu);
      int r2 = (int)(e2.x >> 16);
      atomicAdd(&u2[(size_t)d2 * RB_ + rb], qa1[r2] * __uint_as_float(e2.y) * v1);
    }
  }
}

// ---- batched dense gather (t=2): ONE WAVE per node, halves split 4-edge chunks ----
__global__ __launch_bounds__(256) void gather3_kernel(
    const float* __restrict__ ucur, float* __restrict__ unxt,
    const float* __restrict__ query_attn, int t,
    const int* __restrict__ rowptr, const uint2* __restrict__ ents,
    float* __restrict__ partial /* PSLOTS x 96 */)
{
  __shared__ float qas[3 * B_ * (OPS_ + 1)];  // [r][b][o]
  __shared__ float red[RB_];
  int tid = threadIdx.x;
  for (int i = tid; i < 3 * B_ * (OPS_ + 1); i += 256){
    int r = i / (B_ * (OPS_ + 1));
    int rem = i - r * (B_ * (OPS_ + 1));
    qas[i] = query_attn[(size_t)(r * T_ + t) * B_ * (OPS_ + 1) + rem];
  }
  if (tid < RB_) red[tid] = 0.f;
  __syncthreads();
  int b  = tid & 31;
  int h  = (tid >> 5) & 1;              // half within wave
  int n = blockIdx.x * 4 + (tid >> 6);  // one wave per node; grid*4 == N_
  const float* q0 = &qas[0 * 800 + b * (OPS_ + 1)];
  const float* q1 = &qas[1 * 800 + b * (OPS_ + 1)];
  const float* q2 = &qas[2 * 800 + b * (OPS_ + 1)];
  size_t nb = (size_t)n * RB_;
  float a0 = 0.f, a1 = 0.f, a2 = 0.f;
  if (h == 0){
    a0 = ucur[nb + b]      * q0[OPS_];
    a1 = ucur[nb + 32 + b] * q1[OPS_];
    a2 = ucur[nb + 64 + b] * q2[OPS_];
  }
  int beg = rowptr[n], end = rowptr[n + 1];
  int cnt = end - beg;
  int nq = cnt >> 2;                 // full 4-edge chunks
  for (int c = h; c < nq; c += 2){
    int i0 = beg + 4 * c;
    uint2 e0 = ents[i0 + 0];
    uint2 e1 = ents[i0 + 1];
    uint2 e2 = ents[i0 + 2];
    uint2 e3 = ents[i0 + 3];
    size_t s0 = (size_t)(e0.x & 0xFFFFu) * RB_;
    size_t s1 = (size_t)(e1.x & 0xFFFFu) * RB_;
    size_t s2 = (size_t)(e2.x & 0xFFFFu) * RB_;
    size_t s3 = (size_t)(e3.x & 0xFFFFu) * RB_;
    float u00 = ucur[s0 + b], u01 = ucur[s0 + 32 + b], u02 = ucur[s0 + 64 + b];
    float u10 = ucur[s1 + b], u11 = ucur[s1 + 32 + b], u12 = ucur[s1 + 64 + b];
    float u20 = ucur[s2 + b], u21 = ucur[s2 + 32 + b], u22 = ucur[s2 + 64 + b];
    float u30 = ucur[s3 + b], u31 = ucur[s3 + 32 + b], u32 = ucur[s3 + 64 + b];
    int r0 = (int)(e0.x >> 16), r1 = (int)(e1.x >> 16);
    int r2 = (int)(e2.x >> 16), r3 = (int)(e3.x >> 16);
    float w0 = __uint_as_float(e0.y), w1 = __uint_as_float(e1.y);
    float w2 = __uint_as_float(e2.y), w3 = __uint_as_float(e3.y);
    a0 += q0[r0]*w0*u00 + q0[r1]*w1*u10 + q0[r2]*w2*u20 + q0[r3]*w3*u30;
    a1 += q1[r0]*w0*u01 + q1[r1]*w1*u11 + q1[r2]*w2*u21 + q1[r3]*w3*u31;
    a2 += q2[r0]*w0*u02 + q2[r1]*w1*u12 + q2[r2]*w2*u22 + q2[r3]*w3*u32;
  }
  if (h == 1){
    for (int i = beg + 4 * nq; i < end; ++i){
      uint2 e0 = ents[i];
      size_t s0 = (size_t)(e0.x & 0xFFFFu) * RB_;
      int r0 = (int)(e0.x >> 16);
      float w0 = __uint_as_float(e0.y);
      a0 += q0[r0] * w0 * ucur[s0 + b];
      a1 += q1[r0] * w0 * ucur[s0 + 32 + b];
      a2 += q2[r0] * w0 * ucur[s0 + 64 + b];
    }
  }
  a0 += __shfl_xor(a0, 32);
  a1 += __shfl_xor(a1, 32);
  a2 += __shfl_xor(a2, 32);
  if (h == 0){
    unxt[nb + b]      = a0;
    unxt[nb + 32 + b] = a1;
    unxt[nb + 64 + b] = a2;
    atomicAdd(&red[b], a0);
    atomicAdd(&red[32 + b], a1);
    atomicAdd(&red[64 + b], a2);
  }
  __syncthreads();
  if (tid < RB_)
    atomicAdd(&partial[(blockIdx.x & (PSLOTS - 1)) * RB_ + tid], red[tid]);
}

// ---- finalize + transpose: out[b][n] = sum_r u[n][r*32+b] / rowsum_r ----
__global__ void fintrans_kernel(const float* __restrict__ u, const float* __restrict__ partial,
                                float* __restrict__ out)
{
  __shared__ float sinv[RB_];
  __shared__ float t[B_][72];
  int tid = threadIdx.x;   // 256
  if (tid < RB_){
    float s = 0.f;
    #pragma unroll 8
    for (int k = 0; k < PSLOTS; ++k) s += partial[k * RB_ + tid];
    sinv[tid] = frcp(fmaxf(1e-20f, s));
  }
  __syncthreads();
  int n0 = blockIdx.x * 64;
  for (int i = tid; i < 64 * B_; i += 256){
    int nl = i >> 5, b = i & 31;
    int n = n0 + nl;
    float v = 0.f;
    if (n < N_){
      size_t nb = (size_t)n * RB_;
      v = u[nb + b] * sinv[b] + u[nb + 32 + b] * sinv[32 + b] + u[nb + 64 + b] * sinv[64 + b];
    }
    t[b][nl] = v;
  }
  __syncthreads();
  for (int i = tid; i < 64 * B_; i += 256){
    int b = i >> 6, nl = i & 63;
    int n = n0 + nl;
    if (n < N_) out[(size_t)b * N_ + n] = t[b][nl];
  }
}

extern "C" void kernel_launch(void* const* d_in, const int* in_sizes, int n_in,
                              void* d_out, int out_size, void* d_ws, size_t ws_size,
                              hipStream_t stream)
{
  const int*   queries = (const int*)d_in[0];
  const int*   heads   = (const int*)d_in[1];
  const int*   rels    = (const int*)d_in[2];
  const int*   t_heads = (const int*)d_in[3];
  const int*   t_tails = (const int*)d_in[4];
  const int*   edeg    = (const int*)d_in[5];
  const float* qemb    = (const float*)d_in[6];
  const float* eemb    = (const float*)d_in[7];
  const float* qWih    = (const float*)d_in[8];
  const float* qWhh    = (const float*)d_in[9];
  const float* qbih    = (const float*)d_in[10];
  const float* qbhh    = (const float*)d_in[11];
  const float* eWih    = (const float*)d_in[12];
  const float* eWhh    = (const float*)d_in[13];
  const float* ebih    = (const float*)d_in[14];
  const float* ebhh    = (const float*)d_in[15];
  const float* qlinW   = (const float*)d_in[16];
  const float* qlinb   = (const float*)d_in[17];
  const float* elinW   = (const float*)d_in[18];
  const float* elinb   = (const float*)d_in[19];
  float* out = (float*)d_out;

  char* ws = (char*)d_ws;
  size_t off = 0;
  auto alloc = [&](size_t bytes){ void* p = ws + off; off += (bytes + 255) & ~(size_t)255; return p; };
  // bigA (25.6 MB): houts during [elstm, eattn]; after eattn dead ->
  //   ents (6.4 MB, csr_fill) at +0, u2 (19.2 MB) at +6.4 MB.
  char*  bigA  = (char*)alloc((size_t)2 * N_ * H_ * 2);               // 25,600,000
  u16*   houts = (u16*)bigA;                                          // f16 bits
  uint2* ents  = (uint2*)bigA;                                        // in-CSR, 6.4 MB
  float* u2    = (float*)(bigA + (size_t)2 * E_ * 8);                 // 19.2 MB
  // bigB (19.2 MB): attn (4.8 MB) during [eattn, csr_fill]; then u1; then u3.
  char*  bigB  = (char*)alloc((size_t)N_ * RB_ * 4);
  float* attn  = (float*)bigB;
  float* u1    = (float*)bigB;
  float* u3    = (float*)bigB;
  uint2* ents2      = (uint2*)alloc((size_t)2 * E_ * 8);              // out-CSR, 6.4 MB
  float* query_attn = (float*)alloc((size_t)R_ * T_ * B_ * (OPS_ + 1) * 4);
  u16*   wtile      = (u16*)  alloc((size_t)2 * 32 * 4 * 64 * 8 * 2);
  u16*   wonehot    = (u16*)  alloc((size_t)2 * 32 * 64 * 8 * 2);
  int*   counts     = (int*)  alloc((size_t)(N_ + 1) * 4);
  int*   rowptr     = (int*)  alloc((size_t)(N_ + 1) * 4);
  int*   cursor     = (int*)  alloc((size_t)(N_ + 1) * 4);
  int*   cursor2    = (int*)  alloc((size_t)(N_ + 1) * 4);
  float* sumsP      = (float*)alloc((size_t)PSLOTS * RB_ * 4);        // t2 partials only
  // total ~52 MB

  hipMemsetAsync(sumsP, 0, (size_t)PSLOTS * RB_ * 4, stream);
  hipMemsetAsync(counts, 0, (size_t)(N_ + 1) * 4, stream);

  // fused qattn | wbuild | csr_count (independent; were serialized on the stream)
  front_kernel<<<QB_ + WB_ + CB_, 256, 0, stream>>>(
      queries, qemb, qWih, qWhh, qbih, qbhh, qlinW, qlinb, query_attn,
      eWhh, eemb, eWih, ebih, ebhh, wtile, wonehot,
      t_heads, t_tails, counts);
  csr_scan_kernel<<<1, 1024, 0, stream>>>(counts, rowptr, cursor, cursor2);
  elstm_kernel<<<(N_ + 31) / 32, 512, 0, stream>>>(edeg, wtile, wonehot, houts);
  eattn_kernel<<<256, 256, 0, stream>>>(houts, elinW, elinb, attn);
  // houts dead -> ents may take bigA[0:6.4M]; attn still live (read by csr_fill):
  csr_fill_kernel<<<(E_ + 255) / 256, 256, 0, stream>>>(rels, t_heads, t_tails, attn,
                                                        cursor, cursor2, ents, ents2);
  // attn dead -> u1 takes bigB
  hipMemsetAsync(u1, 0, (size_t)N_ * RB_ * 4, stream);
  t0_kernel<<<1, 128, 0, stream>>>(heads, query_attn, rowptr, ents2, u1);
  // t=1: dense self-term + sparse 2-hop pushes (replaces a full dense gather)
  u2init_kernel<<<(N_ * RB_ + 255) / 256, 256, 0, stream>>>(query_attn, u1, u2);
  t1push_kernel<<<RB_, 64, 0, stream>>>(heads, query_attn, rowptr, ents2, u1, u2);
  // t=2: dense gather (u1 dead; u3 overwrites bigB)
  gather3_kernel<<<N_ / 4, 256, 0, stream>>>(u2, u3, query_attn, 2, rowptr, ents, sumsP);
  fintrans_kernel<<<(N_ + 63) / 64, 256, 0, stream>>>(u3, sumsP, out);
}

// Round 7
// 710.109 us; speedup vs baseline: 1.4011x; 1.1025x over previous
//
#include <hip/hip_runtime.h>

#define R_ 3
#define T_ 3
#define N_ 50000
#define OPS_ 24
#define E_ 400000
#define B_ 32
#define MAXDEG_ 8
#define QD_ 128
#define ED_ 128
#define H_ 128
#define G4_ (4*H_)   /* 512 */
#define HPAD 168     /* padded LDS h-row (bf16): 128 h + 25 one-hot + pad, 336 B */
#define PSLOTS 64    /* partial row-sum slots */
#define RB_ 96       /* 3 rounds x 32 batch */

/* front fat-kernel block ranges */
#define QB_ (R_ * B_)                          /* 96  qattn blocks  */
#define WB_ ((2*32*5*64*8 + 255) / 256)        /* 640 wbuild blocks */
#define CB_ ((E_ + 255) / 256)                 /* 1563 csr_count    */
#define SCANBLK_ ((N_ + 31) / 32)              /* 1563: scan rides in elstm grid */

typedef unsigned short u16;
typedef unsigned char u8;
typedef __attribute__((ext_vector_type(8))) short bf16x8;     // 8 bf16 = 4 VGPRs
typedef __attribute__((ext_vector_type(8))) _Float16 f16x8;   // 8 f16  = 4 VGPRs
typedef __attribute__((ext_vector_type(4))) float f32x4;

#define BF16_ONE ((short)0x3F80)
#define LOG2E_  1.44269504f
#define LOG2E2_ 2.88539008f

__device__ __forceinline__ short f2bf(float f){
  union { float f; unsigned u; } v; v.f = f;
  unsigned r = v.u + 0x7fffu + ((v.u >> 16) & 1u);
  return (short)(r >> 16);
}
__device__ __forceinline__ float bf2f(u16 u){
  union { unsigned u; float f; } v; v.u = ((unsigned)u) << 16; return v.f;
}
__device__ __forceinline__ float frcp(float x){ return __builtin_amdgcn_rcpf(x); }
__device__ __forceinline__ float fsig(float x){ return frcp(1.0f + __expf(-x)); }
// tanh(x) = 2*sigmoid(2x) - 1
__device__ __forceinline__ float ftanh(float x){
  return __builtin_fmaf(2.0f, fsig(2.0f * x), -1.0f);
}
// 2^x via v_exp_f32 (guarded fallback keeps semantics if builtin missing)
__device__ __forceinline__ float fexp2(float x){
#if __has_builtin(__builtin_amdgcn_exp2f)
  return __builtin_amdgcn_exp2f(x);
#else
  return __expf(x * 0.6931471806f);
#endif
}

// ---------------- query BiLSTM + attention: one virtual block per (r,b) ----------------
__device__ void qattn_body(int bid, const int* __restrict__ queries, const float* __restrict__ qemb,
    const float* __restrict__ qWih, const float* __restrict__ qWhh,
    const float* __restrict__ qbih, const float* __restrict__ qbhh,
    const float* __restrict__ qlinW, const float* __restrict__ qlinb,
    float* __restrict__ query_attn /* R,T,B,25 */)
{
  int r = bid / B_;
  int b = bid % B_;
  int tid = threadIdx.x;   // 256
  __shared__ float x[QD_];
  __shared__ float gx[G4_];
  __shared__ float h[H_], c[H_];
  __shared__ float gtmp[G4_];
  __shared__ float hh[2][T_][H_];
  __shared__ float lg[OPS_ + 1];

  int q = queries[b];
  if (tid < QD_) x[tid] = qemb[q * QD_ + tid];
  __syncthreads();

  for (int dir = 0; dir < 2; ++dir){
    const float* Wih = qWih + (size_t)(r * 2 + dir) * G4_ * QD_;
    const float* Whh = qWhh + (size_t)(r * 2 + dir) * G4_ * H_;
    const float* bih = qbih + (r * 2 + dir) * G4_;
    const float* bhh = qbhh + (r * 2 + dir) * G4_;
    for (int j = tid; j < G4_; j += 256){
      const float4* wr = (const float4*)(Wih + (size_t)j * QD_);
      float s = bih[j] + bhh[j];
      for (int k = 0; k < QD_ / 4; ++k){
        float4 wv = wr[k];
        s += wv.x * x[4*k] + wv.y * x[4*k+1] + wv.z * x[4*k+2] + wv.w * x[4*k+3];
      }
      gx[j] = s;
    }
    if (tid < H_){ h[tid] = 0.f; c[tid] = 0.f; }
    __syncthreads();
    for (int t = 0; t < T_; ++t){
      for (int j = tid; j < G4_; j += 256){
        const float4* wr = (const float4*)(Whh + (size_t)j * H_);
        float s = 0.f;
        for (int k = 0; k < H_ / 4; ++k){
          float4 wv = wr[k];
          s += wv.x * h[4*k] + wv.y * h[4*k+1] + wv.z * h[4*k+2] + wv.w * h[4*k+3];
        }
        gtmp[j] = gx[j] + s;
      }
      __syncthreads();
      if (tid < H_){
        float gi = gtmp[tid], gf = gtmp[tid + H_], gg = gtmp[tid + 2*H_], go = gtmp[tid + 3*H_];
        float cn = fsig(gf) * c[tid] + fsig(gi) * ftanh(gg);
        float hn = fsig(go) * ftanh(cn);
        c[tid] = cn; h[tid] = hn;
        hh[dir][t][tid] = hn;
      }
      __syncthreads();
    }
  }

  for (int t = 0; t < T_; ++t){
    if (tid < OPS_ + 1){
      const float* wr = qlinW + tid * (2 * H_);
      float s = qlinb[tid];
      for (int k = 0; k < H_; ++k) s += wr[k] * hh[0][t][k];
      for (int k = 0; k < H_; ++k) s += wr[H_ + k] * hh[1][T_ - 1 - t][k];
      lg[tid] = s;
    }
    __syncthreads();
    if (tid == 0){
      float m = -1e30f;
      for (int o = 0; o < OPS_ + 1; ++o) m = fmaxf(m, lg[o]);
      float sum = 0.f;
      for (int o = 0; o < OPS_ + 1; ++o){ float e = __expf(lg[o] - m); lg[o] = e; sum += e; }
      float inv = frcp(sum);
      for (int o = 0; o < OPS_ + 1; ++o) lg[o] *= inv;
    }
    __syncthreads();
    if (tid < OPS_ + 1) query_attn[((size_t)(r * T_ + t) * B_ + b) * (OPS_ + 1) + tid] = lg[tid];
    __syncthreads();
  }
}

// ---- build B-operand buffers in MFMA-fragment order (eproj folded in) ----
// Gate rows are PRE-SCALED by log2(e) (gates i,f,o) / 2*log2(e) (gate g) so the
// LSTM activation can use raw v_exp_f32 (=2^x) without per-exp ln2 muls.
__device__ void wbuild_body(int bid, const float* __restrict__ eWhh,
                            const float* __restrict__ eemb, const float* __restrict__ eWih,
                            const float* __restrict__ ebih, const float* __restrict__ ebhh,
                            u16* __restrict__ wtile, u16* __restrict__ wonehot)
{
  int idx = bid * 256 + threadIdx.x;    // 2*32*5*64*8 = 163840
  if (idx >= 2 * 32 * 5 * 64 * 8) return;
  int jj = idx & 7;
  int lane = (idx >> 3) & 63;
  int kc = (idx >> 9) % 5;
  int gtile = (idx / (8 * 64 * 5)) & 31;
  int dir = idx / (8 * 64 * 5 * 32);
  int row = lane >> 4, col = lane & 15;
  int j = gtile * 16 + col;
  float sc = ((gtile >> 3) == 2) ? LOG2E2_ : LOG2E_;   // gate g rows get 2*log2e
  if (kc < 4){
    int k = kc * 32 + row * 8 + jj;
    float v = eWhh[((size_t)dir * G4_ + j) * H_ + k] * sc;
    wtile[((((size_t)dir * 32 + gtile) * 4 + kc) * 64 + lane) * 8 + jj] = (u16)f2bf(v);
  } else {
    int vdeg = row * 8 + jj;   // 0..31
    float v = 0.f;
    if (vdeg <= OPS_){
      const float4* wr = (const float4*)(eWih + (size_t)(dir * G4_ + j) * ED_);
      const float4* er = (const float4*)(eemb + (size_t)vdeg * ED_);
      float s = ebih[dir * G4_ + j] + ebhh[dir * G4_ + j];
      for (int k = 0; k < ED_ / 4; ++k){
        float4 wv = wr[k], ev = er[k];
        s += wv.x * ev.x + wv.y * ev.y + wv.z * ev.z + wv.w * ev.w;
      }
      v = s * sc;
    }
    wonehot[(((size_t)dir * 32 + gtile) * 64 + lane) * 8 + jj] = (u16)f2bf(v);
  }
}

__device__ void csr_count_body(int bid, const int* __restrict__ theads,
                               const int* __restrict__ ttails, int* __restrict__ counts)
{
  int e = bid * 256 + threadIdx.x;
  if (e < E_){
    atomicAdd(&counts[ttails[e]], 1);
    atomicAdd(&counts[theads[e]], 1);
  }
}

// ---- front fat-kernel: qattn | wbuild | csr_count are mutually independent but were
// serialized on the stream (qattn alone uses 96/256 CUs). One launch, block-range split.
__global__ __launch_bounds__(256) void front_kernel(
    const int* queries, const float* qemb,
    const float* qWih, const float* qWhh, const float* qbih, const float* qbhh,
    const float* qlinW, const float* qlinb, float* query_attn,
    const float* eWhh, const float* eemb, const float* eWih,
    const float* ebih, const float* ebhh, u16* wtile, u16* wonehot,
    const int* theads, const int* ttails, int* counts)
{
  int bid = blockIdx.x;
  if (bid < QB_){
    qattn_body(bid, queries, qemb, qWih, qWhh, qbih, qbhh, qlinW, qlinb, query_attn);
  } else if (bid < QB_ + WB_){
    wbuild_body(bid - QB_, eWhh, eemb, eWih, ebih, ebhh, wtile, wonehot);
  } else {
    csr_count_body(bid - QB_ - WB_, theads, ttails, counts);
  }
}

// ---- exclusive-scan body (512 threads): rides as block SCANBLK_ of the elstm grid,
// so the former 1-block serial csr_scan launch overlaps the 1563 elstm blocks.
__device__ void scan_body(const int* __restrict__ counts, int* __restrict__ rowptr,
                          int* __restrict__ cursor, int* __restrict__ cursor2)
{
  __shared__ int lsum[512];
  int t = threadIdx.x;
  const int CH = (N_ + 511) / 512;   // 98
  int base = t * CH;
  int s = 0;
  for (int i = 0; i < CH; ++i){
    int idx = base + i;
    if (idx < N_) s += counts[idx];
  }
  lsum[t] = s;
  __syncthreads();
  for (int o = 1; o < 512; o <<= 1){
    int u = (t >= o) ? lsum[t - o] : 0;
    __syncthreads();
    lsum[t] += u;
    __syncthreads();
  }
  int run = lsum[t] - s;
  for (int i = 0; i < CH; ++i){
    int idx = base + i;
    if (idx < N_){
      rowptr[idx] = run;
      cursor[idx] = run;
      cursor2[idx] = run;
      run += counts[idx];
    }
  }
  if (t == 511) rowptr[N_] = run;
}

// ------ entity BiLSTM: 512 threads / 8 waves / 32 entities per block (r6-exact) ------
// + block SCANBLK_ runs the CSR exclusive scan concurrently.
// launch_bounds(512,4): cap 128 regs -> 60 VGPR + 32 AGPR = 92 combined, no spill.
// Occupancy ladder is BINARY (r4/r5): <=64 combined -> 8 waves/SIMD (infeasible,
// demand 92), <=128 -> 4 waves/SIMD. 80% issue-busy (54 VALU + 26 MFMA).
__global__ __launch_bounds__(512, 4) void elstm_kernel(
    const int* __restrict__ degs,
    const u16* __restrict__ wtile, const u16* __restrict__ wonehot,
    u16* __restrict__ houts /* 2,N,128 f16 */,
    const int* __restrict__ counts, int* __restrict__ rowptr,
    int* __restrict__ cursor, int* __restrict__ cursor2)
{
  if (blockIdx.x == SCANBLK_){ scan_body(counts, rowptr, cursor, cursor2); return; }

  int tid = threadIdx.x;
  int lane = tid & 63;
  int w = tid >> 6;          // wave 0..7
  int wu = __builtin_amdgcn_readfirstlane(w);   // provably wave-uniform
  int row = lane >> 4, col = lane & 15;
  int ebase = blockIdx.x * 32;

  __shared__ __align__(16) short hl[2][32 * HPAD];   // 2 x 10.5 KB ping-pong

  int eg0 = ebase + tid; if (eg0 >= N_) eg0 = N_ - 1;   // valid for tid<32 use

  for (int i = tid; i < 2 * 32 * HPAD; i += 512) ((short*)hl)[i] = 0;
  __syncthreads();
  if (tid < 32) hl[0][tid * HPAD + H_ + degs[(size_t)eg0 * MAXDEG_ + 0]] = BF16_ONE;
  __syncthreads();

  for (int dir = 0; dir < 2; ++dir){
    const u16* Wt  = wtile   + (size_t)dir * 32 * 4 * 64 * 8;
    const u16* Woh = wonehot + (size_t)dir * 32 * 64 * 8;
    // per-gate scalar bases (gtile = g*8 + wu)
    const u16* W0 = Wt + (size_t)((0 * 8 + wu) * 4 * 64) * 8;
    const u16* W1 = Wt + (size_t)((1 * 8 + wu) * 4 * 64) * 8;
    const u16* W2 = Wt + (size_t)((2 * 8 + wu) * 4 * 64) * 8;
    const u16* W3 = Wt + (size_t)((3 * 8 + wu) * 4 * 64) * 8;
    const u16* O0 = Woh + (size_t)((0 * 8 + wu) * 64) * 8;
    const u16* O1 = Woh + (size_t)((1 * 8 + wu) * 64) * 8;
    const u16* O2 = Woh + (size_t)((2 * 8 + wu) * 64) * 8;
    const u16* O3 = Woh + (size_t)((3 * 8 + wu) * 64) * 8;
    float cst[8];
    #pragma unroll
    for (int i = 0; i < 8; ++i) cst[i] = 0.f;

    for (int t = 0; t < MAXDEG_; ++t){
      const short* hb = hl[t & 1];          // holds h_t (+ one-hot for step t)
      short*       hw = hl[(t + 1) & 1];    // receives h_{t+1}
      f32x4 acc[8];
      #pragma unroll
      for (int i = 0; i < 8; ++i) acc[i] = (f32x4){0.f, 0.f, 0.f, 0.f};

      #pragma unroll 2
      for (int kc = 0; kc < 4; ++kc){
        bf16x8 af0 = *(const bf16x8*)&hb[(col) * HPAD + kc * 32 + row * 8];
        bf16x8 af1 = *(const bf16x8*)&hb[(16 + col) * HPAD + kc * 32 + row * 8];
        int lo = (kc * 64 + lane) * 8;
        bf16x8 b0 = *(const bf16x8*)(W0 + lo);
        bf16x8 b1 = *(const bf16x8*)(W1 + lo);
        bf16x8 b2 = *(const bf16x8*)(W2 + lo);
        bf16x8 b3 = *(const bf16x8*)(W3 + lo);
        acc[0] = __builtin_amdgcn_mfma_f32_16x16x32_bf16(af0, b0, acc[0], 0, 0, 0);
        acc[1] = __builtin_amdgcn_mfma_f32_16x16x32_bf16(af1, b0, acc[1], 0, 0, 0);
        acc[2] = __builtin_amdgcn_mfma_f32_16x16x32_bf16(af0, b1, acc[2], 0, 0, 0);
        acc[3] = __builtin_amdgcn_mfma_f32_16x16x32_bf16(af1, b1, acc[3], 0, 0, 0);
        acc[4] = __builtin_amdgcn_mfma_f32_16x16x32_bf16(af0, b2, acc[4], 0, 0, 0);
        acc[5] = __builtin_amdgcn_mfma_f32_16x16x32_bf16(af1, b2, acc[5], 0, 0, 0);
        acc[6] = __builtin_amdgcn_mfma_f32_16x16x32_bf16(af0, b3, acc[6], 0, 0, 0);
        acc[7] = __builtin_amdgcn_mfma_f32_16x16x32_bf16(af1, b3, acc[7], 0, 0, 0);
      }
      {
        bf16x8 af0 = *(const bf16x8*)&hb[(col) * HPAD + H_ + row * 8];
        bf16x8 af1 = *(const bf16x8*)&hb[(16 + col) * HPAD + H_ + row * 8];
        int lo = lane * 8;
        bf16x8 b0 = *(const bf16x8*)(O0 + lo);
        bf16x8 b1 = *(const bf16x8*)(O1 + lo);
        bf16x8 b2 = *(const bf16x8*)(O2 + lo);
        bf16x8 b3 = *(const bf16x8*)(O3 + lo);
        acc[0] = __builtin_amdgcn_mfma_f32_16x16x32_bf16(af0, b0, acc[0], 0, 0, 0);
        acc[1] = __builtin_amdgcn_mfma_f32_16x16x32_bf16(af1, b0, acc[1], 0, 0, 0);
        acc[2] = __builtin_amdgcn_mfma_f32_16x16x32_bf16(af0, b1, acc[2], 0, 0, 0);
        acc[3] = __builtin_amdgcn_mfma_f32_16x16x32_bf16(af1, b1, acc[3], 0, 0, 0);
        acc[4] = __builtin_amdgcn_mfma_f32_16x16x32_bf16(af0, b2, acc[4], 0, 0, 0);
        acc[5] = __builtin_amdgcn_mfma_f32_16x16x32_bf16(af1, b2, acc[5], 0, 0, 0);
        acc[6] = __builtin_amdgcn_mfma_f32_16x16x32_bf16(af0, b3, acc[6], 0, 0, 0);
        acc[7] = __builtin_amdgcn_mfma_f32_16x16x32_bf16(af1, b3, acc[7], 0, 0, 0);
      }

      // activation (gates pre-scaled by log2e / 2log2e):
      // cn = [cst*(1+ea)(1+eb) + (1-eb)(1+ef)] / [(1+ef)(1+ea)(1+eb)]
      // hn = (1-ed) / [(1+eo)(1+ed)],  ed = 2^(-2*log2e*cn)
      #pragma unroll
      for (int mt = 0; mt < 2; ++mt){
        #pragma unroll
        for (int reg = 0; reg < 4; ++reg){
          int e = mt * 16 + row * 4 + reg;
          int j = wu * 16 + col;
          float Gi = acc[0 + mt][reg];
          float Gf = acc[2 + mt][reg];
          float Gg = acc[4 + mt][reg];
          float Go = acc[6 + mt][reg];
          int ci = mt * 4 + reg;
          float ea = fexp2(-Gi);
          float ef = fexp2(-Gf);
          float eb = fexp2(-Gg);
          float eo = fexp2(-Go);
          float t1 = 1.f + ef, t2 = 1.f + ea, t3 = 1.f + eb;
          float p = t2 * t3;
          float num = __builtin_fmaf(cst[ci], p, (1.f - eb) * t1);
          float cn = num * frcp(t1 * p);
          float ed = fexp2(cn * (-LOG2E2_));
          float hn = (1.f - ed) * frcp((1.f + eo) * (1.f + ed));
          cst[ci] = cn;
          hw[e * HPAD + j] = f2bf(hn);
        }
      }
      // one-hot maintenance on the write buffer: clear the slot set 2 steps ago,
      // set the slot step t+1 will read (clear BEFORE set handles repeated degrees).
      if (tid < 32){
        const int* dr = degs + (size_t)eg0 * MAXDEG_;
        if (t >= 1)
          hw[tid * HPAD + H_ + dr[dir ? (MAXDEG_ - t) : (t - 1)]] = 0;
        if (t < MAXDEG_ - 1)
          hw[tid * HPAD + H_ + dr[dir ? (MAXDEG_ - 2 - t) : (t + 1)]] = BF16_ONE;
      }
      __syncthreads();
    }

    // MAXDEG_ even -> final h sits in hl[0]. Store as F16 (exact from bf16).
    for (int i = tid; i < 32 * H_; i += 512){
      int e = i >> 7, k = i & 127;
      int n = ebase + e;
      if (n < N_){
        _Float16 hv = (_Float16)bf2f((u16)hl[0][e * HPAD + k]);
        houts[(size_t)dir * N_ * H_ + (size_t)n * H_ + k] = *(const u16*)&hv;
      }
    }
    if (dir == 0){
      __syncthreads();
      for (int i = tid; i < 2 * 32 * HPAD; i += 512) ((short*)hl)[i] = 0;
      __syncthreads();
      if (tid < 32) hl[0][tid * HPAD + H_ + degs[(size_t)eg0 * MAXDEG_ + (MAXDEG_ - 1)]] = BF16_ONE;
      __syncthreads();
    }
  }
}

// ------------- entity attention: f16 MFMA GEMM (N x 24 = hq(N x 256) @ W^T) -------------
__global__ void eattn_kernel(const u16* __restrict__ hq /* f16 bits, 2 x N x 128 */,
                             const float* __restrict__ elinW, const float* __restrict__ elinb,
                             float* __restrict__ attn /* N,24 */)
{
  int tid = threadIdx.x;
  int lane = tid & 63;
  int col = lane & 15;
  int krow = lane >> 4;   // 0..3

  f16x8 Bf[2][8];
  #pragma unroll
  for (int ot = 0; ot < 2; ++ot){
    int o = ot * 16 + col;
    #pragma unroll
    for (int ks = 0; ks < 8; ++ks){
      f16x8 bv;
      if (o < OPS_){
        const float* src = elinW + (size_t)o * (2 * H_) + ks * 32 + krow * 8;
        #pragma unroll
        for (int jj = 0; jj < 8; ++jj) bv[jj] = (_Float16)src[jj];
      } else {
        #pragma unroll
        for (int jj = 0; jj < 8; ++jj) bv[jj] = (_Float16)0.f;
      }
      Bf[ot][ks] = bv;
    }
  }
  float b0 = elinb[col];
  float b1 = (col < 8) ? elinb[16 + col] : -1e30f;

  int wid = blockIdx.x * 4 + (tid >> 6);
  for (int g = wid; g < N_ / 16; g += 256 * 4){
    f16x8 Af[8];
    #pragma unroll
    for (int ks = 0; ks < 8; ++ks){
      const u16* src = hq + (size_t)(ks >> 2) * N_ * H_
                          + (size_t)(g * 16 + col) * H_ + (ks & 3) * 32 + krow * 8;
      Af[ks] = *(const f16x8*)src;
    }
    f32x4 ac0 = (f32x4){0.f, 0.f, 0.f, 0.f};
    f32x4 ac1 = (f32x4){0.f, 0.f, 0.f, 0.f};
    #pragma unroll
    for (int ks = 0; ks < 8; ++ks){
      ac0 = __builtin_amdgcn_mfma_f32_16x16x32_f16(Af[ks], Bf[0][ks], ac0, 0, 0, 0);
      ac1 = __builtin_amdgcn_mfma_f32_16x16x32_f16(Af[ks], Bf[1][ks], ac1, 0, 0, 0);
    }
    #pragma unroll
    for (int reg = 0; reg < 4; ++reg){
      int node = g * 16 + krow * 4 + reg;
      float v0 = ac0[reg] + b0;
      float v1 = (col < 8) ? (ac1[reg] + b1) : -1e30f;
      float m = fmaxf(v0, v1);
      m = fmaxf(m, __shfl_xor(m, 1));
      m = fmaxf(m, __shfl_xor(m, 2));
      m = fmaxf(m, __shfl_xor(m, 4));
      m = fmaxf(m, __shfl_xor(m, 8));
      float e0 = __expf(v0 - m);
      float e1 = (col < 8) ? __expf(v1 - m) : 0.f;
      float s = e0 + e1;
      s += __shfl_xor(s, 1);
      s += __shfl_xor(s, 2);
      s += __shfl_xor(s, 4);
      s += __shfl_xor(s, 8);
      float inv = frcp(s);
      attn[(size_t)node * OPS_ + col] = e0 * inv;
      if (col < 8) attn[(size_t)node * OPS_ + 16 + col] = e1 * inv;
    }
  }
}

__global__ void csr_fill_kernel(const int* __restrict__ rels, const int* __restrict__ theads,
                                const int* __restrict__ ttails, const float* __restrict__ attn,
                                int* __restrict__ cursor, int* __restrict__ cursor2,
                                uint2* __restrict__ ents, uint2* __restrict__ ents2)
{
  int e = blockIdx.x * 256 + threadIdx.x;
  if (e < E_){
    int hh = theads[e], tt = ttails[e], rel = rels[e];
    unsigned wb = __float_as_uint(attn[(size_t)hh * OPS_ + rel]);
    uint2 v1; v1.x = (unsigned)hh | ((unsigned)rel << 16);            v1.y = wb;
    uint2 v2; v2.x = (unsigned)tt | ((unsigned)(rel + OPS_/2) << 16); v2.y = wb;
    ents[atomicAdd(&cursor[tt], 1)] = v1;
    ents[atomicAdd(&cursor[hh], 1)] = v2;
    uint2 w1; w1.x = (unsigned)tt | ((unsigned)rel << 16);            w1.y = wb;
    uint2 w2; w2.x = (unsigned)hh | ((unsigned)(rel + OPS_/2) << 16); w2.y = wb;
    ents2[atomicAdd(&cursor2[hh], 1)] = w1;
    ents2[atomicAdd(&cursor2[tt], 1)] = w2;
  }
}

// ---- fused sparse t=0 + t=1 (normalization telescopes -> everything linear):
// u2[head]  += qa1[24]*qa0[24]                                   (self o self)
// u2[s]     += w1*(qa1[24]*qa0[r1] + qa1[r1]*qa0[24])  per e1(head->s)
// u2[d]     += qa1[r2]*w2 * qa0[r1]*w1                 per e1,e2(s->d)
// Replaces t0_kernel + dense u2init (4.8M elems) + t1push. Also marks the
// nonzero-row mask (only r==0 blocks; reachability is r-independent).
__global__ void t01_kernel(const int* __restrict__ heads, const float* __restrict__ query_attn,
                           const int* __restrict__ rowptr, const uint2* __restrict__ ents2,
                           float* __restrict__ u2, u8* __restrict__ mask)
{
  __shared__ float qa0[OPS_ + 1], qa1[OPS_ + 1];
  int blk = blockIdx.x;   // 0..95
  int r = blk >> 5, b = blk & 31;
  int rb = r * 32 + b;
  int tid = threadIdx.x;  // 64
  if (tid < OPS_ + 1){
    qa0[tid] = query_attn[((size_t)(r * T_ + 0) * B_ + b) * (OPS_ + 1) + tid];
    qa1[tid] = query_attn[((size_t)(r * T_ + 1) * B_ + b) * (OPS_ + 1) + tid];
  }
  __syncthreads();
  int hd = heads[b];
  int beg = rowptr[hd], end = rowptr[hd + 1];
  float q024 = qa0[OPS_], q124 = qa1[OPS_];
  bool mark = (r == 0);
  if (tid == 0){
    atomicAdd(&u2[(size_t)hd * RB_ + rb], q124 * q024);
    if (mark) mask[hd] = 1;
  }
  for (int i = beg + tid; i < end; i += 64){
    uint2 e1 = ents2[i];
    int s  = (int)(e1.x & 0xFFFFu);
    int r1 = (int)(e1.x >> 16);
    float w1 = __uint_as_float(e1.y);
    atomicAdd(&u2[(size_t)s * RB_ + rb], w1 * (q124 * qa0[r1] + qa1[r1] * q024));
    if (mark) mask[s] = 1;
    float v1 = qa0[r1] * w1;      // this path's share of u1[s]
    int b2 = rowptr[s], e2e = rowptr[s + 1];
    for (int jj = b2; jj < e2e; ++jj){
      uint2 e2 = ents2[jj];
      int d2 = (int)(e2.x & 0xFFFFu);
      int r2 = (int)(e2.x >> 16);
      atomicAdd(&u2[(size_t)d2 * RB_ + rb], qa1[r2] * __uint_as_float(e2.y) * v1);
      if (mark) mask[d2] = 1;
    }
  }
}

// ---- batched dense gather (t=2): ONE WAVE per node, halves split 4-edge chunks.
// u2 is nonzero on only ~9k/50k rows (2-hop reachability of 32 heads): mask[] gates
// the 3x128B row loads per edge (wave-uniform branch) -> ~4x less L2/L3 traffic.
__global__ __launch_bounds__(256) void gather3_kernel(
    const float* __restrict__ ucur, float* __restrict__ unxt,
    const float* __restrict__ query_attn, int t,
    const int* __restrict__ rowptr, const uint2* __restrict__ ents,
    const u8* __restrict__ mask,
    float* __restrict__ partial /* PSLOTS x 96 */)
{
  __shared__ float qas[3 * B_ * (OPS_ + 1)];  // [r][b][o]
  __shared__ float red[RB_];
  int tid = threadIdx.x;
  for (int i = tid; i < 3 * B_ * (OPS_ + 1); i += 256){
    int r = i / (B_ * (OPS_ + 1));
    int rem = i - r * (B_ * (OPS_ + 1));
    qas[i] = query_attn[(size_t)(r * T_ + t) * B_ * (OPS_ + 1) + rem];
  }
  if (tid < RB_) red[tid] = 0.f;
  __syncthreads();
  int b  = tid & 31;
  int h  = (tid >> 5) & 1;              // half within wave
  int n = blockIdx.x * 4 + (tid >> 6);  // one wave per node; grid*4 == N_
  const float* q0 = &qas[0 * 800 + b * (OPS_ + 1)];
  const float* q1 = &qas[1 * 800 + b * (OPS_ + 1)];
  const float* q2 = &qas[2 * 800 + b * (OPS_ + 1)];
  size_t nb = (size_t)n * RB_;
  float a0 = 0.f, a1 = 0.f, a2 = 0.f;
  if (h == 0 && mask[n]){
    a0 = ucur[nb + b]      * q0[OPS_];
    a1 = ucur[nb + 32 + b] * q1[OPS_];
    a2 = ucur[nb + 64 + b] * q2[OPS_];
  }
  int beg = rowptr[n], end = rowptr[n + 1];
  int cnt = end - beg;
  int nq = cnt >> 2;                 // full 4-edge chunks
  for (int c = h; c < nq; c += 2){
    int i0 = beg + 4 * c;
    uint2 e0 = ents[i0 + 0];
    uint2 e1 = ents[i0 + 1];
    uint2 e2 = ents[i0 + 2];
    uint2 e3 = ents[i0 + 3];
    int sn0 = (int)(e0.x & 0xFFFFu);
    int sn1 = (int)(e1.x & 0xFFFFu);
    int sn2 = (int)(e2.x & 0xFFFFu);
    int sn3 = (int)(e3.x & 0xFFFFu);
    int m0 = mask[sn0], m1 = mask[sn1], m2 = mask[sn2], m3 = mask[sn3];
    if (!(m0 | m1 | m2 | m3)) continue;
    size_t s0 = (size_t)sn0 * RB_;
    size_t s1 = (size_t)sn1 * RB_;
    size_t s2 = (size_t)sn2 * RB_;
    size_t s3 = (size_t)sn3 * RB_;
    float u00 = 0.f, u01 = 0.f, u02 = 0.f;
    float u10 = 0.f, u11 = 0.f, u12 = 0.f;
    float u20 = 0.f, u21 = 0.f, u22 = 0.f;
    float u30 = 0.f, u31 = 0.f, u32 = 0.f;
    if (m0){ u00 = ucur[s0 + b]; u01 = ucur[s0 + 32 + b]; u02 = ucur[s0 + 64 + b]; }
    if (m1){ u10 = ucur[s1 + b]; u11 = ucur[s1 + 32 + b]; u12 = ucur[s1 + 64 + b]; }
    if (m2){ u20 = ucur[s2 + b]; u21 = ucur[s2 + 32 + b]; u22 = ucur[s2 + 64 + b]; }
    if (m3){ u30 = ucur[s3 + b]; u31 = ucur[s3 + 32 + b]; u32 = ucur[s3 + 64 + b]; }
    int r0 = (int)(e0.x >> 16), r1 = (int)(e1.x >> 16);
    int r2 = (int)(e2.x >> 16), r3 = (int)(e3.x >> 16);
    float w0 = __uint_as_float(e0.y), w1 = __uint_as_float(e1.y);
    float w2 = __uint_as_float(e2.y), w3 = __uint_as_float(e3.y);
    a0 += q0[r0]*w0*u00 + q0[r1]*w1*u10 + q0[r2]*w2*u20 + q0[r3]*w3*u30;
    a1 += q1[r0]*w0*u01 + q1[r1]*w1*u11 + q1[r2]*w2*u21 + q1[r3]*w3*u31;
    a2 += q2[r0]*w0*u02 + q2[r1]*w1*u12 + q2[r2]*w2*u22 + q2[r3]*w3*u32;
  }
  if (h == 1){
    for (int i = beg + 4 * nq; i < end; ++i){
      uint2 e0 = ents[i];
      int sn0 = (int)(e0.x & 0xFFFFu);
      if (!mask[sn0]) continue;
      size_t s0 = (size_t)sn0 * RB_;
      int r0 = (int)(e0.x >> 16);
      float w0 = __uint_as_float(e0.y);
      a0 += q0[r0] * w0 * ucur[s0 + b];
      a1 += q1[r0] * w0 * ucur[s0 + 32 + b];
      a2 += q2[r0] * w0 * ucur[s0 + 64 + b];
    }
  }
  a0 += __shfl_xor(a0, 32);
  a1 += __shfl_xor(a1, 32);
  a2 += __shfl_xor(a2, 32);
  if (h == 0){
    unxt[nb + b]      = a0;
    unxt[nb + 32 + b] = a1;
    unxt[nb + 64 + b] = a2;
    atomicAdd(&red[b], a0);
    atomicAdd(&red[32 + b], a1);
    atomicAdd(&red[64 + b], a2);
  }
  __syncthreads();
  if (tid < RB_)
    atomicAdd(&partial[(blockIdx.x & (PSLOTS - 1)) * RB_ + tid], red[tid]);
}

// ---- finalize + transpose: out[b][n] = sum_r u[n][r*32+b] / rowsum_r ----
__global__ void fintrans_kernel(const float* __restrict__ u, const float* __restrict__ partial,
                                float* __restrict__ out)
{
  __shared__ float sinv[RB_];
  __shared__ float t[B_][72];
  int tid = threadIdx.x;   // 256
  if (tid < RB_){
    float s = 0.f;
    #pragma unroll 8
    for (int k = 0; k < PSLOTS; ++k) s += partial[k * RB_ + tid];
    sinv[tid] = frcp(fmaxf(1e-20f, s));
  }
  __syncthreads();
  int n0 = blockIdx.x * 64;
  for (int i = tid; i < 64 * B_; i += 256){
    int nl = i >> 5, b = i & 31;
    int n = n0 + nl;
    float v = 0.f;
    if (n < N_){
      size_t nb = (size_t)n * RB_;
      v = u[nb + b] * sinv[b] + u[nb + 32 + b] * sinv[32 + b] + u[nb + 64 + b] * sinv[64 + b];
    }
    t[b][nl] = v;
  }
  __syncthreads();
  for (int i = tid; i < 64 * B_; i += 256){
    int b = i >> 6, nl = i & 63;
    int n = n0 + nl;
    if (n < N_) out[(size_t)b * N_ + n] = t[b][nl];
  }
}

extern "C" void kernel_launch(void* const* d_in, const int* in_sizes, int n_in,
                              void* d_out, int out_size, void* d_ws, size_t ws_size,
                              hipStream_t stream)
{
  const int*   queries = (const int*)d_in[0];
  const int*   heads   = (const int*)d_in[1];
  const int*   rels    = (const int*)d_in[2];
  const int*   t_heads = (const int*)d_in[3];
  const int*   t_tails = (const int*)d_in[4];
  const int*   edeg    = (const int*)d_in[5];
  const float* qemb    = (const float*)d_in[6];
  const float* eemb    = (const float*)d_in[7];
  const float* qWih    = (const float*)d_in[8];
  const float* qWhh    = (const float*)d_in[9];
  const float* qbih    = (const float*)d_in[10];
  const float* qbhh    = (const float*)d_in[11];
  const float* eWih    = (const float*)d_in[12];
  const float* eWhh    = (const float*)d_in[13];
  const float* ebih    = (const float*)d_in[14];
  const float* ebhh    = (const float*)d_in[15];
  const float* qlinW   = (const float*)d_in[16];
  const float* qlinb   = (const float*)d_in[17];
  const float* elinW   = (const float*)d_in[18];
  const float* elinb   = (const float*)d_in[19];
  float* out = (float*)d_out;

  char* ws = (char*)d_ws;
  size_t off = 0;
  auto alloc = [&](size_t bytes){ void* p = ws + off; off += (bytes + 255) & ~(size_t)255; return p; };
  // bigA (25.6 MB): houts during [elstm, eattn]; dead after eattn -> ents (csr_fill).
  char*  bigA  = (char*)alloc((size_t)2 * N_ * H_ * 2);               // 25,600,000
  u16*   houts = (u16*)bigA;                                          // f16 bits
  uint2* ents  = (uint2*)bigA;                                        // in-CSR, 6.4 MB
  // bigB (19.2 MB): attn (4.8 MB) during [eattn, csr_fill]; then u3 (gather3 output).
  char*  bigB  = (char*)alloc((size_t)N_ * RB_ * 4);
  float* attn  = (float*)bigB;
  float* u3    = (float*)bigB;
  float* u2         = (float*)alloc((size_t)N_ * RB_ * 4);            // fresh 19.2 MB
  uint2* ents2      = (uint2*)alloc((size_t)2 * E_ * 8);              // out-CSR, 6.4 MB
  float* query_attn = (float*)alloc((size_t)R_ * T_ * B_ * (OPS_ + 1) * 4);
  u16*   wtile      = (u16*)  alloc((size_t)2 * 32 * 4 * 64 * 8 * 2);
  u16*   wonehot    = (u16*)  alloc((size_t)2 * 32 * 64 * 8 * 2);
  int*   counts     = (int*)  alloc((size_t)(N_ + 1) * 4);
  int*   rowptr     = (int*)  alloc((size_t)(N_ + 1) * 4);
  int*   cursor     = (int*)  alloc((size_t)(N_ + 1) * 4);
  int*   cursor2    = (int*)  alloc((size_t)(N_ + 1) * 4);
  u8*    mask       = (u8*)   alloc((size_t)N_);
  float* sumsP      = (float*)alloc((size_t)PSLOTS * RB_ * 4);        // t2 partials only
  // total ~72 MB

  hipMemsetAsync(sumsP, 0, (size_t)PSLOTS * RB_ * 4, stream);
  hipMemsetAsync(counts, 0, (size_t)(N_ + 1) * 4, stream);
  hipMemsetAsync(u2, 0, (size_t)N_ * RB_ * 4, stream);
  hipMemsetAsync(mask, 0, (size_t)N_, stream);

  // fused qattn | wbuild | csr_count (independent; were serialized on the stream)
  front_kernel<<<QB_ + WB_ + CB_, 256, 0, stream>>>(
      queries, qemb, qWih, qWhh, qbih, qbhh, qlinW, qlinb, query_attn,
      eWhh, eemb, eWih, ebih, ebhh, wtile, wonehot,
      t_heads, t_tails, counts);
  // elstm + csr_scan riding as block SCANBLK_ (scan needs counts only; csr_fill
  // consumes rowptr/cursors after this launch completes)
  elstm_kernel<<<SCANBLK_ + 1, 512, 0, stream>>>(edeg, wtile, wonehot, houts,
                                                 counts, rowptr, cursor, cursor2);
  eattn_kernel<<<256, 256, 0, stream>>>(houts, elinW, elinb, attn);
  // houts dead -> ents may take bigA; attn still live (read by csr_fill):
  csr_fill_kernel<<<(E_ + 255) / 256, 256, 0, stream>>>(rels, t_heads, t_tails, attn,
                                                        cursor, cursor2, ents, ents2);
  // fused t=0 + t=1 sparse propagation into u2 (+ nonzero-row mask)
  t01_kernel<<<RB_, 64, 0, stream>>>(heads, query_attn, rowptr, ents2, u2, mask);
  // t=2: dense gather with mask-gated row loads (attn dead; u3 overwrites bigB)
  gather3_kernel<<<N_ / 4, 256, 0, stream>>>(u2, u3, query_attn, 2, rowptr, ents,
                                             mask, sumsP);
  fintrans_kernel<<<(N_ + 63) / 64, 256, 0, stream>>>(u3, sumsP, out);
}

// Round 8
// 585.326 us; speedup vs baseline: 1.6998x; 1.2132x over previous
//
#include <hip/hip_runtime.h>

#define R_ 3
#define T_ 3
#define N_ 50000
#define OPS_ 24
#define E_ 400000
#define B_ 32
#define MAXDEG_ 8
#define QD_ 128
#define ED_ 128
#define H_ 128
#define G4_ (4*H_)   /* 512 */
#define HPAD 168     /* padded LDS h-row (bf16): 128 h + 25 one-hot + pad, 336 B */
#define PSLOTS 64    /* partial row-sum slots */
#define RB_ 96       /* 3 rounds x 32 batch */

/* front fat-kernel block ranges */
#define QB_ (R_ * B_)                          /* 96  qattn blocks  */
#define WB_ ((2*32*5*64*8 + 255) / 256)        /* 640 wbuild blocks */
#define CB_ ((E_ + 255) / 256)                 /* 1563 csr_count    */
#define ZU_ 1172                               /* u2 zero: 4.8M floats / 4096 */
#define ZM_ 49                                 /* mask zero: 12500 ints / 256 */
#define ZS_ 24                                 /* sumsP zero: 6144 floats / 256 */
#define SCANBLK_ ((N_ + 31) / 32)              /* 1563 elstm blocks (+1 scan rider) */

typedef unsigned short u16;
typedef unsigned char u8;
typedef __attribute__((ext_vector_type(8))) short bf16x8;     // 8 bf16 = 4 VGPRs
typedef __attribute__((ext_vector_type(8))) _Float16 f16x8;   // 8 f16  = 4 VGPRs
typedef __attribute__((ext_vector_type(4))) float f32x4;

#define BF16_ONE ((short)0x3F80)
#define LOG2E_  1.44269504f
#define LOG2E2_ 2.88539008f

__device__ __forceinline__ short f2bf(float f){
  union { float f; unsigned u; } v; v.f = f;
  unsigned r = v.u + 0x7fffu + ((v.u >> 16) & 1u);
  return (short)(r >> 16);
}
__device__ __forceinline__ float bf2f(u16 u){
  union { unsigned u; float f; } v; v.u = ((unsigned)u) << 16; return v.f;
}
__device__ __forceinline__ float frcp(float x){ return __builtin_amdgcn_rcpf(x); }
__device__ __forceinline__ float fsig(float x){ return frcp(1.0f + __expf(-x)); }
// tanh(x) = 2*sigmoid(2x) - 1
__device__ __forceinline__ float ftanh(float x){
  return __builtin_fmaf(2.0f, fsig(2.0f * x), -1.0f);
}
// 2^x via v_exp_f32 (guarded fallback keeps semantics if builtin missing)
__device__ __forceinline__ float fexp2(float x){
#if __has_builtin(__builtin_amdgcn_exp2f)
  return __builtin_amdgcn_exp2f(x);
#else
  return __expf(x * 0.6931471806f);
#endif
}

// ---------------- query BiLSTM + attention: one virtual block per (r,b) ----------------
__device__ void qattn_body(int bid, const int* __restrict__ queries, const float* __restrict__ qemb,
    const float* __restrict__ qWih, const float* __restrict__ qWhh,
    const float* __restrict__ qbih, const float* __restrict__ qbhh,
    const float* __restrict__ qlinW, const float* __restrict__ qlinb,
    float* __restrict__ query_attn /* R,T,B,25 */)
{
  int r = bid / B_;
  int b = bid % B_;
  int tid = threadIdx.x;   // 256
  __shared__ float x[QD_];
  __shared__ float gx[G4_];
  __shared__ float h[H_], c[H_];
  __shared__ float gtmp[G4_];
  __shared__ float hh[2][T_][H_];
  __shared__ float lg[OPS_ + 1];

  int q = queries[b];
  if (tid < QD_) x[tid] = qemb[q * QD_ + tid];
  __syncthreads();

  for (int dir = 0; dir < 2; ++dir){
    const float* Wih = qWih + (size_t)(r * 2 + dir) * G4_ * QD_;
    const float* Whh = qWhh + (size_t)(r * 2 + dir) * G4_ * H_;
    const float* bih = qbih + (r * 2 + dir) * G4_;
    const float* bhh = qbhh + (r * 2 + dir) * G4_;
    for (int j = tid; j < G4_; j += 256){
      const float4* wr = (const float4*)(Wih + (size_t)j * QD_);
      float s = bih[j] + bhh[j];
      for (int k = 0; k < QD_ / 4; ++k){
        float4 wv = wr[k];
        s += wv.x * x[4*k] + wv.y * x[4*k+1] + wv.z * x[4*k+2] + wv.w * x[4*k+3];
      }
      gx[j] = s;
    }
    if (tid < H_){ h[tid] = 0.f; c[tid] = 0.f; }
    __syncthreads();
    for (int t = 0; t < T_; ++t){
      for (int j = tid; j < G4_; j += 256){
        const float4* wr = (const float4*)(Whh + (size_t)j * H_);
        float s = 0.f;
        for (int k = 0; k < H_ / 4; ++k){
          float4 wv = wr[k];
          s += wv.x * h[4*k] + wv.y * h[4*k+1] + wv.z * h[4*k+2] + wv.w * h[4*k+3];
        }
        gtmp[j] = gx[j] + s;
      }
      __syncthreads();
      if (tid < H_){
        float gi = gtmp[tid], gf = gtmp[tid + H_], gg = gtmp[tid + 2*H_], go = gtmp[tid + 3*H_];
        float cn = fsig(gf) * c[tid] + fsig(gi) * ftanh(gg);
        float hn = fsig(go) * ftanh(cn);
        c[tid] = cn; h[tid] = hn;
        hh[dir][t][tid] = hn;
      }
      __syncthreads();
    }
  }

  for (int t = 0; t < T_; ++t){
    if (tid < OPS_ + 1){
      const float* wr = qlinW + tid * (2 * H_);
      float s = qlinb[tid];
      for (int k = 0; k < H_; ++k) s += wr[k] * hh[0][t][k];
      for (int k = 0; k < H_; ++k) s += wr[H_ + k] * hh[1][T_ - 1 - t][k];
      lg[tid] = s;
    }
    __syncthreads();
    if (tid == 0){
      float m = -1e30f;
      for (int o = 0; o < OPS_ + 1; ++o) m = fmaxf(m, lg[o]);
      float sum = 0.f;
      for (int o = 0; o < OPS_ + 1; ++o){ float e = __expf(lg[o] - m); lg[o] = e; sum += e; }
      float inv = frcp(sum);
      for (int o = 0; o < OPS_ + 1; ++o) lg[o] *= inv;
    }
    __syncthreads();
    if (tid < OPS_ + 1) query_attn[((size_t)(r * T_ + t) * B_ + b) * (OPS_ + 1) + tid] = lg[tid];
    __syncthreads();
  }
}

// ---- build B-operand buffers in MFMA-fragment order (eproj folded in) ----
// Gate rows are PRE-SCALED by log2(e) (gates i,f,o) / 2*log2(e) (gate g) so the
// LSTM activation can use raw v_exp_f32 (=2^x) without per-exp ln2 muls.
__device__ void wbuild_body(int bid, const float* __restrict__ eWhh,
                            const float* __restrict__ eemb, const float* __restrict__ eWih,
                            const float* __restrict__ ebih, const float* __restrict__ ebhh,
                            u16* __restrict__ wtile, u16* __restrict__ wonehot)
{
  int idx = bid * 256 + threadIdx.x;    // 2*32*5*64*8 = 163840
  if (idx >= 2 * 32 * 5 * 64 * 8) return;
  int jj = idx & 7;
  int lane = (idx >> 3) & 63;
  int kc = (idx >> 9) % 5;
  int gtile = (idx / (8 * 64 * 5)) & 31;
  int dir = idx / (8 * 64 * 5 * 32);
  int row = lane >> 4, col = lane & 15;
  int j = gtile * 16 + col;
  float sc = ((gtile >> 3) == 2) ? LOG2E2_ : LOG2E_;   // gate g rows get 2*log2e
  if (kc < 4){
    int k = kc * 32 + row * 8 + jj;
    float v = eWhh[((size_t)dir * G4_ + j) * H_ + k] * sc;
    wtile[((((size_t)dir * 32 + gtile) * 4 + kc) * 64 + lane) * 8 + jj] = (u16)f2bf(v);
  } else {
    int vdeg = row * 8 + jj;   // 0..31
    float v = 0.f;
    if (vdeg <= OPS_){
      const float4* wr = (const float4*)(eWih + (size_t)(dir * G4_ + j) * ED_);
      const float4* er = (const float4*)(eemb + (size_t)vdeg * ED_);
      float s = ebih[dir * G4_ + j] + ebhh[dir * G4_ + j];
      for (int k = 0; k < ED_ / 4; ++k){
        float4 wv = wr[k], ev = er[k];
        s += wv.x * ev.x + wv.y * ev.y + wv.z * ev.z + wv.w * ev.w;
      }
      v = s * sc;
    }
    wonehot[(((size_t)dir * 32 + gtile) * 64 + lane) * 8 + jj] = (u16)f2bf(v);
  }
}

__device__ void csr_count_body(int bid, const int* __restrict__ theads,
                               const int* __restrict__ ttails, int* __restrict__ counts)
{
  int e = bid * 256 + threadIdx.x;
  if (e < E_){
    atomicAdd(&counts[ttails[e]], 1);
    atomicAdd(&counts[theads[e]], 1);
  }
}

// ---- front fat-kernel: qattn | wbuild | csr_count | zero(u2,mask,sumsP).
// All mutually independent; zeroed buffers are consumed only by later dispatches.
__global__ __launch_bounds__(256) void front_kernel(
    const int* queries, const float* qemb,
    const float* qWih, const float* qWhh, const float* qbih, const float* qbhh,
    const float* qlinW, const float* qlinb, float* query_attn,
    const float* eWhh, const float* eemb, const float* eWih,
    const float* ebih, const float* ebhh, u16* wtile, u16* wonehot,
    const int* theads, const int* ttails, int* counts,
    float* u2, int* maski, float* sumsP)
{
  int bid = blockIdx.x;
  int tid = threadIdx.x;
  if (bid < QB_){
    qattn_body(bid, queries, qemb, qWih, qWhh, qbih, qbhh, qlinW, qlinb, query_attn);
  } else if (bid < QB_ + WB_){
    wbuild_body(bid - QB_, eWhh, eemb, eWih, ebih, ebhh, wtile, wonehot);
  } else if (bid < QB_ + WB_ + CB_){
    csr_count_body(bid - QB_ - WB_, theads, ttails, counts);
  } else if (bid < QB_ + WB_ + CB_ + ZU_){
    int zb = bid - QB_ - WB_ - CB_;
    float4 z = {0.f, 0.f, 0.f, 0.f};
    size_t base = (size_t)zb * 4096 + tid * 4;
    #pragma unroll
    for (int k = 0; k < 4; ++k){
      size_t idx = base + (size_t)k * 1024;
      if (idx < (size_t)N_ * RB_) *(float4*)&u2[idx] = z;
    }
  } else if (bid < QB_ + WB_ + CB_ + ZU_ + ZM_){
    int mi = (bid - QB_ - WB_ - CB_ - ZU_) * 256 + tid;
    if (mi < (N_ + 3) / 4) maski[mi] = 0;
  } else {
    int si = (bid - QB_ - WB_ - CB_ - ZU_ - ZM_) * 256 + tid;
    if (si < PSLOTS * RB_) sumsP[si] = 0.f;
  }
}

// ---- coalesced tile scan (512 threads, rides as block 0 of the elstm grid).
// Round-7 lesson: the naive per-thread-run scan was ~100us (stride-392B access,
// 100k latency-bound L2 loads from ONE CU, twice). Tile version: int4 coalesced
// loads/stores + wave shfl_up scan + 8-entry LDS fixup; 2 barriers/tile, 25 tiles.
__device__ void scan_body(const int* __restrict__ counts, int* __restrict__ rowptr,
                          int* __restrict__ cursor, int* __restrict__ cursor2)
{
  __shared__ int wsum[8];
  int t = threadIdx.x;
  int lane = t & 63, wv = t >> 6;
  int carry = 0;   // live only in thread 0
  for (int base = 0; base < N_; base += 2048){
    int idx = base + t * 4;
    int c0 = 0, c1 = 0, c2 = 0, c3 = 0;
    if (idx + 3 < N_){
      int4 c = *(const int4*)&counts[idx];
      c0 = c.x; c1 = c.y; c2 = c.z; c3 = c.w;
    } else {
      if (idx     < N_) c0 = counts[idx];
      if (idx + 1 < N_) c1 = counts[idx + 1];
      if (idx + 2 < N_) c2 = counts[idx + 2];
      if (idx + 3 < N_) c3 = counts[idx + 3];
    }
    int s = c0 + c1 + c2 + c3;
    int sc = s;                          // inclusive wave scan
    #pragma unroll
    for (int off = 1; off < 64; off <<= 1){
      int v = __shfl_up(sc, off);
      if (lane >= off) sc += v;
    }
    if (lane == 63) wsum[wv] = sc;
    __syncthreads();
    if (t == 0){
      int acc = carry;
      #pragma unroll
      for (int w = 0; w < 8; ++w){ int v = wsum[w]; wsum[w] = acc; acc += v; }
      carry = acc;
    }
    __syncthreads();
    int excl = wsum[wv] + (sc - s);
    int r0 = excl, r1 = r0 + c0, r2 = r1 + c1, r3 = r2 + c2;
    if (idx + 3 < N_){
      int4 rv; rv.x = r0; rv.y = r1; rv.z = r2; rv.w = r3;
      *(int4*)&rowptr[idx]  = rv;
      *(int4*)&cursor[idx]  = rv;
      *(int4*)&cursor2[idx] = rv;
    } else {
      if (idx     < N_){ rowptr[idx]   = r0; cursor[idx]   = r0; cursor2[idx]   = r0; }
      if (idx + 1 < N_){ rowptr[idx+1] = r1; cursor[idx+1] = r1; cursor2[idx+1] = r1; }
      if (idx + 2 < N_){ rowptr[idx+2] = r2; cursor[idx+2] = r2; cursor2[idx+2] = r2; }
      if (idx + 3 < N_){ rowptr[idx+3] = r3; cursor[idx+3] = r3; cursor2[idx+3] = r3; }
    }
    // no extra barrier needed: wsum[wv] is re-written only by this wave's lane 63
    // (program order) and read by t0 only after the next tile's barrier.
  }
  if (t == 0) rowptr[N_] = carry;
}

// ------ entity BiLSTM: 512 threads / 8 waves / 32 entities per block (r6-exact) ------
// + block 0 runs the CSR exclusive scan concurrently (scheduled FIRST, so it
// overlaps the elstm rounds instead of tailing them as in round 7).
// launch_bounds(512,4): cap 128 regs -> 60 VGPR + 32 AGPR = 92 combined, no spill.
// Occupancy ladder is BINARY (r4/r5): <=64 combined -> 8 waves/SIMD (infeasible,
// demand 92), <=128 -> 4 waves/SIMD. 80% issue-busy (54 VALU + 26 MFMA).
__global__ __launch_bounds__(512, 4) void elstm_kernel(
    const int* __restrict__ degs,
    const u16* __restrict__ wtile, const u16* __restrict__ wonehot,
    u16* __restrict__ houts /* 2,N,128 f16 */,
    const int* __restrict__ counts, int* __restrict__ rowptr,
    int* __restrict__ cursor, int* __restrict__ cursor2)
{
  if (blockIdx.x == 0){ scan_body(counts, rowptr, cursor, cursor2); return; }

  int tid = threadIdx.x;
  int lane = tid & 63;
  int w = tid >> 6;          // wave 0..7
  int wu = __builtin_amdgcn_readfirstlane(w);   // provably wave-uniform
  int row = lane >> 4, col = lane & 15;
  int ebase = (blockIdx.x - 1) * 32;

  __shared__ __align__(16) short hl[2][32 * HPAD];   // 2 x 10.5 KB ping-pong

  int eg0 = ebase + tid; if (eg0 >= N_) eg0 = N_ - 1;   // valid for tid<32 use

  for (int i = tid; i < 2 * 32 * HPAD; i += 512) ((short*)hl)[i] = 0;
  __syncthreads();
  if (tid < 32) hl[0][tid * HPAD + H_ + degs[(size_t)eg0 * MAXDEG_ + 0]] = BF16_ONE;
  __syncthreads();

  for (int dir = 0; dir < 2; ++dir){
    const u16* Wt  = wtile   + (size_t)dir * 32 * 4 * 64 * 8;
    const u16* Woh = wonehot + (size_t)dir * 32 * 64 * 8;
    // per-gate scalar bases (gtile = g*8 + wu)
    const u16* W0 = Wt + (size_t)((0 * 8 + wu) * 4 * 64) * 8;
    const u16* W1 = Wt + (size_t)((1 * 8 + wu) * 4 * 64) * 8;
    const u16* W2 = Wt + (size_t)((2 * 8 + wu) * 4 * 64) * 8;
    const u16* W3 = Wt + (size_t)((3 * 8 + wu) * 4 * 64) * 8;
    const u16* O0 = Woh + (size_t)((0 * 8 + wu) * 64) * 8;
    const u16* O1 = Woh + (size_t)((1 * 8 + wu) * 64) * 8;
    const u16* O2 = Woh + (size_t)((2 * 8 + wu) * 64) * 8;
    const u16* O3 = Woh + (size_t)((3 * 8 + wu) * 64) * 8;
    float cst[8];
    #pragma unroll
    for (int i = 0; i < 8; ++i) cst[i] = 0.f;

    for (int t = 0; t < MAXDEG_; ++t){
      const short* hb = hl[t & 1];          // holds h_t (+ one-hot for step t)
      short*       hw = hl[(t + 1) & 1];    // receives h_{t+1}
      f32x4 acc[8];
      #pragma unroll
      for (int i = 0; i < 8; ++i) acc[i] = (f32x4){0.f, 0.f, 0.f, 0.f};

      #pragma unroll 2
      for (int kc = 0; kc < 4; ++kc){
        bf16x8 af0 = *(const bf16x8*)&hb[(col) * HPAD + kc * 32 + row * 8];
        bf16x8 af1 = *(const bf16x8*)&hb[(16 + col) * HPAD + kc * 32 + row * 8];
        int lo = (kc * 64 + lane) * 8;
        bf16x8 b0 = *(const bf16x8*)(W0 + lo);
        bf16x8 b1 = *(const bf16x8*)(W1 + lo);
        bf16x8 b2 = *(const bf16x8*)(W2 + lo);
        bf16x8 b3 = *(const bf16x8*)(W3 + lo);
        acc[0] = __builtin_amdgcn_mfma_f32_16x16x32_bf16(af0, b0, acc[0], 0, 0, 0);
        acc[1] = __builtin_amdgcn_mfma_f32_16x16x32_bf16(af1, b0, acc[1], 0, 0, 0);
        acc[2] = __builtin_amdgcn_mfma_f32_16x16x32_bf16(af0, b1, acc[2], 0, 0, 0);
        acc[3] = __builtin_amdgcn_mfma_f32_16x16x32_bf16(af1, b1, acc[3], 0, 0, 0);
        acc[4] = __builtin_amdgcn_mfma_f32_16x16x32_bf16(af0, b2, acc[4], 0, 0, 0);
        acc[5] = __builtin_amdgcn_mfma_f32_16x16x32_bf16(af1, b2, acc[5], 0, 0, 0);
        acc[6] = __builtin_amdgcn_mfma_f32_16x16x32_bf16(af0, b3, acc[6], 0, 0, 0);
        acc[7] = __builtin_amdgcn_mfma_f32_16x16x32_bf16(af1, b3, acc[7], 0, 0, 0);
      }
      {
        bf16x8 af0 = *(const bf16x8*)&hb[(col) * HPAD + H_ + row * 8];
        bf16x8 af1 = *(const bf16x8*)&hb[(16 + col) * HPAD + H_ + row * 8];
        int lo = lane * 8;
        bf16x8 b0 = *(const bf16x8*)(O0 + lo);
        bf16x8 b1 = *(const bf16x8*)(O1 + lo);
        bf16x8 b2 = *(const bf16x8*)(O2 + lo);
        bf16x8 b3 = *(const bf16x8*)(O3 + lo);
        acc[0] = __builtin_amdgcn_mfma_f32_16x16x32_bf16(af0, b0, acc[0], 0, 0, 0);
        acc[1] = __builtin_amdgcn_mfma_f32_16x16x32_bf16(af1, b0, acc[1], 0, 0, 0);
        acc[2] = __builtin_amdgcn_mfma_f32_16x16x32_bf16(af0, b1, acc[2], 0, 0, 0);
        acc[3] = __builtin_amdgcn_mfma_f32_16x16x32_bf16(af1, b1, acc[3], 0, 0, 0);
        acc[4] = __builtin_amdgcn_mfma_f32_16x16x32_bf16(af0, b2, acc[4], 0, 0, 0);
        acc[5] = __builtin_amdgcn_mfma_f32_16x16x32_bf16(af1, b2, acc[5], 0, 0, 0);
        acc[6] = __builtin_amdgcn_mfma_f32_16x16x32_bf16(af0, b3, acc[6], 0, 0, 0);
        acc[7] = __builtin_amdgcn_mfma_f32_16x16x32_bf16(af1, b3, acc[7], 0, 0, 0);
      }

      // activation (gates pre-scaled by log2e / 2log2e):
      // cn = [cst*(1+ea)(1+eb) + (1-eb)(1+ef)] / [(1+ef)(1+ea)(1+eb)]
      // hn = (1-ed) / [(1+eo)(1+ed)],  ed = 2^(-2*log2e*cn)
      #pragma unroll
      for (int mt = 0; mt < 2; ++mt){
        #pragma unroll
        for (int reg = 0; reg < 4; ++reg){
          int e = mt * 16 + row * 4 + reg;
          int j = wu * 16 + col;
          float Gi = acc[0 + mt][reg];
          float Gf = acc[2 + mt][reg];
          float Gg = acc[4 + mt][reg];
          float Go = acc[6 + mt][reg];
          int ci = mt * 4 + reg;
          float ea = fexp2(-Gi);
          float ef = fexp2(-Gf);
          float eb = fexp2(-Gg);
          float eo = fexp2(-Go);
          float t1 = 1.f + ef, t2 = 1.f + ea, t3 = 1.f + eb;
          float p = t2 * t3;
          float num = __builtin_fmaf(cst[ci], p, (1.f - eb) * t1);
          float cn = num * frcp(t1 * p);
          float ed = fexp2(cn * (-LOG2E2_));
          float hn = (1.f - ed) * frcp((1.f + eo) * (1.f + ed));
          cst[ci] = cn;
          hw[e * HPAD + j] = f2bf(hn);
        }
      }
      // one-hot maintenance on the write buffer: clear the slot set 2 steps ago,
      // set the slot step t+1 will read (clear BEFORE set handles repeated degrees).
      if (tid < 32){
        const int* dr = degs + (size_t)eg0 * MAXDEG_;
        if (t >= 1)
          hw[tid * HPAD + H_ + dr[dir ? (MAXDEG_ - t) : (t - 1)]] = 0;
        if (t < MAXDEG_ - 1)
          hw[tid * HPAD + H_ + dr[dir ? (MAXDEG_ - 2 - t) : (t + 1)]] = BF16_ONE;
      }
      __syncthreads();
    }

    // MAXDEG_ even -> final h sits in hl[0]. Store as F16 (exact from bf16).
    for (int i = tid; i < 32 * H_; i += 512){
      int e = i >> 7, k = i & 127;
      int n = ebase + e;
      if (n < N_){
        _Float16 hv = (_Float16)bf2f((u16)hl[0][e * HPAD + k]);
        houts[(size_t)dir * N_ * H_ + (size_t)n * H_ + k] = *(const u16*)&hv;
      }
    }
    if (dir == 0){
      __syncthreads();
      for (int i = tid; i < 2 * 32 * HPAD; i += 512) ((short*)hl)[i] = 0;
      __syncthreads();
      if (tid < 32) hl[0][tid * HPAD + H_ + degs[(size_t)eg0 * MAXDEG_ + (MAXDEG_ - 1)]] = BF16_ONE;
      __syncthreads();
    }
  }
}

// ------------- entity attention: f16 MFMA GEMM (N x 24 = hq(N x 256) @ W^T) -------------
__global__ void eattn_kernel(const u16* __restrict__ hq /* f16 bits, 2 x N x 128 */,
                             const float* __restrict__ elinW, const float* __restrict__ elinb,
                             float* __restrict__ attn /* N,24 */)
{
  int tid = threadIdx.x;
  int lane = tid & 63;
  int col = lane & 15;
  int krow = lane >> 4;   // 0..3

  f16x8 Bf[2][8];
  #pragma unroll
  for (int ot = 0; ot < 2; ++ot){
    int o = ot * 16 + col;
    #pragma unroll
    for (int ks = 0; ks < 8; ++ks){
      f16x8 bv;
      if (o < OPS_){
        const float* src = elinW + (size_t)o * (2 * H_) + ks * 32 + krow * 8;
        #pragma unroll
        for (int jj = 0; jj < 8; ++jj) bv[jj] = (_Float16)src[jj];
      } else {
        #pragma unroll
        for (int jj = 0; jj < 8; ++jj) bv[jj] = (_Float16)0.f;
      }
      Bf[ot][ks] = bv;
    }
  }
  float b0 = elinb[col];
  float b1 = (col < 8) ? elinb[16 + col] : -1e30f;

  int wid = blockIdx.x * 4 + (tid >> 6);
  for (int g = wid; g < N_ / 16; g += 256 * 4){
    f16x8 Af[8];
    #pragma unroll
    for (int ks = 0; ks < 8; ++ks){
      const u16* src = hq + (size_t)(ks >> 2) * N_ * H_
                          + (size_t)(g * 16 + col) * H_ + (ks & 3) * 32 + krow * 8;
      Af[ks] = *(const f16x8*)src;
    }
    f32x4 ac0 = (f32x4){0.f, 0.f, 0.f, 0.f};
    f32x4 ac1 = (f32x4){0.f, 0.f, 0.f, 0.f};
    #pragma unroll
    for (int ks = 0; ks < 8; ++ks){
      ac0 = __builtin_amdgcn_mfma_f32_16x16x32_f16(Af[ks], Bf[0][ks], ac0, 0, 0, 0);
      ac1 = __builtin_amdgcn_mfma_f32_16x16x32_f16(Af[ks], Bf[1][ks], ac1, 0, 0, 0);
    }
    #pragma unroll
    for (int reg = 0; reg < 4; ++reg){
      int node = g * 16 + krow * 4 + reg;
      float v0 = ac0[reg] + b0;
      float v1 = (col < 8) ? (ac1[reg] + b1) : -1e30f;
      float m = fmaxf(v0, v1);
      m = fmaxf(m, __shfl_xor(m, 1));
      m = fmaxf(m, __shfl_xor(m, 2));
      m = fmaxf(m, __shfl_xor(m, 4));
      m = fmaxf(m, __shfl_xor(m, 8));
      float e0 = __expf(v0 - m);
      float e1 = (col < 8) ? __expf(v1 - m) : 0.f;
      float s = e0 + e1;
      s += __shfl_xor(s, 1);
      s += __shfl_xor(s, 2);
      s += __shfl_xor(s, 4);
      s += __shfl_xor(s, 8);
      float inv = frcp(s);
      attn[(size_t)node * OPS_ + col] = e0 * inv;
      if (col < 8) attn[(size_t)node * OPS_ + 16 + col] = e1 * inv;
    }
  }
}

__global__ void csr_fill_kernel(const int* __restrict__ rels, const int* __restrict__ theads,
                                const int* __restrict__ ttails, const float* __restrict__ attn,
                                int* __restrict__ cursor, int* __restrict__ cursor2,
                                uint2* __restrict__ ents, uint2* __restrict__ ents2)
{
  int e = blockIdx.x * 256 + threadIdx.x;
  if (e < E_){
    int hh = theads[e], tt = ttails[e], rel = rels[e];
    unsigned wb = __float_as_uint(attn[(size_t)hh * OPS_ + rel]);
    uint2 v1; v1.x = (unsigned)hh | ((unsigned)rel << 16);            v1.y = wb;
    uint2 v2; v2.x = (unsigned)tt | ((unsigned)(rel + OPS_/2) << 16); v2.y = wb;
    ents[atomicAdd(&cursor[tt], 1)] = v1;
    ents[atomicAdd(&cursor[hh], 1)] = v2;
    uint2 w1; w1.x = (unsigned)tt | ((unsigned)rel << 16);            w1.y = wb;
    uint2 w2; w2.x = (unsigned)hh | ((unsigned)(rel + OPS_/2) << 16); w2.y = wb;
    ents2[atomicAdd(&cursor2[hh], 1)] = w1;
    ents2[atomicAdd(&cursor2[tt], 1)] = w2;
  }
}

// ---- fused sparse t=0 + t=1 (normalization telescopes -> everything linear):
// u2[head]  += qa1[24]*qa0[24]                                   (self o self)
// u2[s]     += w1*(qa1[24]*qa0[r1] + qa1[r1]*qa0[24])  per e1(head->s)
// u2[d]     += qa1[r2]*w2 * qa0[r1]*w1                 per e1,e2(s->d)
// Also marks the nonzero-row mask (only r==0 blocks; reachability is r-independent).
__global__ void t01_kernel(const int* __restrict__ heads, const float* __restrict__ query_attn,
                           const int* __restrict__ rowptr, const uint2* __restrict__ ents2,
                           float* __restrict__ u2, u8* __restrict__ mask)
{
  __shared__ float qa0[OPS_ + 1], qa1[OPS_ + 1];
  int blk = blockIdx.x;   // 0..95
  int r = blk >> 5, b = blk & 31;
  int rb = r * 32 + b;
  int tid = threadIdx.x;  // 64
  if (tid < OPS_ + 1){
    qa0[tid] = query_attn[((size_t)(r * T_ + 0) * B_ + b) * (OPS_ + 1) + tid];
    qa1[tid] = query_attn[((size_t)(r * T_ + 1) * B_ + b) * (OPS_ + 1) + tid];
  }
  __syncthreads();
  int hd = heads[b];
  int beg = rowptr[hd], end = rowptr[hd + 1];
  float q024 = qa0[OPS_], q124 = qa1[OPS_];
  bool mark = (r == 0);
  if (tid == 0){
    atomicAdd(&u2[(size_t)hd * RB_ + rb], q124 * q024);
    if (mark) mask[hd] = 1;
  }
  for (int i = beg + tid; i < end; i += 64){
    uint2 e1 = ents2[i];
    int s  = (int)(e1.x & 0xFFFFu);
    int r1 = (int)(e1.x >> 16);
    float w1 = __uint_as_float(e1.y);
    atomicAdd(&u2[(size_t)s * RB_ + rb], w1 * (q124 * qa0[r1] + qa1[r1] * q024));
    if (mark) mask[s] = 1;
    float v1 = qa0[r1] * w1;      // this path's share of u1[s]
    int b2 = rowptr[s], e2e = rowptr[s + 1];
    for (int jj = b2; jj < e2e; ++jj){
      uint2 e2 = ents2[jj];
      int d2 = (int)(e2.x & 0xFFFFu);
      int r2 = (int)(e2.x >> 16);
      atomicAdd(&u2[(size_t)d2 * RB_ + rb], qa1[r2] * __uint_as_float(e2.y) * v1);
      if (mark) mask[d2] = 1;
    }
  }
}

// ---- batched dense gather (t=2): ONE WAVE per node, halves split 4-edge chunks.
// u2 is nonzero on only ~9k/50k rows (2-hop reachability of 32 heads): mask[] gates
// the 3x128B row loads per edge (wave-uniform branch) -> ~4x less L2/L3 traffic.
__global__ __launch_bounds__(256) void gather3_kernel(
    const float* __restrict__ ucur, float* __restrict__ unxt,
    const float* __restrict__ query_attn, int t,
    const int* __restrict__ rowptr, const uint2* __restrict__ ents,
    const u8* __restrict__ mask,
    float* __restrict__ partial /* PSLOTS x 96 */)
{
  __shared__ float qas[3 * B_ * (OPS_ + 1)];  // [r][b][o]
  __shared__ float red[RB_];
  int tid = threadIdx.x;
  for (int i = tid; i < 3 * B_ * (OPS_ + 1); i += 256){
    int r = i / (B_ * (OPS_ + 1));
    int rem = i - r * (B_ * (OPS_ + 1));
    qas[i] = query_attn[(size_t)(r * T_ + t) * B_ * (OPS_ + 1) + rem];
  }
  if (tid < RB_) red[tid] = 0.f;
  __syncthreads();
  int b  = tid & 31;
  int h  = (tid >> 5) & 1;              // half within wave
  int n = blockIdx.x * 4 + (tid >> 6);  // one wave per node; grid*4 == N_
  const float* q0 = &qas[0 * 800 + b * (OPS_ + 1)];
  const float* q1 = &qas[1 * 800 + b * (OPS_ + 1)];
  const float* q2 = &qas[2 * 800 + b * (OPS_ + 1)];
  size_t nb = (size_t)n * RB_;
  float a0 = 0.f, a1 = 0.f, a2 = 0.f;
  if (h == 0 && mask[n]){
    a0 = ucur[nb + b]      * q0[OPS_];
    a1 = ucur[nb + 32 + b] * q1[OPS_];
    a2 = ucur[nb + 64 + b] * q2[OPS_];
  }
  int beg = rowptr[n], end = rowptr[n + 1];
  int cnt = end - beg;
  int nq = cnt >> 2;                 // full 4-edge chunks
  for (int c = h; c < nq; c += 2){
    int i0 = beg + 4 * c;
    uint2 e0 = ents[i0 + 0];
    uint2 e1 = ents[i0 + 1];
    uint2 e2 = ents[i0 + 2];
    uint2 e3 = ents[i0 + 3];
    int sn0 = (int)(e0.x & 0xFFFFu);
    int sn1 = (int)(e1.x & 0xFFFFu);
    int sn2 = (int)(e2.x & 0xFFFFu);
    int sn3 = (int)(e3.x & 0xFFFFu);
    int m0 = mask[sn0], m1 = mask[sn1], m2 = mask[sn2], m3 = mask[sn3];
    if (!(m0 | m1 | m2 | m3)) continue;
    size_t s0 = (size_t)sn0 * RB_;
    size_t s1 = (size_t)sn1 * RB_;
    size_t s2 = (size_t)sn2 * RB_;
    size_t s3 = (size_t)sn3 * RB_;
    float u00 = 0.f, u01 = 0.f, u02 = 0.f;
    float u10 = 0.f, u11 = 0.f, u12 = 0.f;
    float u20 = 0.f, u21 = 0.f, u22 = 0.f;
    float u30 = 0.f, u31 = 0.f, u32 = 0.f;
    if (m0){ u00 = ucur[s0 + b]; u01 = ucur[s0 + 32 + b]; u02 = ucur[s0 + 64 + b]; }
    if (m1){ u10 = ucur[s1 + b]; u11 = ucur[s1 + 32 + b]; u12 = ucur[s1 + 64 + b]; }
    if (m2){ u20 = ucur[s2 + b]; u21 = ucur[s2 + 32 + b]; u22 = ucur[s2 + 64 + b]; }
    if (m3){ u30 = ucur[s3 + b]; u31 = ucur[s3 + 32 + b]; u32 = ucur[s3 + 64 + b]; }
    int r0 = (int)(e0.x >> 16), r1 = (int)(e1.x >> 16);
    int r2 = (int)(e2.x >> 16), r3 = (int)(e3.x >> 16);
    float w0 = __uint_as_float(e0.y), w1 = __uint_as_float(e1.y);
    float w2 = __uint_as_float(e2.y), w3 = __uint_as_float(e3.y);
    a0 += q0[r0]*w0*u00 + q0[r1]*w1*u10 + q0[r2]*w2*u20 + q0[r3]*w3*u30;
    a1 += q1[r0]*w0*u01 + q1[r1]*w1*u11 + q1[r2]*w2*u21 + q1[r3]*w3*u31;
    a2 += q2[r0]*w0*u02 + q2[r1]*w1*u12 + q2[r2]*w2*u22 + q2[r3]*w3*u32;
  }
  if (h == 1){
    for (int i = beg + 4 * nq; i < end; ++i){
      uint2 e0 = ents[i];
      int sn0 = (int)(e0.x & 0xFFFFu);
      if (!mask[sn0]) continue;
      size_t s0 = (size_t)sn0 * RB_;
      int r0 = (int)(e0.x >> 16);
      float w0 = __uint_as_float(e0.y);
      a0 += q0[r0] * w0 * ucur[s0 + b];
      a1 += q1[r0] * w0 * ucur[s0 + 32 + b];
      a2 += q2[r0] * w0 * ucur[s0 + 64 + b];
    }
  }
  a0 += __shfl_xor(a0, 32);
  a1 += __shfl_xor(a1, 32);
  a2 += __shfl_xor(a2, 32);
  if (h == 0){
    unxt[nb + b]      = a0;
    unxt[nb + 32 + b] = a1;
    unxt[nb + 64 + b] = a2;
    atomicAdd(&red[b], a0);
    atomicAdd(&red[32 + b], a1);
    atomicAdd(&red[64 + b], a2);
  }
  __syncthreads();
  if (tid < RB_)
    atomicAdd(&partial[(blockIdx.x & (PSLOTS - 1)) * RB_ + tid], red[tid]);
}

// ---- finalize + transpose: out[b][n] = sum_r u[n][r*32+b] / rowsum_r ----
__global__ void fintrans_kernel(const float* __restrict__ u, const float* __restrict__ partial,
                                float* __restrict__ out)
{
  __shared__ float sinv[RB_];
  __shared__ float t[B_][72];
  int tid = threadIdx.x;   // 256
  if (tid < RB_){
    float s = 0.f;
    #pragma unroll 8
    for (int k = 0; k < PSLOTS; ++k) s += partial[k * RB_ + tid];
    sinv[tid] = frcp(fmaxf(1e-20f, s));
  }
  __syncthreads();
  int n0 = blockIdx.x * 64;
  for (int i = tid; i < 64 * B_; i += 256){
    int nl = i >> 5, b = i & 31;
    int n = n0 + nl;
    float v = 0.f;
    if (n < N_){
      size_t nb = (size_t)n * RB_;
      v = u[nb + b] * sinv[b] + u[nb + 32 + b] * sinv[32 + b] + u[nb + 64 + b] * sinv[64 + b];
    }
    t[b][nl] = v;
  }
  __syncthreads();
  for (int i = tid; i < 64 * B_; i += 256){
    int b = i >> 6, nl = i & 63;
    int n = n0 + nl;
    if (n < N_) out[(size_t)b * N_ + n] = t[b][nl];
  }
}

extern "C" void kernel_launch(void* const* d_in, const int* in_sizes, int n_in,
                              void* d_out, int out_size, void* d_ws, size_t ws_size,
                              hipStream_t stream)
{
  const int*   queries = (const int*)d_in[0];
  const int*   heads   = (const int*)d_in[1];
  const int*   rels    = (const int*)d_in[2];
  const int*   t_heads = (const int*)d_in[3];
  const int*   t_tails = (const int*)d_in[4];
  const int*   edeg    = (const int*)d_in[5];
  const float* qemb    = (const float*)d_in[6];
  const float* eemb    = (const float*)d_in[7];
  const float* qWih    = (const float*)d_in[8];
  const float* qWhh    = (const float*)d_in[9];
  const float* qbih    = (const float*)d_in[10];
  const float* qbhh    = (const float*)d_in[11];
  const float* eWih    = (const float*)d_in[12];
  const float* eWhh    = (const float*)d_in[13];
  const float* ebih    = (const float*)d_in[14];
  const float* ebhh    = (const float*)d_in[15];
  const float* qlinW   = (const float*)d_in[16];
  const float* qlinb   = (const float*)d_in[17];
  const float* elinW   = (const float*)d_in[18];
  const float* elinb   = (const float*)d_in[19];
  float* out = (float*)d_out;

  char* ws = (char*)d_ws;
  size_t off = 0;
  auto alloc = [&](size_t bytes){ void* p = ws + off; off += (bytes + 255) & ~(size_t)255; return p; };
  // bigA (25.6 MB): houts during [elstm, eattn]; dead after eattn -> ents (csr_fill).
  char*  bigA  = (char*)alloc((size_t)2 * N_ * H_ * 2);               // 25,600,000
  u16*   houts = (u16*)bigA;                                          // f16 bits
  uint2* ents  = (uint2*)bigA;                                        // in-CSR, 6.4 MB
  // bigB (19.2 MB): attn (4.8 MB) during [eattn, csr_fill]; then u3 (gather3 output).
  char*  bigB  = (char*)alloc((size_t)N_ * RB_ * 4);
  float* attn  = (float*)bigB;
  float* u3    = (float*)bigB;
  float* u2         = (float*)alloc((size_t)N_ * RB_ * 4);            // fresh 19.2 MB
  uint2* ents2      = (uint2*)alloc((size_t)2 * E_ * 8);              // out-CSR, 6.4 MB
  float* query_attn = (float*)alloc((size_t)R_ * T_ * B_ * (OPS_ + 1) * 4);
  u16*   wtile      = (u16*)  alloc((size_t)2 * 32 * 4 * 64 * 8 * 2);
  u16*   wonehot    = (u16*)  alloc((size_t)2 * 32 * 64 * 8 * 2);
  int*   counts     = (int*)  alloc((size_t)(N_ + 1) * 4);
  int*   rowptr     = (int*)  alloc((size_t)(N_ + 1) * 4);
  int*   cursor     = (int*)  alloc((size_t)(N_ + 1) * 4);
  int*   cursor2    = (int*)  alloc((size_t)(N_ + 1) * 4);
  u8*    mask       = (u8*)   alloc((size_t)N_);
  float* sumsP      = (float*)alloc((size_t)PSLOTS * RB_ * 4);        // t2 partials only
  // total ~72 MB

  // counts must be zeroed BEFORE front's csr_count range (same-kernel zeroing
  // would race with the atomics); everything else is zeroed inside front.
  hipMemsetAsync(counts, 0, (size_t)(N_ + 1) * 4, stream);

  // fused qattn | wbuild | csr_count | zero(u2, mask, sumsP)
  front_kernel<<<QB_ + WB_ + CB_ + ZU_ + ZM_ + ZS_, 256, 0, stream>>>(
      queries, qemb, qWih, qWhh, qbih, qbhh, qlinW, qlinb, query_attn,
      eWhh, eemb, eWih, ebih, ebhh, wtile, wonehot,
      t_heads, t_tails, counts, u2, (int*)mask, sumsP);
  // elstm + coalesced csr_scan riding as block 0 (scheduled first -> overlaps)
  elstm_kernel<<<SCANBLK_ + 1, 512, 0, stream>>>(edeg, wtile, wonehot, houts,
                                                 counts, rowptr, cursor, cursor2);
  eattn_kernel<<<256, 256, 0, stream>>>(houts, elinW, elinb, attn);
  // houts dead -> ents may take bigA; attn still live (read by csr_fill):
  csr_fill_kernel<<<(E_ + 255) / 256, 256, 0, stream>>>(rels, t_heads, t_tails, attn,
                                                        cursor, cursor2, ents, ents2);
  // fused t=0 + t=1 sparse propagation into u2 (+ nonzero-row mask)
  t01_kernel<<<RB_, 64, 0, stream>>>(heads, query_attn, rowptr, ents2, u2, mask);
  // t=2: dense gather with mask-gated row loads (attn dead; u3 overwrites bigB)
  gather3_kernel<<<N_ / 4, 256, 0, stream>>>(u2, u3, query_attn, 2, rowptr, ents,
                                             mask, sumsP);
  fintrans_kernel<<<(N_ + 63) / 64, 256, 0, stream>>>(u3, sumsP, out);
}

// Round 9
// 563.810 us; speedup vs baseline: 1.7647x; 1.0382x over previous
//
#include <hip/hip_runtime.h>

#define R_ 3
#define T_ 3
#define N_ 50000
#define OPS_ 24
#define E_ 400000
#define B_ 32
#define MAXDEG_ 8
#define QD_ 128
#define ED_ 128
#define H_ 128
#define G4_ (4*H_)   /* 512 */
#define HPAD 168     /* padded LDS h-row (bf16): 128 h + 25 one-hot + pad, 336 B */
#define PSLOTS 64    /* partial row-sum slots */
#define RB_ 96       /* 3 rounds x 32 batch */

/* front fat-kernel block ranges */
#define QB_ (R_ * B_)                          /* 96  qattn blocks  */
#define WB_ ((2*32*5*64*8 + 255) / 256)        /* 640 wbuild blocks */
#define CB_ ((E_ + 255) / 256)                 /* 1563 csr_count    */
#define ZU_ 1172                               /* u2 zero: 4.8M floats / 4096 */
#define ZM_ 49                                 /* mask zero: 12500 ints / 256 */
#define ZS_ 24                                 /* sumsP zero: 6144 floats / 256 */
#define EB_ 32                                 /* elinW f16-frag build: 8192/256 */
#define SCANBLK_ ((N_ + 31) / 32)              /* 1563 elstm blocks (+1 scan rider) */

typedef unsigned short u16;
typedef unsigned char u8;
typedef __attribute__((ext_vector_type(8))) short bf16x8;     // 8 bf16 = 4 VGPRs
typedef __attribute__((ext_vector_type(8))) _Float16 f16x8;   // 8 f16  = 4 VGPRs
typedef __attribute__((ext_vector_type(4))) float f32x4;

#define BF16_ONE ((short)0x3F80)
#define LOG2E_  1.44269504f
#define LOG2E2_ 2.88539008f

__device__ __forceinline__ short f2bf(float f){
  union { float f; unsigned u; } v; v.f = f;
  unsigned r = v.u + 0x7fffu + ((v.u >> 16) & 1u);
  return (short)(r >> 16);
}
__device__ __forceinline__ float bf2f(u16 u){
  union { unsigned u; float f; } v; v.u = ((unsigned)u) << 16; return v.f;
}
__device__ __forceinline__ float frcp(float x){ return __builtin_amdgcn_rcpf(x); }
__device__ __forceinline__ float fsig(float x){ return frcp(1.0f + __expf(-x)); }
// tanh(x) = 2*sigmoid(2x) - 1
__device__ __forceinline__ float ftanh(float x){
  return __builtin_fmaf(2.0f, fsig(2.0f * x), -1.0f);
}
// 2^x via v_exp_f32 (guarded fallback keeps semantics if builtin missing)
__device__ __forceinline__ float fexp2(float x){
#if __has_builtin(__builtin_amdgcn_exp2f)
  return __builtin_amdgcn_exp2f(x);
#else
  return __expf(x * 0.6931471806f);
#endif
}

// ---------------- query BiLSTM + attention: one virtual block per (r,b) ----------------
__device__ void qattn_body(int bid, const int* __restrict__ queries, const float* __restrict__ qemb,
    const float* __restrict__ qWih, const float* __restrict__ qWhh,
    const float* __restrict__ qbih, const float* __restrict__ qbhh,
    const float* __restrict__ qlinW, const float* __restrict__ qlinb,
    float* __restrict__ query_attn /* R,T,B,25 */)
{
  int r = bid / B_;
  int b = bid % B_;
  int tid = threadIdx.x;   // 256
  __shared__ float x[QD_];
  __shared__ float gx[G4_];
  __shared__ float h[H_], c[H_];
  __shared__ float gtmp[G4_];
  __shared__ float hh[2][T_][H_];
  __shared__ float lg[OPS_ + 1];

  int q = queries[b];
  if (tid < QD_) x[tid] = qemb[q * QD_ + tid];
  __syncthreads();

  for (int dir = 0; dir < 2; ++dir){
    const float* Wih = qWih + (size_t)(r * 2 + dir) * G4_ * QD_;
    const float* Whh = qWhh + (size_t)(r * 2 + dir) * G4_ * H_;
    const float* bih = qbih + (r * 2 + dir) * G4_;
    const float* bhh = qbhh + (r * 2 + dir) * G4_;
    for (int j = tid; j < G4_; j += 256){
      const float4* wr = (const float4*)(Wih + (size_t)j * QD_);
      float s = bih[j] + bhh[j];
      for (int k = 0; k < QD_ / 4; ++k){
        float4 wv = wr[k];
        s += wv.x * x[4*k] + wv.y * x[4*k+1] + wv.z * x[4*k+2] + wv.w * x[4*k+3];
      }
      gx[j] = s;
    }
    if (tid < H_){ h[tid] = 0.f; c[tid] = 0.f; }
    __syncthreads();
    for (int t = 0; t < T_; ++t){
      for (int j = tid; j < G4_; j += 256){
        const float4* wr = (const float4*)(Whh + (size_t)j * H_);
        float s = 0.f;
        for (int k = 0; k < H_ / 4; ++k){
          float4 wv = wr[k];
          s += wv.x * h[4*k] + wv.y * h[4*k+1] + wv.z * h[4*k+2] + wv.w * h[4*k+3];
        }
        gtmp[j] = gx[j] + s;
      }
      __syncthreads();
      if (tid < H_){
        float gi = gtmp[tid], gf = gtmp[tid + H_], gg = gtmp[tid + 2*H_], go = gtmp[tid + 3*H_];
        float cn = fsig(gf) * c[tid] + fsig(gi) * ftanh(gg);
        float hn = fsig(go) * ftanh(cn);
        c[tid] = cn; h[tid] = hn;
        hh[dir][t][tid] = hn;
      }
      __syncthreads();
    }
  }

  for (int t = 0; t < T_; ++t){
    if (tid < OPS_ + 1){
      const float* wr = qlinW + tid * (2 * H_);
      float s = qlinb[tid];
      for (int k = 0; k < H_; ++k) s += wr[k] * hh[0][t][k];
      for (int k = 0; k < H_; ++k) s += wr[H_ + k] * hh[1][T_ - 1 - t][k];
      lg[tid] = s;
    }
    __syncthreads();
    if (tid == 0){
      float m = -1e30f;
      for (int o = 0; o < OPS_ + 1; ++o) m = fmaxf(m, lg[o]);
      float sum = 0.f;
      for (int o = 0; o < OPS_ + 1; ++o){ float e = __expf(lg[o] - m); lg[o] = e; sum += e; }
      float inv = frcp(sum);
      for (int o = 0; o < OPS_ + 1; ++o) lg[o] *= inv;
    }
    __syncthreads();
    if (tid < OPS_ + 1) query_attn[((size_t)(r * T_ + t) * B_ + b) * (OPS_ + 1) + tid] = lg[tid];
    __syncthreads();
  }
}

// ---- build B-operand buffers in MFMA-fragment order (eproj folded in) ----
// Gate rows are PRE-SCALED by log2(e) (gates i,f,o) / 2*log2(e) (gate g) so the
// LSTM activation can use raw v_exp_f32 (=2^x) without per-exp ln2 muls.
__device__ void wbuild_body(int bid, const float* __restrict__ eWhh,
                            const float* __restrict__ eemb, const float* __restrict__ eWih,
                            const float* __restrict__ ebih, const float* __restrict__ ebhh,
                            u16* __restrict__ wtile, u16* __restrict__ wonehot)
{
  int idx = bid * 256 + threadIdx.x;    // 2*32*5*64*8 = 163840
  if (idx >= 2 * 32 * 5 * 64 * 8) return;
  int jj = idx & 7;
  int lane = (idx >> 3) & 63;
  int kc = (idx >> 9) % 5;
  int gtile = (idx / (8 * 64 * 5)) & 31;
  int dir = idx / (8 * 64 * 5 * 32);
  int row = lane >> 4, col = lane & 15;
  int j = gtile * 16 + col;
  float sc = ((gtile >> 3) == 2) ? LOG2E2_ : LOG2E_;   // gate g rows get 2*log2e
  if (kc < 4){
    int k = kc * 32 + row * 8 + jj;
    float v = eWhh[((size_t)dir * G4_ + j) * H_ + k] * sc;
    wtile[((((size_t)dir * 32 + gtile) * 4 + kc) * 64 + lane) * 8 + jj] = (u16)f2bf(v);
  } else {
    int vdeg = row * 8 + jj;   // 0..31
    float v = 0.f;
    if (vdeg <= OPS_){
      const float4* wr = (const float4*)(eWih + (size_t)(dir * G4_ + j) * ED_);
      const float4* er = (const float4*)(eemb + (size_t)vdeg * ED_);
      float s = ebih[dir * G4_ + j] + ebhh[dir * G4_ + j];
      for (int k = 0; k < ED_ / 4; ++k){
        float4 wv = wr[k], ev = er[k];
        s += wv.x * ev.x + wv.y * ev.y + wv.z * ev.z + wv.w * ev.w;
      }
      v = s * sc;
    }
    wonehot[(((size_t)dir * 32 + gtile) * 64 + lane) * 8 + jj] = (u16)f2bf(v);
  }
}

__device__ void csr_count_body(int bid, const int* __restrict__ theads,
                               const int* __restrict__ ttails, int* __restrict__ counts)
{
  int e = bid * 256 + threadIdx.x;
  if (e < E_){
    atomicAdd(&counts[ttails[e]], 1);
    atomicAdd(&counts[theads[e]], 1);
  }
}

// ---- front fat-kernel: qattn | wbuild | csr_count | zero(u2,mask,sumsP) | etile.
// All mutually independent; outputs consumed only by later dispatches.
__global__ __launch_bounds__(256) void front_kernel(
    const int* queries, const float* qemb,
    const float* qWih, const float* qWhh, const float* qbih, const float* qbhh,
    const float* qlinW, const float* qlinb, float* query_attn,
    const float* eWhh, const float* eemb, const float* eWih,
    const float* ebih, const float* ebhh, u16* wtile, u16* wonehot,
    const int* theads, const int* ttails, int* counts,
    float* u2, int* maski, float* sumsP,
    const float* elinW, u16* etile)
{
  int bid = blockIdx.x;
  int tid = threadIdx.x;
  if (bid < QB_){
    qattn_body(bid, queries, qemb, qWih, qWhh, qbih, qbhh, qlinW, qlinb, query_attn);
  } else if (bid < QB_ + WB_){
    wbuild_body(bid - QB_, eWhh, eemb, eWih, ebih, ebhh, wtile, wonehot);
  } else if (bid < QB_ + WB_ + CB_){
    csr_count_body(bid - QB_ - WB_, theads, ttails, counts);
  } else if (bid < QB_ + WB_ + CB_ + ZU_){
    int zb = bid - QB_ - WB_ - CB_;
    float4 z = {0.f, 0.f, 0.f, 0.f};
    size_t base = (size_t)zb * 4096 + tid * 4;
    #pragma unroll
    for (int k = 0; k < 4; ++k){
      size_t idx = base + (size_t)k * 1024;
      if (idx < (size_t)N_ * RB_) *(float4*)&u2[idx] = z;
    }
  } else if (bid < QB_ + WB_ + CB_ + ZU_ + ZM_){
    int mi = (bid - QB_ - WB_ - CB_ - ZU_) * 256 + tid;
    if (mi < (N_ + 3) / 4) maski[mi] = 0;
  } else if (bid < QB_ + WB_ + CB_ + ZU_ + ZM_ + ZS_){
    int si = (bid - QB_ - WB_ - CB_ - ZU_ - ZM_) * 256 + tid;
    if (si < PSLOTS * RB_) sumsP[si] = 0.f;
  } else {
    // elinW -> f16 MFMA B-frags: [2 op-tiles][8 ksteps][64 lanes][8] (16 KB)
    int idx = (bid - (QB_ + WB_ + CB_ + ZU_ + ZM_ + ZS_)) * 256 + tid;   // 0..8191
    int jj = idx & 7;
    int lane = (idx >> 3) & 63;
    int ks = (idx >> 9) & 7;
    int ot = idx >> 12;
    int op = ot * 16 + (lane & 15);
    int k  = ks * 32 + (lane >> 4) * 8 + jj;
    float v = (op < OPS_) ? elinW[(size_t)op * (2 * H_) + k] : 0.f;
    _Float16 hv = (_Float16)v;
    etile[idx] = *(const u16*)&hv;
  }
}

// ---- coalesced tile scan (512 threads, rides as block 0 of the elstm grid).
__device__ void scan_body(const int* __restrict__ counts, int* __restrict__ rowptr,
                          int* __restrict__ cursor, int* __restrict__ cursor2)
{
  __shared__ int wsum[8];
  int t = threadIdx.x;
  int lane = t & 63, wv = t >> 6;
  int carry = 0;   // live only in thread 0
  for (int base = 0; base < N_; base += 2048){
    int idx = base + t * 4;
    int c0 = 0, c1 = 0, c2 = 0, c3 = 0;
    if (idx + 3 < N_){
      int4 c = *(const int4*)&counts[idx];
      c0 = c.x; c1 = c.y; c2 = c.z; c3 = c.w;
    } else {
      if (idx     < N_) c0 = counts[idx];
      if (idx + 1 < N_) c1 = counts[idx + 1];
      if (idx + 2 < N_) c2 = counts[idx + 2];
      if (idx + 3 < N_) c3 = counts[idx + 3];
    }
    int s = c0 + c1 + c2 + c3;
    int sc = s;                          // inclusive wave scan
    #pragma unroll
    for (int off = 1; off < 64; off <<= 1){
      int v = __shfl_up(sc, off);
      if (lane >= off) sc += v;
    }
    if (lane == 63) wsum[wv] = sc;
    __syncthreads();
    if (t == 0){
      int acc = carry;
      #pragma unroll
      for (int w = 0; w < 8; ++w){ int v = wsum[w]; wsum[w] = acc; acc += v; }
      carry = acc;
    }
    __syncthreads();
    int excl = wsum[wv] + (sc - s);
    int r0 = excl, r1 = r0 + c0, r2 = r1 + c1, r3 = r2 + c2;
    if (idx + 3 < N_){
      int4 rv; rv.x = r0; rv.y = r1; rv.z = r2; rv.w = r3;
      *(int4*)&rowptr[idx]  = rv;
      *(int4*)&cursor[idx]  = rv;
      *(int4*)&cursor2[idx] = rv;
    } else {
      if (idx     < N_){ rowptr[idx]   = r0; cursor[idx]   = r0; cursor2[idx]   = r0; }
      if (idx + 1 < N_){ rowptr[idx+1] = r1; cursor[idx+1] = r1; cursor2[idx+1] = r1; }
      if (idx + 2 < N_){ rowptr[idx+2] = r2; cursor[idx+2] = r2; cursor2[idx+2] = r2; }
      if (idx + 3 < N_){ rowptr[idx+3] = r3; cursor[idx+3] = r3; cursor2[idx+3] = r3; }
    }
  }
  if (t == 0) rowptr[N_] = carry;
}

// ------ entity BiLSTM: 512 threads / 8 waves / 32 entities per block ------
// + block 0 runs the CSR exclusive scan concurrently.
// + LDS write swizzle: activation writes hw[e][j] had row-stride 336B = 16 banks
//   -> 4-way conflict across the wave's 4 row groups. XOR the 16B-block index
//   (jb = j>>3) with (e>>2)&3: rows land {0,20,8,28} banks apart -> only the
//   free 2-way col pairing remains. Reads use block-granular XOR -> still b128.
// + fused entity-attention epilogue (replaces eattn kernel + houts round-trip):
//   dir0 final h preserved in hfin; logits via f16 MFMA (A = bf16 h widened to
//   f16 in-register -> bit-identical to the old f16 eattn), softmax, attn write.
// launch_bounds(512,4): cap 128 regs -> ~60 VGPR + 32 AGPR, no spill.
__global__ __launch_bounds__(512, 4) void elstm_kernel(
    const int* __restrict__ degs,
    const u16* __restrict__ wtile, const u16* __restrict__ wonehot,
    const u16* __restrict__ etile, const float* __restrict__ elinb,
    float* __restrict__ attn /* N,24 */,
    const int* __restrict__ counts, int* __restrict__ rowptr,
    int* __restrict__ cursor, int* __restrict__ cursor2)
{
  if (blockIdx.x == 0){ scan_body(counts, rowptr, cursor, cursor2); return; }

  int tid = threadIdx.x;
  int lane = tid & 63;
  int w = tid >> 6;          // wave 0..7
  int wu = __builtin_amdgcn_readfirstlane(w);   // provably wave-uniform
  int row = lane >> 4, col = lane & 15;
  int ebase = (blockIdx.x - 1) * 32;

  __shared__ __align__(16) short hl[2][32 * HPAD];   // 2 x 10.5 KB ping-pong
  __shared__ __align__(16) short hfin[32 * 136];     // dir0 final h (8.5 KB)
  __shared__ float lgs[32][33];                      // epilogue logits (4.2 KB)

  int eg0 = ebase + tid; if (eg0 >= N_) eg0 = N_ - 1;   // valid for tid<32 use

  for (int i = tid; i < 2 * 32 * HPAD; i += 512) ((short*)hl)[i] = 0;
  __syncthreads();
  if (tid < 32) hl[0][tid * HPAD + H_ + degs[(size_t)eg0 * MAXDEG_ + 0]] = BF16_ONE;
  __syncthreads();

  int swzr = (col >> 2) & 3;   // read-side swizzle for entities col and 16+col

  for (int dir = 0; dir < 2; ++dir){
    const u16* Wt  = wtile   + (size_t)dir * 32 * 4 * 64 * 8;
    const u16* Woh = wonehot + (size_t)dir * 32 * 64 * 8;
    // per-gate scalar bases (gtile = g*8 + wu)
    const u16* W0 = Wt + (size_t)((0 * 8 + wu) * 4 * 64) * 8;
    const u16* W1 = Wt + (size_t)((1 * 8 + wu) * 4 * 64) * 8;
    const u16* W2 = Wt + (size_t)((2 * 8 + wu) * 4 * 64) * 8;
    const u16* W3 = Wt + (size_t)((3 * 8 + wu) * 4 * 64) * 8;
    const u16* O0 = Woh + (size_t)((0 * 8 + wu) * 64) * 8;
    const u16* O1 = Woh + (size_t)((1 * 8 + wu) * 64) * 8;
    const u16* O2 = Woh + (size_t)((2 * 8 + wu) * 64) * 8;
    const u16* O3 = Woh + (size_t)((3 * 8 + wu) * 64) * 8;
    float cst[8];
    #pragma unroll
    for (int i = 0; i < 8; ++i) cst[i] = 0.f;

    for (int t = 0; t < MAXDEG_; ++t){
      const short* hb = hl[t & 1];          // holds h_t (+ one-hot for step t)
      short*       hw = hl[(t + 1) & 1];    // receives h_{t+1}
      f32x4 acc[8];
      #pragma unroll
      for (int i = 0; i < 8; ++i) acc[i] = (f32x4){0.f, 0.f, 0.f, 0.f};

      #pragma unroll 2
      for (int kc = 0; kc < 4; ++kc){
        bf16x8 af0 = *(const bf16x8*)&hb[(col) * HPAD + kc * 32 + (row ^ swzr) * 8];
        bf16x8 af1 = *(const bf16x8*)&hb[(16 + col) * HPAD + kc * 32 + (row ^ swzr) * 8];
        int lo = (kc * 64 + lane) * 8;
        bf16x8 b0 = *(const bf16x8*)(W0 + lo);
        bf16x8 b1 = *(const bf16x8*)(W1 + lo);
        bf16x8 b2 = *(const bf16x8*)(W2 + lo);
        bf16x8 b3 = *(const bf16x8*)(W3 + lo);
        acc[0] = __builtin_amdgcn_mfma_f32_16x16x32_bf16(af0, b0, acc[0], 0, 0, 0);
        acc[1] = __builtin_amdgcn_mfma_f32_16x16x32_bf16(af1, b0, acc[1], 0, 0, 0);
        acc[2] = __builtin_amdgcn_mfma_f32_16x16x32_bf16(af0, b1, acc[2], 0, 0, 0);
        acc[3] = __builtin_amdgcn_mfma_f32_16x16x32_bf16(af1, b1, acc[3], 0, 0, 0);
        acc[4] = __builtin_amdgcn_mfma_f32_16x16x32_bf16(af0, b2, acc[4], 0, 0, 0);
        acc[5] = __builtin_amdgcn_mfma_f32_16x16x32_bf16(af1, b2, acc[5], 0, 0, 0);
        acc[6] = __builtin_amdgcn_mfma_f32_16x16x32_bf16(af0, b3, acc[6], 0, 0, 0);
        acc[7] = __builtin_amdgcn_mfma_f32_16x16x32_bf16(af1, b3, acc[7], 0, 0, 0);
      }
      {
        bf16x8 af0 = *(const bf16x8*)&hb[(col) * HPAD + H_ + row * 8];
        bf16x8 af1 = *(const bf16x8*)&hb[(16 + col) * HPAD + H_ + row * 8];
        int lo = lane * 8;
        bf16x8 b0 = *(const bf16x8*)(O0 + lo);
        bf16x8 b1 = *(const bf16x8*)(O1 + lo);
        bf16x8 b2 = *(const bf16x8*)(O2 + lo);
        bf16x8 b3 = *(const bf16x8*)(O3 + lo);
        acc[0] = __builtin_amdgcn_mfma_f32_16x16x32_bf16(af0, b0, acc[0], 0, 0, 0);
        acc[1] = __builtin_amdgcn_mfma_f32_16x16x32_bf16(af1, b0, acc[1], 0, 0, 0);
        acc[2] = __builtin_amdgcn_mfma_f32_16x16x32_bf16(af0, b1, acc[2], 0, 0, 0);
        acc[3] = __builtin_amdgcn_mfma_f32_16x16x32_bf16(af1, b1, acc[3], 0, 0, 0);
        acc[4] = __builtin_amdgcn_mfma_f32_16x16x32_bf16(af0, b2, acc[4], 0, 0, 0);
        acc[5] = __builtin_amdgcn_mfma_f32_16x16x32_bf16(af1, b2, acc[5], 0, 0, 0);
        acc[6] = __builtin_amdgcn_mfma_f32_16x16x32_bf16(af0, b3, acc[6], 0, 0, 0);
        acc[7] = __builtin_amdgcn_mfma_f32_16x16x32_bf16(af1, b3, acc[7], 0, 0, 0);
      }

      // activation (gates pre-scaled by log2e / 2log2e):
      // cn = [cst*(1+ea)(1+eb) + (1-eb)(1+ef)] / [(1+ef)(1+ea)(1+eb)]
      // hn = (1-ed) / [(1+eo)(1+ed)],  ed = 2^(-2*log2e*cn)
      #pragma unroll
      for (int mt = 0; mt < 2; ++mt){
        #pragma unroll
        for (int reg = 0; reg < 4; ++reg){
          int e = mt * 16 + row * 4 + reg;
          // swizzled write: logical j = wu*16+col; jb = wu*2+(col>>3);
          // swz = (e>>2)&3 = row; j' = (jb^row)*8 + (col&7)
          int jsw = (((wu * 2 + (col >> 3)) ^ row) * 8) + (col & 7);
          float Gi = acc[0 + mt][reg];
          float Gf = acc[2 + mt][reg];
          float Gg = acc[4 + mt][reg];
          float Go = acc[6 + mt][reg];
          int ci = mt * 4 + reg;
          float ea = fexp2(-Gi);
          float ef = fexp2(-Gf);
          float eb = fexp2(-Gg);
          float eo = fexp2(-Go);
          float t1 = 1.f + ef, t2 = 1.f + ea, t3 = 1.f + eb;
          float p = t2 * t3;
          float num = __builtin_fmaf(cst[ci], p, (1.f - eb) * t1);
          float cn = num * frcp(t1 * p);
          float ed = fexp2(cn * (-LOG2E2_));
          float hn = (1.f - ed) * frcp((1.f + eo) * (1.f + ed));
          cst[ci] = cn;
          hw[e * HPAD + jsw] = f2bf(hn);
        }
      }
      // one-hot maintenance on the write buffer (j >= 128 region: unswizzled).
      if (tid < 32){
        const int* dr = degs + (size_t)eg0 * MAXDEG_;
        if (t >= 1)
          hw[tid * HPAD + H_ + dr[dir ? (MAXDEG_ - t) : (t - 1)]] = 0;
        if (t < MAXDEG_ - 1)
          hw[tid * HPAD + H_ + dr[dir ? (MAXDEG_ - 2 - t) : (t + 1)]] = BF16_ONE;
      }
      __syncthreads();
    }

    if (dir == 0){
      // preserve dir0 final h (MAXDEG_ even -> in hl[0]) for the epilogue,
      // unswizzling 16B chunks: physical chunk = logical c ^ ((e>>2)&3).
      for (int i = tid; i < 32 * 16; i += 512){
        int e = i >> 4, c = i & 15;
        int sz = (e >> 2) & 3;
        *(bf16x8*)&hfin[e * 136 + c * 8] =
            *(const bf16x8*)&hl[0][e * HPAD + ((c ^ sz) * 8)];
      }
      __syncthreads();
      for (int i = tid; i < 2 * 32 * HPAD; i += 512) ((short*)hl)[i] = 0;
      __syncthreads();
      if (tid < 32) hl[0][tid * HPAD + H_ + degs[(size_t)eg0 * MAXDEG_ + (MAXDEG_ - 1)]] = BF16_ONE;
      __syncthreads();
    }
  }

  // ---- fused entity-attention epilogue: logits = [hf|hb] @ elinW^T (f16 MFMA).
  // Waves 0-3: wave wu computes tile (mt = wu>>1 entities, ot = wu&1 op-group).
  // C layout: op = ot*16 + (lane&15), entity = mt*16 + (lane>>4)*4 + reg.
  if (wu < 4){
    int mt = wu >> 1, ot = wu & 1;
    int e2 = mt * 16 + col;
    f32x4 accL = (f32x4){0.f, 0.f, 0.f, 0.f};
    #pragma unroll
    for (int ks = 0; ks < 8; ++ks){
      bf16x8 ra;
      if (ks < 4) ra = *(const bf16x8*)&hfin[e2 * 136 + ks * 32 + row * 8];
      else        ra = *(const bf16x8*)&hl[0][e2 * HPAD + (ks - 4) * 32 + (row ^ swzr) * 8];
      f16x8 af;
      #pragma unroll
      for (int jj = 0; jj < 8; ++jj) af[jj] = (_Float16)bf2f((u16)ra[jj]);
      f16x8 bfr = *(const f16x8*)(etile + (((size_t)(ot * 8 + ks)) * 64 + lane) * 8);
      accL = __builtin_amdgcn_mfma_f32_16x16x32_f16(af, bfr, accL, 0, 0, 0);
    }
    #pragma unroll
    for (int reg = 0; reg < 4; ++reg){
      int ent = mt * 16 + (lane >> 4) * 4 + reg;
      int op  = ot * 16 + (lane & 15);
      float bb = (op < OPS_) ? elinb[op] : 0.f;
      lgs[ent][op] = accL[reg] + bb;
    }
  }
  __syncthreads();
  if (tid < 32){
    int n = ebase + tid;
    if (n < N_){
      float m = -1e30f;
      #pragma unroll
      for (int o = 0; o < OPS_; ++o) m = fmaxf(m, lgs[tid][o]);
      float s = 0.f;
      #pragma unroll
      for (int o = 0; o < OPS_; ++o) s += __expf(lgs[tid][o] - m);
      float inv = frcp(s);
      #pragma unroll
      for (int o = 0; o < OPS_; ++o)
        attn[(size_t)n * OPS_ + o] = __expf(lgs[tid][o] - m) * inv;
    }
  }
}

__global__ void csr_fill_kernel(const int* __restrict__ rels, const int* __restrict__ theads,
                                const int* __restrict__ ttails, const float* __restrict__ attn,
                                int* __restrict__ cursor, int* __restrict__ cursor2,
                                uint2* __restrict__ ents, uint2* __restrict__ ents2)
{
  int e = blockIdx.x * 256 + threadIdx.x;
  if (e < E_){
    int hh = theads[e], tt = ttails[e], rel = rels[e];
    unsigned wb = __float_as_uint(attn[(size_t)hh * OPS_ + rel]);
    uint2 v1; v1.x = (unsigned)hh | ((unsigned)rel << 16);            v1.y = wb;
    uint2 v2; v2.x = (unsigned)tt | ((unsigned)(rel + OPS_/2) << 16); v2.y = wb;
    ents[atomicAdd(&cursor[tt], 1)] = v1;
    ents[atomicAdd(&cursor[hh], 1)] = v2;
    uint2 w1; w1.x = (unsigned)tt | ((unsigned)rel << 16);            w1.y = wb;
    uint2 w2; w2.x = (unsigned)hh | ((unsigned)(rel + OPS_/2) << 16); w2.y = wb;
    ents2[atomicAdd(&cursor2[hh], 1)] = w1;
    ents2[atomicAdd(&cursor2[tt], 1)] = w2;
  }
}

// ---- fused sparse t=0 + t=1 (normalization telescopes -> everything linear):
// u2[head]  += qa1[24]*qa0[24]                                   (self o self)
// u2[s]     += w1*(qa1[24]*qa0[r1] + qa1[r1]*qa0[24])  per e1(head->s)
// u2[d]     += qa1[r2]*w2 * qa0[r1]*w1                 per e1,e2(s->d)
// Also marks the nonzero-row mask (only r==0 blocks; reachability is r-independent).
__global__ void t01_kernel(const int* __restrict__ heads, const float* __restrict__ query_attn,
                           const int* __restrict__ rowptr, const uint2* __restrict__ ents2,
                           float* __restrict__ u2, u8* __restrict__ mask)
{
  __shared__ float qa0[OPS_ + 1], qa1[OPS_ + 1];
  int blk = blockIdx.x;   // 0..95
  int r = blk >> 5, b = blk & 31;
  int rb = r * 32 + b;
  int tid = threadIdx.x;  // 64
  if (tid < OPS_ + 1){
    qa0[tid] = query_attn[((size_t)(r * T_ + 0) * B_ + b) * (OPS_ + 1) + tid];
    qa1[tid] = query_attn[((size_t)(r * T_ + 1) * B_ + b) * (OPS_ + 1) + tid];
  }
  __syncthreads();
  int hd = heads[b];
  int beg = rowptr[hd], end = rowptr[hd + 1];
  float q024 = qa0[OPS_], q124 = qa1[OPS_];
  bool mark = (r == 0);
  if (tid == 0){
    atomicAdd(&u2[(size_t)hd * RB_ + rb], q124 * q024);
    if (mark) mask[hd] = 1;
  }
  for (int i = beg + tid; i < end; i += 64){
    uint2 e1 = ents2[i];
    int s  = (int)(e1.x & 0xFFFFu);
    int r1 = (int)(e1.x >> 16);
    float w1 = __uint_as_float(e1.y);
    atomicAdd(&u2[(size_t)s * RB_ + rb], w1 * (q124 * qa0[r1] + qa1[r1] * q024));
    if (mark) mask[s] = 1;
    float v1 = qa0[r1] * w1;      // this path's share of u1[s]
    int b2 = rowptr[s], e2e = rowptr[s + 1];
    for (int jj = b2; jj < e2e; ++jj){
      uint2 e2 = ents2[jj];
      int d2 = (int)(e2.x & 0xFFFFu);
      int r2 = (int)(e2.x >> 16);
      atomicAdd(&u2[(size_t)d2 * RB_ + rb], qa1[r2] * __uint_as_float(e2.y) * v1);
      if (mark) mask[d2] = 1;
    }
  }
}

// ---- batched dense gather (t=2): ONE WAVE per node, halves split 4-edge chunks.
// u2 is nonzero on only ~9k/50k rows: mask[] gates the 3x128B row loads per edge.
__global__ __launch_bounds__(256) void gather3_kernel(
    const float* __restrict__ ucur, float* __restrict__ unxt,
    const float* __restrict__ query_attn, int t,
    const int* __restrict__ rowptr, const uint2* __restrict__ ents,
    const u8* __restrict__ mask,
    float* __restrict__ partial /* PSLOTS x 96 */)
{
  __shared__ float qas[3 * B_ * (OPS_ + 1)];  // [r][b][o]
  __shared__ float red[RB_];
  int tid = threadIdx.x;
  for (int i = tid; i < 3 * B_ * (OPS_ + 1); i += 256){
    int r = i / (B_ * (OPS_ + 1));
    int rem = i - r * (B_ * (OPS_ + 1));
    qas[i] = query_attn[(size_t)(r * T_ + t) * B_ * (OPS_ + 1) + rem];
  }
  if (tid < RB_) red[tid] = 0.f;
  __syncthreads();
  int b  = tid & 31;
  int h  = (tid >> 5) & 1;              // half within wave
  int n = blockIdx.x * 4 + (tid >> 6);  // one wave per node; grid*4 == N_
  const float* q0 = &qas[0 * 800 + b * (OPS_ + 1)];
  const float* q1 = &qas[1 * 800 + b * (OPS_ + 1)];
  const float* q2 = &qas[2 * 800 + b * (OPS_ + 1)];
  size_t nb = (size_t)n * RB_;
  float a0 = 0.f, a1 = 0.f, a2 = 0.f;
  if (h == 0 && mask[n]){
    a0 = ucur[nb + b]      * q0[OPS_];
    a1 = ucur[nb + 32 + b] * q1[OPS_];
    a2 = ucur[nb + 64 + b] * q2[OPS_];
  }
  int beg = rowptr[n], end = rowptr[n + 1];
  int cnt = end - beg;
  int nq = cnt >> 2;                 // full 4-edge chunks
  for (int c = h; c < nq; c += 2){
    int i0 = beg + 4 * c;
    uint2 e0 = ents[i0 + 0];
    uint2 e1 = ents[i0 + 1];
    uint2 e2 = ents[i0 + 2];
    uint2 e3 = ents[i0 + 3];
    int sn0 = (int)(e0.x & 0xFFFFu);
    int sn1 = (int)(e1.x & 0xFFFFu);
    int sn2 = (int)(e2.x & 0xFFFFu);
    int sn3 = (int)(e3.x & 0xFFFFu);
    int m0 = mask[sn0], m1 = mask[sn1], m2 = mask[sn2], m3 = mask[sn3];
    if (!(m0 | m1 | m2 | m3)) continue;
    size_t s0 = (size_t)sn0 * RB_;
    size_t s1 = (size_t)sn1 * RB_;
    size_t s2 = (size_t)sn2 * RB_;
    size_t s3 = (size_t)sn3 * RB_;
    float u00 = 0.f, u01 = 0.f, u02 = 0.f;
    float u10 = 0.f, u11 = 0.f, u12 = 0.f;
    float u20 = 0.f, u21 = 0.f, u22 = 0.f;
    float u30 = 0.f, u31 = 0.f, u32 = 0.f;
    if (m0){ u00 = ucur[s0 + b]; u01 = ucur[s0 + 32 + b]; u02 = ucur[s0 + 64 + b]; }
    if (m1){ u10 = ucur[s1 + b]; u11 = ucur[s1 + 32 + b]; u12 = ucur[s1 + 64 + b]; }
    if (m2){ u20 = ucur[s2 + b]; u21 = ucur[s2 + 32 + b]; u22 = ucur[s2 + 64 + b]; }
    if (m3){ u30 = ucur[s3 + b]; u31 = ucur[s3 + 32 + b]; u32 = ucur[s3 + 64 + b]; }
    int r0 = (int)(e0.x >> 16), r1 = (int)(e1.x >> 16);
    int r2 = (int)(e2.x >> 16), r3 = (int)(e3.x >> 16);
    float w0 = __uint_as_float(e0.y), w1 = __uint_as_float(e1.y);
    float w2 = __uint_as_float(e2.y), w3 = __uint_as_float(e3.y);
    a0 += q0[r0]*w0*u00 + q0[r1]*w1*u10 + q0[r2]*w2*u20 + q0[r3]*w3*u30;
    a1 += q1[r0]*w0*u01 + q1[r1]*w1*u11 + q1[r2]*w2*u21 + q1[r3]*w3*u31;
    a2 += q2[r0]*w0*u02 + q2[r1]*w1*u12 + q2[r2]*w2*u22 + q2[r3]*w3*u32;
  }
  if (h == 1){
    for (int i = beg + 4 * nq; i < end; ++i){
      uint2 e0 = ents[i];
      int sn0 = (int)(e0.x & 0xFFFFu);
      if (!mask[sn0]) continue;
      size_t s0 = (size_t)sn0 * RB_;
      int r0 = (int)(e0.x >> 16);
      float w0 = __uint_as_float(e0.y);
      a0 += q0[r0] * w0 * ucur[s0 + b];
      a1 += q1[r0] * w0 * ucur[s0 + 32 + b];
      a2 += q2[r0] * w0 * ucur[s0 + 64 + b];
    }
  }
  a0 += __shfl_xor(a0, 32);
  a1 += __shfl_xor(a1, 32);
  a2 += __shfl_xor(a2, 32);
  if (h == 0){
    unxt[nb + b]      = a0;
    unxt[nb + 32 + b] = a1;
    unxt[nb + 64 + b] = a2;
    atomicAdd(&red[b], a0);
    atomicAdd(&red[32 + b], a1);
    atomicAdd(&red[64 + b], a2);
  }
  __syncthreads();
  if (tid < RB_)
    atomicAdd(&partial[(blockIdx.x & (PSLOTS - 1)) * RB_ + tid], red[tid]);
}

// ---- finalize + transpose: out[b][n] = sum_r u[n][r*32+b] / rowsum_r ----
__global__ void fintrans_kernel(const float* __restrict__ u, const float* __restrict__ partial,
                                float* __restrict__ out)
{
  __shared__ float sinv[RB_];
  __shared__ float t[B_][72];
  int tid = threadIdx.x;   // 256
  if (tid < RB_){
    float s = 0.f;
    #pragma unroll 8
    for (int k = 0; k < PSLOTS; ++k) s += partial[k * RB_ + tid];
    sinv[tid] = frcp(fmaxf(1e-20f, s));
  }
  __syncthreads();
  int n0 = blockIdx.x * 64;
  for (int i = tid; i < 64 * B_; i += 256){
    int nl = i >> 5, b = i & 31;
    int n = n0 + nl;
    float v = 0.f;
    if (n < N_){
      size_t nb = (size_t)n * RB_;
      v = u[nb + b] * sinv[b] + u[nb + 32 + b] * sinv[32 + b] + u[nb + 64 + b] * sinv[64 + b];
    }
    t[b][nl] = v;
  }
  __syncthreads();
  for (int i = tid; i < 64 * B_; i += 256){
    int b = i >> 6, nl = i & 63;
    int n = n0 + nl;
    if (n < N_) out[(size_t)b * N_ + n] = t[b][nl];
  }
}

extern "C" void kernel_launch(void* const* d_in, const int* in_sizes, int n_in,
                              void* d_out, int out_size, void* d_ws, size_t ws_size,
                              hipStream_t stream)
{
  const int*   queries = (const int*)d_in[0];
  const int*   heads   = (const int*)d_in[1];
  const int*   rels    = (const int*)d_in[2];
  const int*   t_heads = (const int*)d_in[3];
  const int*   t_tails = (const int*)d_in[4];
  const int*   edeg    = (const int*)d_in[5];
  const float* qemb    = (const float*)d_in[6];
  const float* eemb    = (const float*)d_in[7];
  const float* qWih    = (const float*)d_in[8];
  const float* qWhh    = (const float*)d_in[9];
  const float* qbih    = (const float*)d_in[10];
  const float* qbhh    = (const float*)d_in[11];
  const float* eWih    = (const float*)d_in[12];
  const float* eWhh    = (const float*)d_in[13];
  const float* ebih    = (const float*)d_in[14];
  const float* ebhh    = (const float*)d_in[15];
  const float* qlinW   = (const float*)d_in[16];
  const float* qlinb   = (const float*)d_in[17];
  const float* elinW   = (const float*)d_in[18];
  const float* elinb   = (const float*)d_in[19];
  float* out = (float*)d_out;

  char* ws = (char*)d_ws;
  size_t off = 0;
  auto alloc = [&](size_t bytes){ void* p = ws + off; off += (bytes + 255) & ~(size_t)255; return p; };
  // bigB (19.2 MB): attn (4.8 MB) during [elstm, csr_fill]; then u3 (gather3 out).
  char*  bigB  = (char*)alloc((size_t)N_ * RB_ * 4);
  float* attn  = (float*)bigB;
  float* u3    = (float*)bigB;
  uint2* ents       = (uint2*)alloc((size_t)2 * E_ * 8);              // in-CSR, 6.4 MB
  float* u2         = (float*)alloc((size_t)N_ * RB_ * 4);            // 19.2 MB
  uint2* ents2      = (uint2*)alloc((size_t)2 * E_ * 8);              // out-CSR, 6.4 MB
  float* query_attn = (float*)alloc((size_t)R_ * T_ * B_ * (OPS_ + 1) * 4);
  u16*   wtile      = (u16*)  alloc((size_t)2 * 32 * 4 * 64 * 8 * 2);
  u16*   wonehot    = (u16*)  alloc((size_t)2 * 32 * 64 * 8 * 2);
  u16*   etile      = (u16*)  alloc((size_t)2 * 8 * 64 * 8 * 2);      // 16 KB
  int*   counts     = (int*)  alloc((size_t)(N_ + 1) * 4);
  int*   rowptr     = (int*)  alloc((size_t)(N_ + 1) * 4);
  int*   cursor     = (int*)  alloc((size_t)(N_ + 1) * 4);
  int*   cursor2    = (int*)  alloc((size_t)(N_ + 1) * 4);
  u8*    mask       = (u8*)   alloc((size_t)N_);
  float* sumsP      = (float*)alloc((size_t)PSLOTS * RB_ * 4);        // t2 partials only
  // total ~52 MB

  // counts must be zeroed BEFORE front's csr_count range (same-kernel zeroing
  // would race with the atomics); everything else is zeroed inside front.
  hipMemsetAsync(counts, 0, (size_t)(N_ + 1) * 4, stream);

  // fused qattn | wbuild | csr_count | zero(u2, mask, sumsP) | etile
  front_kernel<<<QB_ + WB_ + CB_ + ZU_ + ZM_ + ZS_ + EB_, 256, 0, stream>>>(
      queries, qemb, qWih, qWhh, qbih, qbhh, qlinW, qlinb, query_attn,
      eWhh, eemb, eWih, ebih, ebhh, wtile, wonehot,
      t_heads, t_tails, counts, u2, (int*)mask, sumsP, elinW, etile);
  // elstm + scan rider (block 0) + fused entity-attention epilogue -> attn
  elstm_kernel<<<SCANBLK_ + 1, 512, 0, stream>>>(edeg, wtile, wonehot, etile, elinb,
                                                 attn, counts, rowptr, cursor, cursor2);
  csr_fill_kernel<<<(E_ + 255) / 256, 256, 0, stream>>>(rels, t_heads, t_tails, attn,
                                                        cursor, cursor2, ents, ents2);
  // fused t=0 + t=1 sparse propagation into u2 (+ nonzero-row mask)
  t01_kernel<<<RB_, 64, 0, stream>>>(heads, query_attn, rowptr, ents2, u2, mask);
  // t=2: dense gather with mask-gated row loads (attn dead; u3 overwrites bigB)
  gather3_kernel<<<N_ / 4, 256, 0, stream>>>(u2, u3, query_attn, 2, rowptr, ents,
                                             mask, sumsP);
  fintrans_kernel<<<(N_ + 63) / 64, 256, 0, stream>>>(u3, sumsP, out);
}

// Round 10
// 463.160 us; speedup vs baseline: 2.1481x; 1.2173x over previous
//
#include <hip/hip_runtime.h>

#define R_ 3
#define T_ 3
#define N_ 50000
#define OPS_ 24
#define E_ 400000
#define B_ 32
#define MAXDEG_ 8
#define QD_ 128
#define ED_ 128
#define H_ 128
#define G4_ (4*H_)   /* 512 */
#define HPAD 168     /* padded LDS h-row (bf16): 128 h + 25 one-hot + pad, 336 B */
#define PSLOTS 64    /* partial row-sum slots */
#define RB_ 96       /* 3 rounds x 32 batch */

/* front fat-kernel block ranges (512-thread blocks) */
#define QB_ (R_ * B_)                          /* 96   qattn (dirs in parallel) */
#define WB_ ((2*32*5*64*8 + 511) / 512)        /* 320  wbuild */
#define CB_ ((E_ + 511) / 512)                 /* 782  csr_count */
#define BF_ ((E_ + 511) / 512)                 /* 782  bfs1 (1-hop mark) */
#define ZU_ 586                                /* u2 zero: 4.8M floats / 8192 */
#define ZM_ 25                                 /* mask zero: 12500 ints / 512 */
#define ZS_ 12                                 /* sumsP zero: 6144 / 512 */
#define EB_ 16                                 /* etile build: 8192 / 512 */
#define SCANBLK_ ((N_ + 31) / 32)              /* 1563 elstm blocks (+1 scan rider) */

typedef unsigned short u16;
typedef unsigned char u8;
typedef __attribute__((ext_vector_type(8))) short bf16x8;     // 8 bf16 = 4 VGPRs
typedef __attribute__((ext_vector_type(8))) _Float16 f16x8;   // 8 f16  = 4 VGPRs
typedef __attribute__((ext_vector_type(4))) float f32x4;

#define BF16_ONE ((short)0x3F80)
#define LOG2E_  1.44269504f
#define LOG2E2_ 2.88539008f

__device__ __forceinline__ short f2bf(float f){
  union { float f; unsigned u; } v; v.f = f;
  unsigned r = v.u + 0x7fffu + ((v.u >> 16) & 1u);
  return (short)(r >> 16);
}
__device__ __forceinline__ float bf2f(u16 u){
  union { unsigned u; float f; } v; v.u = ((unsigned)u) << 16; return v.f;
}
__device__ __forceinline__ float frcp(float x){ return __builtin_amdgcn_rcpf(x); }
__device__ __forceinline__ float fsig(float x){ return frcp(1.0f + __expf(-x)); }
__device__ __forceinline__ float ftanh(float x){
  return __builtin_fmaf(2.0f, fsig(2.0f * x), -1.0f);
}
__device__ __forceinline__ float fexp2(float x){
#if __has_builtin(__builtin_amdgcn_exp2f)
  return __builtin_amdgcn_exp2f(x);
#else
  return __expf(x * 0.6931471806f);
#endif
}

// ------- query BiLSTM + attention: one virtual 512-thread block per (r,b) -------
// The two LSTM directions are independent until the logits stage -> run them
// CONCURRENTLY (threads 0-255 = dir0, 256-511 = dir1): serial chain halves.
__device__ void qattn_body(int bid, const int* __restrict__ queries, const float* __restrict__ qemb,
    const float* __restrict__ qWih, const float* __restrict__ qWhh,
    const float* __restrict__ qbih, const float* __restrict__ qbhh,
    const float* __restrict__ qlinW, const float* __restrict__ qlinb,
    float* __restrict__ query_attn /* R,T,B,25 */)
{
  int r = bid / B_;
  int b = bid % B_;
  int tid = threadIdx.x;   // 512
  int d   = tid >> 8;      // direction
  int t2  = tid & 255;
  __shared__ float x[QD_];
  __shared__ float gx[2][G4_];
  __shared__ float h[2][H_], c[2][H_];
  __shared__ float gtmp[2][G4_];
  __shared__ float hh[2][T_][H_];
  __shared__ float lg[OPS_ + 1];

  int q = queries[b];
  if (tid < QD_) x[tid] = qemb[q * QD_ + tid];
  __syncthreads();

  const float* Wih = qWih + (size_t)(r * 2 + d) * G4_ * QD_;
  const float* Whh = qWhh + (size_t)(r * 2 + d) * G4_ * H_;
  const float* bih = qbih + (r * 2 + d) * G4_;
  const float* bhh = qbhh + (r * 2 + d) * G4_;
  for (int j = t2; j < G4_; j += 256){
    const float4* wr = (const float4*)(Wih + (size_t)j * QD_);
    float s = bih[j] + bhh[j];
    for (int k = 0; k < QD_ / 4; ++k){
      float4 wv = wr[k];
      s += wv.x * x[4*k] + wv.y * x[4*k+1] + wv.z * x[4*k+2] + wv.w * x[4*k+3];
    }
    gx[d][j] = s;
  }
  if (t2 < H_){ h[d][t2] = 0.f; c[d][t2] = 0.f; }
  __syncthreads();
  for (int t = 0; t < T_; ++t){
    for (int j = t2; j < G4_; j += 256){
      const float4* wr = (const float4*)(Whh + (size_t)j * H_);
      float s = 0.f;
      for (int k = 0; k < H_ / 4; ++k){
        float4 wv = wr[k];
        s += wv.x * h[d][4*k] + wv.y * h[d][4*k+1] + wv.z * h[d][4*k+2] + wv.w * h[d][4*k+3];
      }
      gtmp[d][j] = gx[d][j] + s;
    }
    __syncthreads();
    if (t2 < H_){
      float gi = gtmp[d][t2], gf = gtmp[d][t2 + H_], gg = gtmp[d][t2 + 2*H_], go = gtmp[d][t2 + 3*H_];
      float cn = fsig(gf) * c[d][t2] + fsig(gi) * ftanh(gg);
      float hn = fsig(go) * ftanh(cn);
      c[d][t2] = cn; h[d][t2] = hn;
      hh[d][t][t2] = hn;
    }
    __syncthreads();
  }

  for (int t = 0; t < T_; ++t){
    if (tid < OPS_ + 1){
      const float* wr = qlinW + tid * (2 * H_);
      float s = qlinb[tid];
      for (int k = 0; k < H_; ++k) s += wr[k] * hh[0][t][k];
      for (int k = 0; k < H_; ++k) s += wr[H_ + k] * hh[1][T_ - 1 - t][k];
      lg[tid] = s;
    }
    __syncthreads();
    if (tid == 0){
      float m = -1e30f;
      for (int o = 0; o < OPS_ + 1; ++o) m = fmaxf(m, lg[o]);
      float sum = 0.f;
      for (int o = 0; o < OPS_ + 1; ++o){ float e = __expf(lg[o] - m); lg[o] = e; sum += e; }
      float inv = frcp(sum);
      for (int o = 0; o < OPS_ + 1; ++o) lg[o] *= inv;
    }
    __syncthreads();
    if (tid < OPS_ + 1) query_attn[((size_t)(r * T_ + t) * B_ + b) * (OPS_ + 1) + tid] = lg[tid];
    __syncthreads();
  }
}

// ---- build B-operand buffers in MFMA-fragment order (eproj folded in) ----
__device__ void wbuild_body(int bid, const float* __restrict__ eWhh,
                            const float* __restrict__ eemb, const float* __restrict__ eWih,
                            const float* __restrict__ ebih, const float* __restrict__ ebhh,
                            u16* __restrict__ wtile, u16* __restrict__ wonehot)
{
  int idx = bid * 512 + threadIdx.x;    // 2*32*5*64*8 = 163840
  if (idx >= 2 * 32 * 5 * 64 * 8) return;
  int jj = idx & 7;
  int lane = (idx >> 3) & 63;
  int kc = (idx >> 9) % 5;
  int gtile = (idx / (8 * 64 * 5)) & 31;
  int dir = idx / (8 * 64 * 5 * 32);
  int row = lane >> 4, col = lane & 15;
  int j = gtile * 16 + col;
  float sc = ((gtile >> 3) == 2) ? LOG2E2_ : LOG2E_;   // gate g rows get 2*log2e
  if (kc < 4){
    int k = kc * 32 + row * 8 + jj;
    float v = eWhh[((size_t)dir * G4_ + j) * H_ + k] * sc;
    wtile[((((size_t)dir * 32 + gtile) * 4 + kc) * 64 + lane) * 8 + jj] = (u16)f2bf(v);
  } else {
    int vdeg = row * 8 + jj;   // 0..31
    float v = 0.f;
    if (vdeg <= OPS_){
      const float4* wr = (const float4*)(eWih + (size_t)(dir * G4_ + j) * ED_);
      const float4* er = (const float4*)(eemb + (size_t)vdeg * ED_);
      float s = ebih[dir * G4_ + j] + ebhh[dir * G4_ + j];
      for (int k = 0; k < ED_ / 4; ++k){
        float4 wv = wr[k], ev = er[k];
        s += wv.x * ev.x + wv.y * ev.y + wv.z * ev.z + wv.w * ev.w;
      }
      v = s * sc;
    }
    wonehot[(((size_t)dir * 32 + gtile) * 64 + lane) * 8 + jj] = (u16)f2bf(v);
  }
}

__device__ void csr_count_body(int bid, const int* __restrict__ theads,
                               const int* __restrict__ ttails, int* __restrict__ counts)
{
  int e = bid * 512 + threadIdx.x;
  if (e < E_){
    atomicAdd(&counts[ttails[e]], 1);
    atomicAdd(&counts[theads[e]], 1);
  }
}

// ---- bfs1: mark 1-hop neighborhood of heads (both edge roles) + heads selves.
// hs1 zeroed by a memset BEFORE front (this body only writes). Graph-only ->
// independent of attn/elstm, so reachability masks come for free up front.
__device__ void bfs1_body(int bid, const int* __restrict__ heads,
                          const int* __restrict__ theads, const int* __restrict__ ttails,
                          u8* __restrict__ hs1)
{
  if (bid == 0 && threadIdx.x < B_) hs1[heads[threadIdx.x]] = 1;
  int e = bid * 512 + threadIdx.x;
  if (e < E_){
    int a = theads[e], t = ttails[e];
    #pragma unroll 8
    for (int i = 0; i < B_; ++i){
      int hd = heads[i];             // uniform -> scalar loads
      if (a == hd) hs1[t] = 1;
      if (t == hd) hs1[a] = 1;
    }
  }
}

// ---- front fat-kernel: qattn | wbuild | csr_count | bfs1 | zero(u2,mask,sumsP) | etile
__global__ __launch_bounds__(512) void front_kernel(
    const int* queries, const float* qemb,
    const float* qWih, const float* qWhh, const float* qbih, const float* qbhh,
    const float* qlinW, const float* qlinb, float* query_attn,
    const float* eWhh, const float* eemb, const float* eWih,
    const float* ebih, const float* ebhh, u16* wtile, u16* wonehot,
    const int* theads, const int* ttails, int* counts,
    const int* heads, u8* hs1,
    float* u2, int* maski, float* sumsP,
    const float* elinW, u16* etile)
{
  int bid = blockIdx.x;
  int tid = threadIdx.x;
  if (bid < QB_){
    qattn_body(bid, queries, qemb, qWih, qWhh, qbih, qbhh, qlinW, qlinb, query_attn);
  } else if (bid < QB_ + WB_){
    wbuild_body(bid - QB_, eWhh, eemb, eWih, ebih, ebhh, wtile, wonehot);
  } else if (bid < QB_ + WB_ + CB_){
    csr_count_body(bid - QB_ - WB_, theads, ttails, counts);
  } else if (bid < QB_ + WB_ + CB_ + BF_){
    bfs1_body(bid - QB_ - WB_ - CB_, heads, theads, ttails, hs1);
  } else if (bid < QB_ + WB_ + CB_ + BF_ + ZU_){
    int zb = bid - QB_ - WB_ - CB_ - BF_;
    float4 z = {0.f, 0.f, 0.f, 0.f};
    size_t base = (size_t)zb * 8192 + tid * 4;
    #pragma unroll
    for (int k = 0; k < 4; ++k){
      size_t idx = base + (size_t)k * 2048;
      if (idx < (size_t)N_ * RB_) *(float4*)&u2[idx] = z;
    }
  } else if (bid < QB_ + WB_ + CB_ + BF_ + ZU_ + ZM_){
    int mi = (bid - QB_ - WB_ - CB_ - BF_ - ZU_) * 512 + tid;
    if (mi < (N_ + 3) / 4) maski[mi] = 0;
  } else if (bid < QB_ + WB_ + CB_ + BF_ + ZU_ + ZM_ + ZS_){
    int si = (bid - QB_ - WB_ - CB_ - BF_ - ZU_ - ZM_) * 512 + tid;
    if (si < PSLOTS * RB_) sumsP[si] = 0.f;
  } else {
    // elinW -> f16 MFMA B-frags: [2 op-tiles][8 ksteps][64 lanes][8] (16 KB)
    int idx = (bid - (QB_ + WB_ + CB_ + BF_ + ZU_ + ZM_ + ZS_)) * 512 + tid;   // 0..8191
    if (idx < 8192){
      int jj = idx & 7;
      int lane = (idx >> 3) & 63;
      int ks = (idx >> 9) & 7;
      int ot = idx >> 12;
      int op = ot * 16 + (lane & 15);
      int k  = ks * 32 + (lane >> 4) * 8 + jj;
      float v = (op < OPS_) ? elinW[(size_t)op * (2 * H_) + k] : 0.f;
      _Float16 hv = (_Float16)v;
      etile[idx] = *(const u16*)&hv;
    }
  }
}

// ---- bfs2: 2-hop closure. mask = hs1 U {nodes adjacent to hs1 (either role)}.
// mask is a SUPERSET of u2's nonzero rows (t01 pushes reach exactly this set).
__global__ __launch_bounds__(512) void bfs2_kernel(
    const int* __restrict__ theads, const int* __restrict__ ttails,
    const u8* __restrict__ hs1, u8* __restrict__ mask)
{
  int bid = blockIdx.x;
  if (bid < BF_){
    int e = bid * 512 + threadIdx.x;
    if (e < E_){
      int a = theads[e], t = ttails[e];
      if (hs1[a]) mask[t] = 1;
      if (hs1[t]) mask[a] = 1;
    }
  } else {
    int n = (bid - BF_) * 512 + threadIdx.x;
    if (n < N_ && hs1[n]) mask[n] = 1;
  }
}

// ---- coalesced tile scan (512 threads, rides as block 0 of the elstm grid).
__device__ void scan_body(const int* __restrict__ counts, int* __restrict__ rowptr,
                          int* __restrict__ cursor, int* __restrict__ cursor2)
{
  __shared__ int wsum[8];
  int t = threadIdx.x;
  int lane = t & 63, wv = t >> 6;
  int carry = 0;   // live only in thread 0
  for (int base = 0; base < N_; base += 2048){
    int idx = base + t * 4;
    int c0 = 0, c1 = 0, c2 = 0, c3 = 0;
    if (idx + 3 < N_){
      int4 c = *(const int4*)&counts[idx];
      c0 = c.x; c1 = c.y; c2 = c.z; c3 = c.w;
    } else {
      if (idx     < N_) c0 = counts[idx];
      if (idx + 1 < N_) c1 = counts[idx + 1];
      if (idx + 2 < N_) c2 = counts[idx + 2];
      if (idx + 3 < N_) c3 = counts[idx + 3];
    }
    int s = c0 + c1 + c2 + c3;
    int sc = s;                          // inclusive wave scan
    #pragma unroll
    for (int off = 1; off < 64; off <<= 1){
      int v = __shfl_up(sc, off);
      if (lane >= off) sc += v;
    }
    if (lane == 63) wsum[wv] = sc;
    __syncthreads();
    if (t == 0){
      int acc = carry;
      #pragma unroll
      for (int w = 0; w < 8; ++w){ int v = wsum[w]; wsum[w] = acc; acc += v; }
      carry = acc;
    }
    __syncthreads();
    int excl = wsum[wv] + (sc - s);
    int r0 = excl, r1 = r0 + c0, r2 = r1 + c1, r3 = r2 + c2;
    if (idx + 3 < N_){
      int4 rv; rv.x = r0; rv.y = r1; rv.z = r2; rv.w = r3;
      *(int4*)&rowptr[idx]  = rv;
      *(int4*)&cursor[idx]  = rv;
      *(int4*)&cursor2[idx] = rv;
    } else {
      if (idx     < N_){ rowptr[idx]   = r0; cursor[idx]   = r0; cursor2[idx]   = r0; }
      if (idx + 1 < N_){ rowptr[idx+1] = r1; cursor[idx+1] = r1; cursor2[idx+1] = r1; }
      if (idx + 2 < N_){ rowptr[idx+2] = r2; cursor[idx+2] = r2; cursor2[idx+2] = r2; }
      if (idx + 3 < N_){ rowptr[idx+3] = r3; cursor[idx+3] = r3; cursor2[idx+3] = r3; }
    }
  }
  if (t == 0) rowptr[N_] = carry;
}

// ------ entity BiLSTM (r9-exact): 512 thr / 8 waves / 32 entities per block,
// scan rider at block 0, fused entity-attention epilogue.
__global__ __launch_bounds__(512, 4) void elstm_kernel(
    const int* __restrict__ degs,
    const u16* __restrict__ wtile, const u16* __restrict__ wonehot,
    const u16* __restrict__ etile, const float* __restrict__ elinb,
    float* __restrict__ attn /* N,24 */,
    const int* __restrict__ counts, int* __restrict__ rowptr,
    int* __restrict__ cursor, int* __restrict__ cursor2)
{
  if (blockIdx.x == 0){ scan_body(counts, rowptr, cursor, cursor2); return; }

  int tid = threadIdx.x;
  int lane = tid & 63;
  int w = tid >> 6;          // wave 0..7
  int wu = __builtin_amdgcn_readfirstlane(w);   // provably wave-uniform
  int row = lane >> 4, col = lane & 15;
  int ebase = (blockIdx.x - 1) * 32;

  __shared__ __align__(16) short hl[2][32 * HPAD];   // 2 x 10.5 KB ping-pong
  __shared__ __align__(16) short hfin[32 * 136];     // dir0 final h (8.5 KB)
  __shared__ float lgs[32][33];                      // epilogue logits (4.2 KB)

  int eg0 = ebase + tid; if (eg0 >= N_) eg0 = N_ - 1;   // valid for tid<32 use

  for (int i = tid; i < 2 * 32 * HPAD; i += 512) ((short*)hl)[i] = 0;
  __syncthreads();
  if (tid < 32) hl[0][tid * HPAD + H_ + degs[(size_t)eg0 * MAXDEG_ + 0]] = BF16_ONE;
  __syncthreads();

  int swzr = (col >> 2) & 3;   // read-side swizzle for entities col and 16+col

  for (int dir = 0; dir < 2; ++dir){
    const u16* Wt  = wtile   + (size_t)dir * 32 * 4 * 64 * 8;
    const u16* Woh = wonehot + (size_t)dir * 32 * 64 * 8;
    const u16* W0 = Wt + (size_t)((0 * 8 + wu) * 4 * 64) * 8;
    const u16* W1 = Wt + (size_t)((1 * 8 + wu) * 4 * 64) * 8;
    const u16* W2 = Wt + (size_t)((2 * 8 + wu) * 4 * 64) * 8;
    const u16* W3 = Wt + (size_t)((3 * 8 + wu) * 4 * 64) * 8;
    const u16* O0 = Woh + (size_t)((0 * 8 + wu) * 64) * 8;
    const u16* O1 = Woh + (size_t)((1 * 8 + wu) * 64) * 8;
    const u16* O2 = Woh + (size_t)((2 * 8 + wu) * 64) * 8;
    const u16* O3 = Woh + (size_t)((3 * 8 + wu) * 64) * 8;
    float cst[8];
    #pragma unroll
    for (int i = 0; i < 8; ++i) cst[i] = 0.f;

    for (int t = 0; t < MAXDEG_; ++t){
      const short* hb = hl[t & 1];          // holds h_t (+ one-hot for step t)
      short*       hw = hl[(t + 1) & 1];    // receives h_{t+1}
      f32x4 acc[8];
      #pragma unroll
      for (int i = 0; i < 8; ++i) acc[i] = (f32x4){0.f, 0.f, 0.f, 0.f};

      #pragma unroll 2
      for (int kc = 0; kc < 4; ++kc){
        bf16x8 af0 = *(const bf16x8*)&hb[(col) * HPAD + kc * 32 + (row ^ swzr) * 8];
        bf16x8 af1 = *(const bf16x8*)&hb[(16 + col) * HPAD + kc * 32 + (row ^ swzr) * 8];
        int lo = (kc * 64 + lane) * 8;
        bf16x8 b0 = *(const bf16x8*)(W0 + lo);
        bf16x8 b1 = *(const bf16x8*)(W1 + lo);
        bf16x8 b2 = *(const bf16x8*)(W2 + lo);
        bf16x8 b3 = *(const bf16x8*)(W3 + lo);
        acc[0] = __builtin_amdgcn_mfma_f32_16x16x32_bf16(af0, b0, acc[0], 0, 0, 0);
        acc[1] = __builtin_amdgcn_mfma_f32_16x16x32_bf16(af1, b0, acc[1], 0, 0, 0);
        acc[2] = __builtin_amdgcn_mfma_f32_16x16x32_bf16(af0, b1, acc[2], 0, 0, 0);
        acc[3] = __builtin_amdgcn_mfma_f32_16x16x32_bf16(af1, b1, acc[3], 0, 0, 0);
        acc[4] = __builtin_amdgcn_mfma_f32_16x16x32_bf16(af0, b2, acc[4], 0, 0, 0);
        acc[5] = __builtin_amdgcn_mfma_f32_16x16x32_bf16(af1, b2, acc[5], 0, 0, 0);
        acc[6] = __builtin_amdgcn_mfma_f32_16x16x32_bf16(af0, b3, acc[6], 0, 0, 0);
        acc[7] = __builtin_amdgcn_mfma_f32_16x16x32_bf16(af1, b3, acc[7], 0, 0, 0);
      }
      {
        bf16x8 af0 = *(const bf16x8*)&hb[(col) * HPAD + H_ + row * 8];
        bf16x8 af1 = *(const bf16x8*)&hb[(16 + col) * HPAD + H_ + row * 8];
        int lo = lane * 8;
        bf16x8 b0 = *(const bf16x8*)(O0 + lo);
        bf16x8 b1 = *(const bf16x8*)(O1 + lo);
        bf16x8 b2 = *(const bf16x8*)(O2 + lo);
        bf16x8 b3 = *(const bf16x8*)(O3 + lo);
        acc[0] = __builtin_amdgcn_mfma_f32_16x16x32_bf16(af0, b0, acc[0], 0, 0, 0);
        acc[1] = __builtin_amdgcn_mfma_f32_16x16x32_bf16(af1, b0, acc[1], 0, 0, 0);
        acc[2] = __builtin_amdgcn_mfma_f32_16x16x32_bf16(af0, b1, acc[2], 0, 0, 0);
        acc[3] = __builtin_amdgcn_mfma_f32_16x16x32_bf16(af1, b1, acc[3], 0, 0, 0);
        acc[4] = __builtin_amdgcn_mfma_f32_16x16x32_bf16(af0, b2, acc[4], 0, 0, 0);
        acc[5] = __builtin_amdgcn_mfma_f32_16x16x32_bf16(af1, b2, acc[5], 0, 0, 0);
        acc[6] = __builtin_amdgcn_mfma_f32_16x16x32_bf16(af0, b3, acc[6], 0, 0, 0);
        acc[7] = __builtin_amdgcn_mfma_f32_16x16x32_bf16(af1, b3, acc[7], 0, 0, 0);
      }

      #pragma unroll
      for (int mt = 0; mt < 2; ++mt){
        #pragma unroll
        for (int reg = 0; reg < 4; ++reg){
          int e = mt * 16 + row * 4 + reg;
          int jsw = (((wu * 2 + (col >> 3)) ^ row) * 8) + (col & 7);
          float Gi = acc[0 + mt][reg];
          float Gf = acc[2 + mt][reg];
          float Gg = acc[4 + mt][reg];
          float Go = acc[6 + mt][reg];
          int ci = mt * 4 + reg;
          float ea = fexp2(-Gi);
          float ef = fexp2(-Gf);
          float eb = fexp2(-Gg);
          float eo = fexp2(-Go);
          float t1 = 1.f + ef, t2 = 1.f + ea, t3 = 1.f + eb;
          float p = t2 * t3;
          float num = __builtin_fmaf(cst[ci], p, (1.f - eb) * t1);
          float cn = num * frcp(t1 * p);
          float ed = fexp2(cn * (-LOG2E2_));
          float hn = (1.f - ed) * frcp((1.f + eo) * (1.f + ed));
          cst[ci] = cn;
          hw[e * HPAD + jsw] = f2bf(hn);
        }
      }
      if (tid < 32){
        const int* dr = degs + (size_t)eg0 * MAXDEG_;
        if (t >= 1)
          hw[tid * HPAD + H_ + dr[dir ? (MAXDEG_ - t) : (t - 1)]] = 0;
        if (t < MAXDEG_ - 1)
          hw[tid * HPAD + H_ + dr[dir ? (MAXDEG_ - 2 - t) : (t + 1)]] = BF16_ONE;
      }
      __syncthreads();
    }

    if (dir == 0){
      for (int i = tid; i < 32 * 16; i += 512){
        int e = i >> 4, c = i & 15;
        int sz = (e >> 2) & 3;
        *(bf16x8*)&hfin[e * 136 + c * 8] =
            *(const bf16x8*)&hl[0][e * HPAD + ((c ^ sz) * 8)];
      }
      __syncthreads();
      for (int i = tid; i < 2 * 32 * HPAD; i += 512) ((short*)hl)[i] = 0;
      __syncthreads();
      if (tid < 32) hl[0][tid * HPAD + H_ + degs[(size_t)eg0 * MAXDEG_ + (MAXDEG_ - 1)]] = BF16_ONE;
      __syncthreads();
    }
  }

  // fused entity-attention epilogue
  if (wu < 4){
    int mt = wu >> 1, ot = wu & 1;
    int e2 = mt * 16 + col;
    f32x4 accL = (f32x4){0.f, 0.f, 0.f, 0.f};
    #pragma unroll
    for (int ks = 0; ks < 8; ++ks){
      bf16x8 ra;
      if (ks < 4) ra = *(const bf16x8*)&hfin[e2 * 136 + ks * 32 + row * 8];
      else        ra = *(const bf16x8*)&hl[0][e2 * HPAD + (ks - 4) * 32 + (row ^ swzr) * 8];
      f16x8 af;
      #pragma unroll
      for (int jj = 0; jj < 8; ++jj) af[jj] = (_Float16)bf2f((u16)ra[jj]);
      f16x8 bfr = *(const f16x8*)(etile + (((size_t)(ot * 8 + ks)) * 64 + lane) * 8);
      accL = __builtin_amdgcn_mfma_f32_16x16x32_f16(af, bfr, accL, 0, 0, 0);
    }
    #pragma unroll
    for (int reg = 0; reg < 4; ++reg){
      int ent = mt * 16 + (lane >> 4) * 4 + reg;
      int op  = ot * 16 + (lane & 15);
      float bb = (op < OPS_) ? elinb[op] : 0.f;
      lgs[ent][op] = accL[reg] + bb;
    }
  }
  __syncthreads();
  if (tid < 32){
    int n = ebase + tid;
    if (n < N_){
      float m = -1e30f;
      #pragma unroll
      for (int o = 0; o < OPS_; ++o) m = fmaxf(m, lgs[tid][o]);
      float s = 0.f;
      #pragma unroll
      for (int o = 0; o < OPS_; ++o) s += __expf(lgs[tid][o] - m);
      float inv = frcp(s);
      #pragma unroll
      for (int o = 0; o < OPS_; ++o)
        attn[(size_t)n * OPS_ + o] = __expf(lgs[tid][o] - m) * inv;
    }
  }
}

// ---- compact CSR fill: in-CSR keeps only edges with masked src (~18%); out-CSR
// keeps only rows in hs1 = heads U 1hop (~1%). Post-fill, cursor/cursor2 hold the
// compact row ends. mask superset proof: see t01 push targets.
__global__ void csr_fill_kernel(const int* __restrict__ rels, const int* __restrict__ theads,
                                const int* __restrict__ ttails, const float* __restrict__ attn,
                                const u8* __restrict__ mask, const u8* __restrict__ hs1,
                                int* __restrict__ cursor, int* __restrict__ cursor2,
                                uint2* __restrict__ ents, uint2* __restrict__ ents2)
{
  int e = blockIdx.x * 256 + threadIdx.x;
  if (e < E_){
    int hh = theads[e], tt = ttails[e];
    int mh = mask[hh], mt = mask[tt];
    if (!(mh | mt)) return;          // mask superset of hs1 -> covers all cases
    int rel = rels[e];
    unsigned wb = __float_as_uint(attn[(size_t)hh * OPS_ + rel]);
    if (mh){                         // fwd: src hh -> row tt
      uint2 v1; v1.x = (unsigned)hh | ((unsigned)rel << 16); v1.y = wb;
      ents[atomicAdd(&cursor[tt], 1)] = v1;
    }
    if (mt){                         // rev: src tt -> row hh
      uint2 v2; v2.x = (unsigned)tt | ((unsigned)(rel + OPS_/2) << 16); v2.y = wb;
      ents[atomicAdd(&cursor[hh], 1)] = v2;
    }
    if (hs1[hh]){                    // out-edge of hh
      uint2 w1; w1.x = (unsigned)tt | ((unsigned)rel << 16); w1.y = wb;
      ents2[atomicAdd(&cursor2[hh], 1)] = w1;
    }
    if (hs1[tt]){                    // out-edge of tt (reverse op)
      uint2 w2; w2.x = (unsigned)hh | ((unsigned)(rel + OPS_/2) << 16); w2.y = wb;
      ents2[atomicAdd(&cursor2[tt], 1)] = w2;
    }
  }
}

// ---- fused sparse t=0 + t=1 (linear; normalization telescopes). Compact out-CSR:
// row ends come from cursor2 (heads and 1hop rows are complete by construction).
__global__ void t01_kernel(const int* __restrict__ heads, const float* __restrict__ query_attn,
                           const int* __restrict__ rowptr, const int* __restrict__ cend2,
                           const uint2* __restrict__ ents2, float* __restrict__ u2)
{
  __shared__ float qa0[OPS_ + 1], qa1[OPS_ + 1];
  int blk = blockIdx.x;   // 0..95
  int r = blk >> 5, b = blk & 31;
  int rb = r * 32 + b;
  int tid = threadIdx.x;  // 64
  if (tid < OPS_ + 1){
    qa0[tid] = query_attn[((size_t)(r * T_ + 0) * B_ + b) * (OPS_ + 1) + tid];
    qa1[tid] = query_attn[((size_t)(r * T_ + 1) * B_ + b) * (OPS_ + 1) + tid];
  }
  __syncthreads();
  int hd = heads[b];
  int beg = rowptr[hd], end = cend2[hd];
  float q024 = qa0[OPS_], q124 = qa1[OPS_];
  if (tid == 0) atomicAdd(&u2[(size_t)hd * RB_ + rb], q124 * q024);
  for (int i = beg + tid; i < end; i += 64){
    uint2 e1 = ents2[i];
    int s  = (int)(e1.x & 0xFFFFu);
    int r1 = (int)(e1.x >> 16);
    float w1 = __uint_as_float(e1.y);
    atomicAdd(&u2[(size_t)s * RB_ + rb], w1 * (q124 * qa0[r1] + qa1[r1] * q024));
    float v1 = qa0[r1] * w1;      // this path's share of u1[s]
    int b2 = rowptr[s], e2e = cend2[s];
    for (int jj = b2; jj < e2e; ++jj){
      uint2 e2 = ents2[jj];
      int d2 = (int)(e2.x & 0xFFFFu);
      int r2 = (int)(e2.x >> 16);
      atomicAdd(&u2[(size_t)d2 * RB_ + rb], qa1[r2] * __uint_as_float(e2.y) * v1);
    }
  }
}

// ---- dense gather (t=2), compact in-CSR: every stored edge has masked src, so
// the per-edge mask branches vanish; row end = cursor[n] (compact fill end).
__global__ __launch_bounds__(256) void gather3_kernel(
    const float* __restrict__ ucur, float* __restrict__ unxt,
    const float* __restrict__ query_attn, int t,
    const int* __restrict__ rowptr, const int* __restrict__ cend,
    const uint2* __restrict__ ents, const u8* __restrict__ mask,
    float* __restrict__ partial /* PSLOTS x 96 */)
{
  __shared__ float qas[3 * B_ * (OPS_ + 1)];  // [r][b][o]
  __shared__ float red[RB_];
  int tid = threadIdx.x;
  for (int i = tid; i < 3 * B_ * (OPS_ + 1); i += 256){
    int r = i / (B_ * (OPS_ + 1));
    int rem = i - r * (B_ * (OPS_ + 1));
    qas[i] = query_attn[(size_t)(r * T_ + t) * B_ * (OPS_ + 1) + rem];
  }
  if (tid < RB_) red[tid] = 0.f;
  __syncthreads();
  int b  = tid & 31;
  int h  = (tid >> 5) & 1;              // half within wave
  int n = blockIdx.x * 4 + (tid >> 6);  // one wave per node; grid*4 == N_
  const float* q0 = &qas[0 * 800 + b * (OPS_ + 1)];
  const float* q1 = &qas[1 * 800 + b * (OPS_ + 1)];
  const float* q2 = &qas[2 * 800 + b * (OPS_ + 1)];
  size_t nb = (size_t)n * RB_;
  float a0 = 0.f, a1 = 0.f, a2 = 0.f;
  if (h == 0 && mask[n]){
    a0 = ucur[nb + b]      * q0[OPS_];
    a1 = ucur[nb + 32 + b] * q1[OPS_];
    a2 = ucur[nb + 64 + b] * q2[OPS_];
  }
  int beg = rowptr[n], end = cend[n];
  int cnt = end - beg;
  int nq = cnt >> 2;                 // full 4-edge chunks
  for (int c = h; c < nq; c += 2){
    int i0 = beg + 4 * c;
    uint2 e0 = ents[i0 + 0];
    uint2 e1 = ents[i0 + 1];
    uint2 e2 = ents[i0 + 2];
    uint2 e3 = ents[i0 + 3];
    size_t s0 = (size_t)(e0.x & 0xFFFFu) * RB_;
    size_t s1 = (size_t)(e1.x & 0xFFFFu) * RB_;
    size_t s2 = (size_t)(e2.x & 0xFFFFu) * RB_;
    size_t s3 = (size_t)(e3.x & 0xFFFFu) * RB_;
    float u00 = ucur[s0 + b], u01 = ucur[s0 + 32 + b], u02 = ucur[s0 + 64 + b];
    float u10 = ucur[s1 + b], u11 = ucur[s1 + 32 + b], u12 = ucur[s1 + 64 + b];
    float u20 = ucur[s2 + b], u21 = ucur[s2 + 32 + b], u22 = ucur[s2 + 64 + b];
    float u30 = ucur[s3 + b], u31 = ucur[s3 + 32 + b], u32 = ucur[s3 + 64 + b];
    int r0 = (int)(e0.x >> 16), r1 = (int)(e1.x >> 16);
    int r2 = (int)(e2.x >> 16), r3 = (int)(e3.x >> 16);
    float w0 = __uint_as_float(e0.y), w1 = __uint_as_float(e1.y);
    float w2 = __uint_as_float(e2.y), w3 = __uint_as_float(e3.y);
    a0 += q0[r0]*w0*u00 + q0[r1]*w1*u10 + q0[r2]*w2*u20 + q0[r3]*w3*u30;
    a1 += q1[r0]*w0*u01 + q1[r1]*w1*u11 + q1[r2]*w2*u21 + q1[r3]*w3*u31;
    a2 += q2[r0]*w0*u02 + q2[r1]*w1*u12 + q2[r2]*w2*u22 + q2[r3]*w3*u32;
  }
  if (h == 1){
    for (int i = beg + 4 * nq; i < end; ++i){
      uint2 e0 = ents[i];
      size_t s0 = (size_t)(e0.x & 0xFFFFu) * RB_;
      int r0 = (int)(e0.x >> 16);
      float w0 = __uint_as_float(e0.y);
      a0 += q0[r0] * w0 * ucur[s0 + b];
      a1 += q1[r0] * w0 * ucur[s0 + 32 + b];
      a2 += q2[r0] * w0 * ucur[s0 + 64 + b];
    }
  }
  a0 += __shfl_xor(a0, 32);
  a1 += __shfl_xor(a1, 32);
  a2 += __shfl_xor(a2, 32);
  if (h == 0){
    unxt[nb + b]      = a0;
    unxt[nb + 32 + b] = a1;
    unxt[nb + 64 + b] = a2;
    atomicAdd(&red[b], a0);
    atomicAdd(&red[32 + b], a1);
    atomicAdd(&red[64 + b], a2);
  }
  __syncthreads();
  if (tid < RB_)
    atomicAdd(&partial[(blockIdx.x & (PSLOTS - 1)) * RB_ + tid], red[tid]);
}

// ---- finalize + transpose: out[b][n] = sum_r u[n][r*32+b] / rowsum_r ----
__global__ void fintrans_kernel(const float* __restrict__ u, const float* __restrict__ partial,
                                float* __restrict__ out)
{
  __shared__ float sinv[RB_];
  __shared__ float t[B_][72];
  int tid = threadIdx.x;   // 256
  if (tid < RB_){
    float s = 0.f;
    #pragma unroll 8
    for (int k = 0; k < PSLOTS; ++k) s += partial[k * RB_ + tid];
    sinv[tid] = frcp(fmaxf(1e-20f, s));
  }
  __syncthreads();
  int n0 = blockIdx.x * 64;
  for (int i = tid; i < 64 * B_; i += 256){
    int nl = i >> 5, b = i & 31;
    int n = n0 + nl;
    float v = 0.f;
    if (n < N_){
      size_t nb = (size_t)n * RB_;
      v = u[nb + b] * sinv[b] + u[nb + 32 + b] * sinv[32 + b] + u[nb + 64 + b] * sinv[64 + b];
    }
    t[b][nl] = v;
  }
  __syncthreads();
  for (int i = tid; i < 64 * B_; i += 256){
    int b = i >> 6, nl = i & 63;
    int n = n0 + nl;
    if (n < N_) out[(size_t)b * N_ + n] = t[b][nl];
  }
}

extern "C" void kernel_launch(void* const* d_in, const int* in_sizes, int n_in,
                              void* d_out, int out_size, void* d_ws, size_t ws_size,
                              hipStream_t stream)
{
  const int*   queries = (const int*)d_in[0];
  const int*   heads   = (const int*)d_in[1];
  const int*   rels    = (const int*)d_in[2];
  const int*   t_heads = (const int*)d_in[3];
  const int*   t_tails = (const int*)d_in[4];
  const int*   edeg    = (const int*)d_in[5];
  const float* qemb    = (const float*)d_in[6];
  const float* eemb    = (const float*)d_in[7];
  const float* qWih    = (const float*)d_in[8];
  const float* qWhh    = (const float*)d_in[9];
  const float* qbih    = (const float*)d_in[10];
  const float* qbhh    = (const float*)d_in[11];
  const float* eWih    = (const float*)d_in[12];
  const float* eWhh    = (const float*)d_in[13];
  const float* ebih    = (const float*)d_in[14];
  const float* ebhh    = (const float*)d_in[15];
  const float* qlinW   = (const float*)d_in[16];
  const float* qlinb   = (const float*)d_in[17];
  const float* elinW   = (const float*)d_in[18];
  const float* elinb   = (const float*)d_in[19];
  float* out = (float*)d_out;

  char* ws = (char*)d_ws;
  size_t off = 0;
  auto alloc = [&](size_t bytes){ void* p = ws + off; off += (bytes + 255) & ~(size_t)255; return p; };
  // bigB (19.2 MB): attn (4.8 MB) during [elstm, csr_fill]; then u3 (gather3 out).
  char*  bigB  = (char*)alloc((size_t)N_ * RB_ * 4);
  float* attn  = (float*)bigB;
  float* u3    = (float*)bigB;
  uint2* ents       = (uint2*)alloc((size_t)2 * E_ * 8);              // in-CSR (compact-filled)
  float* u2         = (float*)alloc((size_t)N_ * RB_ * 4);            // 19.2 MB
  uint2* ents2      = (uint2*)alloc((size_t)2 * E_ * 8);              // out-CSR (compact-filled)
  float* query_attn = (float*)alloc((size_t)R_ * T_ * B_ * (OPS_ + 1) * 4);
  u16*   wtile      = (u16*)  alloc((size_t)2 * 32 * 4 * 64 * 8 * 2);
  u16*   wonehot    = (u16*)  alloc((size_t)2 * 32 * 64 * 8 * 2);
  u16*   etile      = (u16*)  alloc((size_t)2 * 8 * 64 * 8 * 2);      // 16 KB
  int*   counts     = (int*)  alloc((size_t)(N_ + 1) * 4);
  int*   rowptr     = (int*)  alloc((size_t)(N_ + 1) * 4);
  int*   cursor     = (int*)  alloc((size_t)(N_ + 1) * 4);
  int*   cursor2    = (int*)  alloc((size_t)(N_ + 1) * 4);
  u8*    hs1        = (u8*)   alloc((size_t)N_);
  u8*    mask       = (u8*)   alloc((size_t)N_);
  float* sumsP      = (float*)alloc((size_t)PSLOTS * RB_ * 4);
  // total ~52 MB

  // counts + hs1 must be zero BEFORE front (csr_count atomics / bfs1 marks ride it);
  // u2 / mask / sumsP are zeroed inside front (consumed only later).
  hipMemsetAsync(counts, 0, (size_t)(N_ + 1) * 4, stream);
  hipMemsetAsync(hs1, 0, (size_t)N_, stream);

  front_kernel<<<QB_ + WB_ + CB_ + BF_ + ZU_ + ZM_ + ZS_ + EB_, 512, 0, stream>>>(
      queries, qemb, qWih, qWhh, qbih, qbhh, qlinW, qlinb, query_attn,
      eWhh, eemb, eWih, ebih, ebhh, wtile, wonehot,
      t_heads, t_tails, counts, heads, hs1, u2, (int*)mask, sumsP, elinW, etile);
  // 2-hop closure mask (graph-only; needs hs1 complete)
  bfs2_kernel<<<BF_ + (N_ + 511) / 512, 512, 0, stream>>>(t_heads, t_tails, hs1, mask);
  // elstm + scan rider (block 0) + fused entity-attention epilogue -> attn
  elstm_kernel<<<SCANBLK_ + 1, 512, 0, stream>>>(edeg, wtile, wonehot, etile, elinb,
                                                 attn, counts, rowptr, cursor, cursor2);
  // compact CSR fill (cursor/cursor2 become compact row ends)
  csr_fill_kernel<<<(E_ + 255) / 256, 256, 0, stream>>>(rels, t_heads, t_tails, attn,
                                                        mask, hs1, cursor, cursor2,
                                                        ents, ents2);
  // fused t=0 + t=1 sparse propagation into u2
  t01_kernel<<<RB_, 64, 0, stream>>>(heads, query_attn, rowptr, cursor2, ents2, u2);
  // t=2: dense gather over compact in-CSR (attn dead; u3 overwrites bigB)
  gather3_kernel<<<N_ / 4, 256, 0, stream>>>(u2, u3, query_attn, 2, rowptr, cursor,
                                             ents, mask, sumsP);
  fintrans_kernel<<<(N_ + 63) / 64, 256, 0, stream>>>(u3, sumsP, out);
}

// Round 11
// 450.291 us; speedup vs baseline: 2.2095x; 1.0286x over previous
//
#include <hip/hip_runtime.h>

#define R_ 3
#define T_ 3
#define N_ 50000
#define OPS_ 24
#define E_ 400000
#define B_ 32
#define MAXDEG_ 8
#define QD_ 128
#define ED_ 128
#define H_ 128
#define G4_ (4*H_)   /* 512 */
#define HPAD 168     /* padded LDS h-row (bf16): 128 h + 25 one-hot + pad, 336 B */
#define PSLOTS 64    /* partial row-sum slots */
#define RB_ 96       /* 3 rounds x 32 batch */

/* front fat-kernel block ranges (512-thread blocks) — qattn moved to elstm riders */
#define WB_ ((2*32*5*64*8 + 511) / 512)        /* 320  wbuild */
#define CB_ ((E_ + 511) / 512)                 /* 782  csr_count */
#define BF_ ((E_ + 511) / 512)                 /* 782  bfs1 (1-hop mark) */
#define ZU_ 586                                /* u2 zero: 4.8M floats / 8192 */
#define ZM_ 25                                 /* mask zero: 12500 ints / 512 */
#define ZS_ 12                                 /* sumsP zero: 6144 / 512 */
#define EB_ 16                                 /* etile build: 8192 / 512 */

/* elstm mega-grid riders */
#define QB_ (R_ * B_)                          /* 96  qattn riders */
#define BF2E_ ((E_ + 511) / 512)               /* 782 bfs2 edge riders */
#define BF2N_ ((N_ + 511) / 512)               /* 98  bfs2 node riders */
#define RIDERS_ (1 + BF2E_ + BF2N_ + QB_)      /* 977: scan + bfs2 + qattn */
#define SCANBLK_ ((N_ + 31) / 32)              /* 1563 elstm blocks */

typedef unsigned short u16;
typedef unsigned char u8;
typedef __attribute__((ext_vector_type(8))) short bf16x8;     // 8 bf16 = 4 VGPRs
typedef __attribute__((ext_vector_type(8))) _Float16 f16x8;   // 8 f16  = 4 VGPRs
typedef __attribute__((ext_vector_type(4))) float f32x4;

#define BF16_ONE ((short)0x3F80)
#define LOG2E_  1.44269504f
#define LOG2E2_ 2.88539008f

__device__ __forceinline__ short f2bf(float f){
  union { float f; unsigned u; } v; v.f = f;
  unsigned r = v.u + 0x7fffu + ((v.u >> 16) & 1u);
  return (short)(r >> 16);
}
__device__ __forceinline__ float bf2f(u16 u){
  union { unsigned u; float f; } v; v.u = ((unsigned)u) << 16; return v.f;
}
__device__ __forceinline__ float frcp(float x){ return __builtin_amdgcn_rcpf(x); }
__device__ __forceinline__ float fsig(float x){ return frcp(1.0f + __expf(-x)); }
__device__ __forceinline__ float ftanh(float x){
  return __builtin_fmaf(2.0f, fsig(2.0f * x), -1.0f);
}
__device__ __forceinline__ float fexp2(float x){
#if __has_builtin(__builtin_amdgcn_exp2f)
  return __builtin_amdgcn_exp2f(x);
#else
  return __expf(x * 0.6931471806f);
#endif
}

// ------- query BiLSTM + attention: 512-thread body, dirs run concurrently -------
// Output consumed only AFTER the elstm mega-kernel -> safe to ride in its grid.
__device__ void qattn_body(int bid, const int* __restrict__ queries, const float* __restrict__ qemb,
    const float* __restrict__ qWih, const float* __restrict__ qWhh,
    const float* __restrict__ qbih, const float* __restrict__ qbhh,
    const float* __restrict__ qlinW, const float* __restrict__ qlinb,
    float* __restrict__ query_attn /* R,T,B,25 */)
{
  int r = bid / B_;
  int b = bid % B_;
  int tid = threadIdx.x;   // 512
  int d   = tid >> 8;      // direction
  int t2  = tid & 255;
  __shared__ float x[QD_];
  __shared__ float gx[2][G4_];
  __shared__ float h[2][H_], c[2][H_];
  __shared__ float gtmp[2][G4_];
  __shared__ float hh[2][T_][H_];
  __shared__ float lg[OPS_ + 1];

  int q = queries[b];
  if (tid < QD_) x[tid] = qemb[q * QD_ + tid];
  __syncthreads();

  const float* Wih = qWih + (size_t)(r * 2 + d) * G4_ * QD_;
  const float* Whh = qWhh + (size_t)(r * 2 + d) * G4_ * H_;
  const float* bih = qbih + (r * 2 + d) * G4_;
  const float* bhh = qbhh + (r * 2 + d) * G4_;
  for (int j = t2; j < G4_; j += 256){
    const float4* wr = (const float4*)(Wih + (size_t)j * QD_);
    float s = bih[j] + bhh[j];
    for (int k = 0; k < QD_ / 4; ++k){
      float4 wv = wr[k];
      s += wv.x * x[4*k] + wv.y * x[4*k+1] + wv.z * x[4*k+2] + wv.w * x[4*k+3];
    }
    gx[d][j] = s;
  }
  if (t2 < H_){ h[d][t2] = 0.f; c[d][t2] = 0.f; }
  __syncthreads();
  for (int t = 0; t < T_; ++t){
    for (int j = t2; j < G4_; j += 256){
      const float4* wr = (const float4*)(Whh + (size_t)j * H_);
      float s = 0.f;
      for (int k = 0; k < H_ / 4; ++k){
        float4 wv = wr[k];
        s += wv.x * h[d][4*k] + wv.y * h[d][4*k+1] + wv.z * h[d][4*k+2] + wv.w * h[d][4*k+3];
      }
      gtmp[d][j] = gx[d][j] + s;
    }
    __syncthreads();
    if (t2 < H_){
      float gi = gtmp[d][t2], gf = gtmp[d][t2 + H_], gg = gtmp[d][t2 + 2*H_], go = gtmp[d][t2 + 3*H_];
      float cn = fsig(gf) * c[d][t2] + fsig(gi) * ftanh(gg);
      float hn = fsig(go) * ftanh(cn);
      c[d][t2] = cn; h[d][t2] = hn;
      hh[d][t][t2] = hn;
    }
    __syncthreads();
  }

  for (int t = 0; t < T_; ++t){
    if (tid < OPS_ + 1){
      const float* wr = qlinW + tid * (2 * H_);
      float s = qlinb[tid];
      for (int k = 0; k < H_; ++k) s += wr[k] * hh[0][t][k];
      for (int k = 0; k < H_; ++k) s += wr[H_ + k] * hh[1][T_ - 1 - t][k];
      lg[tid] = s;
    }
    __syncthreads();
    if (tid == 0){
      float m = -1e30f;
      for (int o = 0; o < OPS_ + 1; ++o) m = fmaxf(m, lg[o]);
      float sum = 0.f;
      for (int o = 0; o < OPS_ + 1; ++o){ float e = __expf(lg[o] - m); lg[o] = e; sum += e; }
      float inv = frcp(sum);
      for (int o = 0; o < OPS_ + 1; ++o) lg[o] *= inv;
    }
    __syncthreads();
    if (tid < OPS_ + 1) query_attn[((size_t)(r * T_ + t) * B_ + b) * (OPS_ + 1) + tid] = lg[tid];
    __syncthreads();
  }
}

// ---- build B-operand buffers in MFMA-fragment order (eproj folded in) ----
__device__ void wbuild_body(int bid, const float* __restrict__ eWhh,
                            const float* __restrict__ eemb, const float* __restrict__ eWih,
                            const float* __restrict__ ebih, const float* __restrict__ ebhh,
                            u16* __restrict__ wtile, u16* __restrict__ wonehot)
{
  int idx = bid * 512 + threadIdx.x;    // 2*32*5*64*8 = 163840
  if (idx >= 2 * 32 * 5 * 64 * 8) return;
  int jj = idx & 7;
  int lane = (idx >> 3) & 63;
  int kc = (idx >> 9) % 5;
  int gtile = (idx / (8 * 64 * 5)) & 31;
  int dir = idx / (8 * 64 * 5 * 32);
  int row = lane >> 4, col = lane & 15;
  int j = gtile * 16 + col;
  float sc = ((gtile >> 3) == 2) ? LOG2E2_ : LOG2E_;   // gate g rows get 2*log2e
  if (kc < 4){
    int k = kc * 32 + row * 8 + jj;
    float v = eWhh[((size_t)dir * G4_ + j) * H_ + k] * sc;
    wtile[((((size_t)dir * 32 + gtile) * 4 + kc) * 64 + lane) * 8 + jj] = (u16)f2bf(v);
  } else {
    int vdeg = row * 8 + jj;   // 0..31
    float v = 0.f;
    if (vdeg <= OPS_){
      const float4* wr = (const float4*)(eWih + (size_t)(dir * G4_ + j) * ED_);
      const float4* er = (const float4*)(eemb + (size_t)vdeg * ED_);
      float s = ebih[dir * G4_ + j] + ebhh[dir * G4_ + j];
      for (int k = 0; k < ED_ / 4; ++k){
        float4 wv = wr[k], ev = er[k];
        s += wv.x * ev.x + wv.y * ev.y + wv.z * ev.z + wv.w * ev.w;
      }
      v = s * sc;
    }
    wonehot[(((size_t)dir * 32 + gtile) * 64 + lane) * 8 + jj] = (u16)f2bf(v);
  }
}

__device__ void csr_count_body(int bid, const int* __restrict__ theads,
                               const int* __restrict__ ttails, int* __restrict__ counts)
{
  int e = bid * 512 + threadIdx.x;
  if (e < E_){
    atomicAdd(&counts[ttails[e]], 1);
    atomicAdd(&counts[theads[e]], 1);
  }
}

// ---- bfs1: mark 1-hop neighborhood of heads (both edge roles) + heads selves.
__device__ void bfs1_body(int bid, const int* __restrict__ heads,
                          const int* __restrict__ theads, const int* __restrict__ ttails,
                          u8* __restrict__ hs1)
{
  if (bid == 0 && threadIdx.x < B_) hs1[heads[threadIdx.x]] = 1;
  int e = bid * 512 + threadIdx.x;
  if (e < E_){
    int a = theads[e], t = ttails[e];
    #pragma unroll 8
    for (int i = 0; i < B_; ++i){
      int hd = heads[i];             // uniform -> scalar loads
      if (a == hd) hs1[t] = 1;
      if (t == hd) hs1[a] = 1;
    }
  }
}

// ---- front fat-kernel: wbuild | csr_count | bfs1 | zero(u2,mask,sumsP) | etile
__global__ __launch_bounds__(512) void front_kernel(
    const float* eWhh, const float* eemb, const float* eWih,
    const float* ebih, const float* ebhh, u16* wtile, u16* wonehot,
    const int* theads, const int* ttails, int* counts,
    const int* heads, u8* hs1,
    float* u2, int* maski, float* sumsP,
    const float* elinW, u16* etile)
{
  int bid = blockIdx.x;
  int tid = threadIdx.x;
  if (bid < WB_){
    wbuild_body(bid, eWhh, eemb, eWih, ebih, ebhh, wtile, wonehot);
  } else if (bid < WB_ + CB_){
    csr_count_body(bid - WB_, theads, ttails, counts);
  } else if (bid < WB_ + CB_ + BF_){
    bfs1_body(bid - WB_ - CB_, heads, theads, ttails, hs1);
  } else if (bid < WB_ + CB_ + BF_ + ZU_){
    int zb = bid - WB_ - CB_ - BF_;
    float4 z = {0.f, 0.f, 0.f, 0.f};
    size_t base = (size_t)zb * 8192 + tid * 4;
    #pragma unroll
    for (int k = 0; k < 4; ++k){
      size_t idx = base + (size_t)k * 2048;
      if (idx < (size_t)N_ * RB_) *(float4*)&u2[idx] = z;
    }
  } else if (bid < WB_ + CB_ + BF_ + ZU_ + ZM_){
    int mi = (bid - WB_ - CB_ - BF_ - ZU_) * 512 + tid;
    if (mi < (N_ + 3) / 4) maski[mi] = 0;
  } else if (bid < WB_ + CB_ + BF_ + ZU_ + ZM_ + ZS_){
    int si = (bid - WB_ - CB_ - BF_ - ZU_ - ZM_) * 512 + tid;
    if (si < PSLOTS * RB_) sumsP[si] = 0.f;
  } else {
    // elinW -> f16 MFMA B-frags: [2 op-tiles][8 ksteps][64 lanes][8] (16 KB)
    int idx = (bid - (WB_ + CB_ + BF_ + ZU_ + ZM_ + ZS_)) * 512 + tid;   // 0..8191
    if (idx < 8192){
      int jj = idx & 7;
      int lane = (idx >> 3) & 63;
      int ks = (idx >> 9) & 7;
      int ot = idx >> 12;
      int op = ot * 16 + (lane & 15);
      int k  = ks * 32 + (lane >> 4) * 8 + jj;
      float v = (op < OPS_) ? elinW[(size_t)op * (2 * H_) + k] : 0.f;
      _Float16 hv = (_Float16)v;
      etile[idx] = *(const u16*)&hv;
    }
  }
}

// ---- bfs2 body: 2-hop closure. mask = hs1 U adj(hs1). Superset of u2's rows.
// Rides in the elstm grid (needs only hs1 from front; mask consumed after).
__device__ void bfs2_body(int bid, const int* __restrict__ theads,
                          const int* __restrict__ ttails,
                          const u8* __restrict__ hs1, u8* __restrict__ mask)
{
  if (bid < BF2E_){
    int e = bid * 512 + threadIdx.x;
    if (e < E_){
      int a = theads[e], t = ttails[e];
      if (hs1[a]) mask[t] = 1;
      if (hs1[t]) mask[a] = 1;
    }
  } else {
    int n = (bid - BF2E_) * 512 + threadIdx.x;
    if (n < N_ && hs1[n]) mask[n] = 1;
  }
}

// ---- coalesced tile scan (512 threads, rides as block 0 of the elstm grid).
__device__ void scan_body(const int* __restrict__ counts, int* __restrict__ rowptr,
                          int* __restrict__ cursor, int* __restrict__ cursor2)
{
  __shared__ int wsum[8];
  int t = threadIdx.x;
  int lane = t & 63, wv = t >> 6;
  int carry = 0;   // live only in thread 0
  for (int base = 0; base < N_; base += 2048){
    int idx = base + t * 4;
    int c0 = 0, c1 = 0, c2 = 0, c3 = 0;
    if (idx + 3 < N_){
      int4 c = *(const int4*)&counts[idx];
      c0 = c.x; c1 = c.y; c2 = c.z; c3 = c.w;
    } else {
      if (idx     < N_) c0 = counts[idx];
      if (idx + 1 < N_) c1 = counts[idx + 1];
      if (idx + 2 < N_) c2 = counts[idx + 2];
      if (idx + 3 < N_) c3 = counts[idx + 3];
    }
    int s = c0 + c1 + c2 + c3;
    int sc = s;                          // inclusive wave scan
    #pragma unroll
    for (int off = 1; off < 64; off <<= 1){
      int v = __shfl_up(sc, off);
      if (lane >= off) sc += v;
    }
    if (lane == 63) wsum[wv] = sc;
    __syncthreads();
    if (t == 0){
      int acc = carry;
      #pragma unroll
      for (int w = 0; w < 8; ++w){ int v = wsum[w]; wsum[w] = acc; acc += v; }
      carry = acc;
    }
    __syncthreads();
    int excl = wsum[wv] + (sc - s);
    int r0 = excl, r1 = r0 + c0, r2 = r1 + c1, r3 = r2 + c2;
    if (idx + 3 < N_){
      int4 rv; rv.x = r0; rv.y = r1; rv.z = r2; rv.w = r3;
      *(int4*)&rowptr[idx]  = rv;
      *(int4*)&cursor[idx]  = rv;
      *(int4*)&cursor2[idx] = rv;
    } else {
      if (idx     < N_){ rowptr[idx]   = r0; cursor[idx]   = r0; cursor2[idx]   = r0; }
      if (idx + 1 < N_){ rowptr[idx+1] = r1; cursor[idx+1] = r1; cursor2[idx+1] = r1; }
      if (idx + 2 < N_){ rowptr[idx+2] = r2; cursor[idx+2] = r2; cursor2[idx+2] = r2; }
      if (idx + 3 < N_){ rowptr[idx+3] = r3; cursor[idx+3] = r3; cursor2[idx+3] = r3; }
    }
  }
  if (t == 0) rowptr[N_] = carry;
}

// ------ elstm MEGA-kernel: block 0 = scan rider; blocks 1..880 = bfs2 riders;
// 881..976 = qattn riders; remainder = entity BiLSTM (r10-exact structure) with
// the fused entity-attention epilogue. Short riders scheduled FIRST vacate slots
// quickly; the 1563 long elstm blocks backfill -> rider work overlaps elstm.
__global__ __launch_bounds__(512, 4) void elstm_kernel(
    const int* __restrict__ degs,
    const u16* __restrict__ wtile, const u16* __restrict__ wonehot,
    const u16* __restrict__ etile, const float* __restrict__ elinb,
    float* __restrict__ attn /* N,24 */,
    const int* __restrict__ counts, int* __restrict__ rowptr,
    int* __restrict__ cursor, int* __restrict__ cursor2,
    const int* __restrict__ theads, const int* __restrict__ ttails,
    const u8* __restrict__ hs1, u8* __restrict__ mask,
    const int* __restrict__ queries, const float* __restrict__ qemb,
    const float* __restrict__ qWih, const float* __restrict__ qWhh,
    const float* __restrict__ qbih, const float* __restrict__ qbhh,
    const float* __restrict__ qlinW, const float* __restrict__ qlinb,
    float* __restrict__ query_attn)
{
  int bid = blockIdx.x;
  if (bid == 0){ scan_body(counts, rowptr, cursor, cursor2); return; }
  if (bid < 1 + BF2E_ + BF2N_){ bfs2_body(bid - 1, theads, ttails, hs1, mask); return; }
  if (bid < RIDERS_){
    qattn_body(bid - (1 + BF2E_ + BF2N_), queries, qemb, qWih, qWhh, qbih, qbhh,
               qlinW, qlinb, query_attn);
    return;
  }

  int tid = threadIdx.x;
  int lane = tid & 63;
  int w = tid >> 6;          // wave 0..7
  int wu = __builtin_amdgcn_readfirstlane(w);   // provably wave-uniform
  int row = lane >> 4, col = lane & 15;
  int ebase = (bid - RIDERS_) * 32;

  __shared__ __align__(16) short hl[2][32 * HPAD];   // 2 x 10.5 KB ping-pong
  __shared__ __align__(16) short hfin[32 * 136];     // dir0 final h (8.5 KB)
  __shared__ float lgs[32][33];                      // epilogue logits (4.2 KB)

  int eg0 = ebase + tid; if (eg0 >= N_) eg0 = N_ - 1;   // valid for tid<32 use

  for (int i = tid; i < 2 * 32 * HPAD; i += 512) ((short*)hl)[i] = 0;
  __syncthreads();
  if (tid < 32) hl[0][tid * HPAD + H_ + degs[(size_t)eg0 * MAXDEG_ + 0]] = BF16_ONE;
  __syncthreads();

  int swzr = (col >> 2) & 3;   // read-side swizzle for entities col and 16+col

  for (int dir = 0; dir < 2; ++dir){
    const u16* Wt  = wtile   + (size_t)dir * 32 * 4 * 64 * 8;
    const u16* Woh = wonehot + (size_t)dir * 32 * 64 * 8;
    const u16* W0 = Wt + (size_t)((0 * 8 + wu) * 4 * 64) * 8;
    const u16* W1 = Wt + (size_t)((1 * 8 + wu) * 4 * 64) * 8;
    const u16* W2 = Wt + (size_t)((2 * 8 + wu) * 4 * 64) * 8;
    const u16* W3 = Wt + (size_t)((3 * 8 + wu) * 4 * 64) * 8;
    const u16* O0 = Woh + (size_t)((0 * 8 + wu) * 64) * 8;
    const u16* O1 = Woh + (size_t)((1 * 8 + wu) * 64) * 8;
    const u16* O2 = Woh + (size_t)((2 * 8 + wu) * 64) * 8;
    const u16* O3 = Woh + (size_t)((3 * 8 + wu) * 64) * 8;
    float cst[8];
    #pragma unroll
    for (int i = 0; i < 8; ++i) cst[i] = 0.f;

    for (int t = 0; t < MAXDEG_; ++t){
      const short* hb = hl[t & 1];          // holds h_t (+ one-hot for step t)
      short*       hw = hl[(t + 1) & 1];    // receives h_{t+1}
      f32x4 acc[8];
      #pragma unroll
      for (int i = 0; i < 8; ++i) acc[i] = (f32x4){0.f, 0.f, 0.f, 0.f};

      #pragma unroll 2
      for (int kc = 0; kc < 4; ++kc){
        bf16x8 af0 = *(const bf16x8*)&hb[(col) * HPAD + kc * 32 + (row ^ swzr) * 8];
        bf16x8 af1 = *(const bf16x8*)&hb[(16 + col) * HPAD + kc * 32 + (row ^ swzr) * 8];
        int lo = (kc * 64 + lane) * 8;
        bf16x8 b0 = *(const bf16x8*)(W0 + lo);
        bf16x8 b1 = *(const bf16x8*)(W1 + lo);
        bf16x8 b2 = *(const bf16x8*)(W2 + lo);
        bf16x8 b3 = *(const bf16x8*)(W3 + lo);
        acc[0] = __builtin_amdgcn_mfma_f32_16x16x32_bf16(af0, b0, acc[0], 0, 0, 0);
        acc[1] = __builtin_amdgcn_mfma_f32_16x16x32_bf16(af1, b0, acc[1], 0, 0, 0);
        acc[2] = __builtin_amdgcn_mfma_f32_16x16x32_bf16(af0, b1, acc[2], 0, 0, 0);
        acc[3] = __builtin_amdgcn_mfma_f32_16x16x32_bf16(af1, b1, acc[3], 0, 0, 0);
        acc[4] = __builtin_amdgcn_mfma_f32_16x16x32_bf16(af0, b2, acc[4], 0, 0, 0);
        acc[5] = __builtin_amdgcn_mfma_f32_16x16x32_bf16(af1, b2, acc[5], 0, 0, 0);
        acc[6] = __builtin_amdgcn_mfma_f32_16x16x32_bf16(af0, b3, acc[6], 0, 0, 0);
        acc[7] = __builtin_amdgcn_mfma_f32_16x16x32_bf16(af1, b3, acc[7], 0, 0, 0);
      }
      {
        bf16x8 af0 = *(const bf16x8*)&hb[(col) * HPAD + H_ + row * 8];
        bf16x8 af1 = *(const bf16x8*)&hb[(16 + col) * HPAD + H_ + row * 8];
        int lo = lane * 8;
        bf16x8 b0 = *(const bf16x8*)(O0 + lo);
        bf16x8 b1 = *(const bf16x8*)(O1 + lo);
        bf16x8 b2 = *(const bf16x8*)(O2 + lo);
        bf16x8 b3 = *(const bf16x8*)(O3 + lo);
        acc[0] = __builtin_amdgcn_mfma_f32_16x16x32_bf16(af0, b0, acc[0], 0, 0, 0);
        acc[1] = __builtin_amdgcn_mfma_f32_16x16x32_bf16(af1, b0, acc[1], 0, 0, 0);
        acc[2] = __builtin_amdgcn_mfma_f32_16x16x32_bf16(af0, b1, acc[2], 0, 0, 0);
        acc[3] = __builtin_amdgcn_mfma_f32_16x16x32_bf16(af1, b1, acc[3], 0, 0, 0);
        acc[4] = __builtin_amdgcn_mfma_f32_16x16x32_bf16(af0, b2, acc[4], 0, 0, 0);
        acc[5] = __builtin_amdgcn_mfma_f32_16x16x32_bf16(af1, b2, acc[5], 0, 0, 0);
        acc[6] = __builtin_amdgcn_mfma_f32_16x16x32_bf16(af0, b3, acc[6], 0, 0, 0);
        acc[7] = __builtin_amdgcn_mfma_f32_16x16x32_bf16(af1, b3, acc[7], 0, 0, 0);
      }

      #pragma unroll
      for (int mt = 0; mt < 2; ++mt){
        #pragma unroll
        for (int reg = 0; reg < 4; ++reg){
          int e = mt * 16 + row * 4 + reg;
          int jsw = (((wu * 2 + (col >> 3)) ^ row) * 8) + (col & 7);
          float Gi = acc[0 + mt][reg];
          float Gf = acc[2 + mt][reg];
          float Gg = acc[4 + mt][reg];
          float Go = acc[6 + mt][reg];
          int ci = mt * 4 + reg;
          float ea = fexp2(-Gi);
          float ef = fexp2(-Gf);
          float eb = fexp2(-Gg);
          float eo = fexp2(-Go);
          float t1 = 1.f + ef, t2 = 1.f + ea, t3 = 1.f + eb;
          float p = t2 * t3;
          float num = __builtin_fmaf(cst[ci], p, (1.f - eb) * t1);
          float cn = num * frcp(t1 * p);
          float ed = fexp2(cn * (-LOG2E2_));
          float hn = (1.f - ed) * frcp((1.f + eo) * (1.f + ed));
          cst[ci] = cn;
          hw[e * HPAD + jsw] = f2bf(hn);
        }
      }
      if (tid < 32){
        const int* dr = degs + (size_t)eg0 * MAXDEG_;
        if (t >= 1)
          hw[tid * HPAD + H_ + dr[dir ? (MAXDEG_ - t) : (t - 1)]] = 0;
        if (t < MAXDEG_ - 1)
          hw[tid * HPAD + H_ + dr[dir ? (MAXDEG_ - 2 - t) : (t + 1)]] = BF16_ONE;
      }
      __syncthreads();
    }

    if (dir == 0){
      for (int i = tid; i < 32 * 16; i += 512){
        int e = i >> 4, c = i & 15;
        int sz = (e >> 2) & 3;
        *(bf16x8*)&hfin[e * 136 + c * 8] =
            *(const bf16x8*)&hl[0][e * HPAD + ((c ^ sz) * 8)];
      }
      __syncthreads();
      for (int i = tid; i < 2 * 32 * HPAD; i += 512) ((short*)hl)[i] = 0;
      __syncthreads();
      if (tid < 32) hl[0][tid * HPAD + H_ + degs[(size_t)eg0 * MAXDEG_ + (MAXDEG_ - 1)]] = BF16_ONE;
      __syncthreads();
    }
  }

  // fused entity-attention epilogue
  if (wu < 4){
    int mt = wu >> 1, ot = wu & 1;
    int e2 = mt * 16 + col;
    f32x4 accL = (f32x4){0.f, 0.f, 0.f, 0.f};
    #pragma unroll
    for (int ks = 0; ks < 8; ++ks){
      bf16x8 ra;
      if (ks < 4) ra = *(const bf16x8*)&hfin[e2 * 136 + ks * 32 + row * 8];
      else        ra = *(const bf16x8*)&hl[0][e2 * HPAD + (ks - 4) * 32 + (row ^ swzr) * 8];
      f16x8 af;
      #pragma unroll
      for (int jj = 0; jj < 8; ++jj) af[jj] = (_Float16)bf2f((u16)ra[jj]);
      f16x8 bfr = *(const f16x8*)(etile + (((size_t)(ot * 8 + ks)) * 64 + lane) * 8);
      accL = __builtin_amdgcn_mfma_f32_16x16x32_f16(af, bfr, accL, 0, 0, 0);
    }
    #pragma unroll
    for (int reg = 0; reg < 4; ++reg){
      int ent = mt * 16 + (lane >> 4) * 4 + reg;
      int op  = ot * 16 + (lane & 15);
      float bb = (op < OPS_) ? elinb[op] : 0.f;
      lgs[ent][op] = accL[reg] + bb;
    }
  }
  __syncthreads();
  if (tid < 32){
    int n = ebase + tid;
    if (n < N_){
      float m = -1e30f;
      #pragma unroll
      for (int o = 0; o < OPS_; ++o) m = fmaxf(m, lgs[tid][o]);
      float s = 0.f;
      #pragma unroll
      for (int o = 0; o < OPS_; ++o) s += __expf(lgs[tid][o] - m);
      float inv = frcp(s);
      #pragma unroll
      for (int o = 0; o < OPS_; ++o)
        attn[(size_t)n * OPS_ + o] = __expf(lgs[tid][o] - m) * inv;
    }
  }
}

// ---- compact CSR fill (r10-exact) ----
__global__ void csr_fill_kernel(const int* __restrict__ rels, const int* __restrict__ theads,
                                const int* __restrict__ ttails, const float* __restrict__ attn,
                                const u8* __restrict__ mask, const u8* __restrict__ hs1,
                                int* __restrict__ cursor, int* __restrict__ cursor2,
                                uint2* __restrict__ ents, uint2* __restrict__ ents2)
{
  int e = blockIdx.x * 256 + threadIdx.x;
  if (e < E_){
    int hh = theads[e], tt = ttails[e];
    int mh = mask[hh], mt = mask[tt];
    if (!(mh | mt)) return;
    int rel = rels[e];
    unsigned wb = __float_as_uint(attn[(size_t)hh * OPS_ + rel]);
    if (mh){                         // fwd: src hh -> row tt
      uint2 v1; v1.x = (unsigned)hh | ((unsigned)rel << 16); v1.y = wb;
      ents[atomicAdd(&cursor[tt], 1)] = v1;
    }
    if (mt){                         // rev: src tt -> row hh
      uint2 v2; v2.x = (unsigned)tt | ((unsigned)(rel + OPS_/2) << 16); v2.y = wb;
      ents[atomicAdd(&cursor[hh], 1)] = v2;
    }
    if (hs1[hh]){                    // out-edge of hh
      uint2 w1; w1.x = (unsigned)tt | ((unsigned)rel << 16); w1.y = wb;
      ents2[atomicAdd(&cursor2[hh], 1)] = w1;
    }
    if (hs1[tt]){                    // out-edge of tt (reverse op)
      uint2 w2; w2.x = (unsigned)hh | ((unsigned)(rel + OPS_/2) << 16); w2.y = wb;
      ents2[atomicAdd(&cursor2[tt], 1)] = w2;
    }
  }
}

// ---- fused sparse t=0 + t=1 (r10-exact) ----
__global__ void t01_kernel(const int* __restrict__ heads, const float* __restrict__ query_attn,
                           const int* __restrict__ rowptr, const int* __restrict__ cend2,
                           const uint2* __restrict__ ents2, float* __restrict__ u2)
{
  __shared__ float qa0[OPS_ + 1], qa1[OPS_ + 1];
  int blk = blockIdx.x;   // 0..95
  int r = blk >> 5, b = blk & 31;
  int rb = r * 32 + b;
  int tid = threadIdx.x;  // 64
  if (tid < OPS_ + 1){
    qa0[tid] = query_attn[((size_t)(r * T_ + 0) * B_ + b) * (OPS_ + 1) + tid];
    qa1[tid] = query_attn[((size_t)(r * T_ + 1) * B_ + b) * (OPS_ + 1) + tid];
  }
  __syncthreads();
  int hd = heads[b];
  int beg = rowptr[hd], end = cend2[hd];
  float q024 = qa0[OPS_], q124 = qa1[OPS_];
  if (tid == 0) atomicAdd(&u2[(size_t)hd * RB_ + rb], q124 * q024);
  for (int i = beg + tid; i < end; i += 64){
    uint2 e1 = ents2[i];
    int s  = (int)(e1.x & 0xFFFFu);
    int r1 = (int)(e1.x >> 16);
    float w1 = __uint_as_float(e1.y);
    atomicAdd(&u2[(size_t)s * RB_ + rb], w1 * (q124 * qa0[r1] + qa1[r1] * q024));
    float v1 = qa0[r1] * w1;      // this path's share of u1[s]
    int b2 = rowptr[s], e2e = cend2[s];
    for (int jj = b2; jj < e2e; ++jj){
      uint2 e2 = ents2[jj];
      int d2 = (int)(e2.x & 0xFFFFu);
      int r2 = (int)(e2.x >> 16);
      atomicAdd(&u2[(size_t)d2 * RB_ + rb], qa1[r2] * __uint_as_float(e2.y) * v1);
    }
  }
}

// ---- dense gather (t=2), compact in-CSR + dead-row skipping:
// rows with empty compact row AND unmasked node are exactly zero -> whole-block
// early exit (before qas staging) when all 4 nodes trivial; per-node write skip
// otherwise (fintrans zero-fills via the same predicate).
__global__ __launch_bounds__(256) void gather3_kernel(
    const float* __restrict__ ucur, float* __restrict__ unxt,
    const float* __restrict__ query_attn, int t,
    const int* __restrict__ rowptr, const int* __restrict__ cend,
    const uint2* __restrict__ ents, const u8* __restrict__ mask,
    float* __restrict__ partial /* PSLOTS x 96 */)
{
  __shared__ float qas[3 * B_ * (OPS_ + 1)];  // [r][b][o]
  __shared__ float red[RB_];
  int tid = threadIdx.x;
  int b  = tid & 31;
  int h  = (tid >> 5) & 1;              // half within wave
  int n = blockIdx.x * 4 + (tid >> 6);  // one wave per node; grid*4 == N_
  int beg = rowptr[n], end = cend[n];
  int mk = mask[n];
  int cnt = end - beg;
  if (__syncthreads_and(cnt == 0 && !mk)) return;   // all 4 nodes trivial

  for (int i = tid; i < 3 * B_ * (OPS_ + 1); i += 256){
    int r = i / (B_ * (OPS_ + 1));
    int rem = i - r * (B_ * (OPS_ + 1));
    qas[i] = query_attn[(size_t)(r * T_ + t) * B_ * (OPS_ + 1) + rem];
  }
  if (tid < RB_) red[tid] = 0.f;
  __syncthreads();
  const float* q0 = &qas[0 * 800 + b * (OPS_ + 1)];
  const float* q1 = &qas[1 * 800 + b * (OPS_ + 1)];
  const float* q2 = &qas[2 * 800 + b * (OPS_ + 1)];
  size_t nb = (size_t)n * RB_;
  float a0 = 0.f, a1 = 0.f, a2 = 0.f;
  if (h == 0 && mk){
    a0 = ucur[nb + b]      * q0[OPS_];
    a1 = ucur[nb + 32 + b] * q1[OPS_];
    a2 = ucur[nb + 64 + b] * q2[OPS_];
  }
  int nq = cnt >> 2;                 // full 4-edge chunks
  for (int c = h; c < nq; c += 2){
    int i0 = beg + 4 * c;
    uint2 e0 = ents[i0 + 0];
    uint2 e1 = ents[i0 + 1];
    uint2 e2 = ents[i0 + 2];
    uint2 e3 = ents[i0 + 3];
    size_t s0 = (size_t)(e0.x & 0xFFFFu) * RB_;
    size_t s1 = (size_t)(e1.x & 0xFFFFu) * RB_;
    size_t s2 = (size_t)(e2.x & 0xFFFFu) * RB_;
    size_t s3 = (size_t)(e3.x & 0xFFFFu) * RB_;
    float u00 = ucur[s0 + b], u01 = ucur[s0 + 32 + b], u02 = ucur[s0 + 64 + b];
    float u10 = ucur[s1 + b], u11 = ucur[s1 + 32 + b], u12 = ucur[s1 + 64 + b];
    float u20 = ucur[s2 + b], u21 = ucur[s2 + 32 + b], u22 = ucur[s2 + 64 + b];
    float u30 = ucur[s3 + b], u31 = ucur[s3 + 32 + b], u32 = ucur[s3 + 64 + b];
    int r0 = (int)(e0.x >> 16), r1 = (int)(e1.x >> 16);
    int r2 = (int)(e2.x >> 16), r3 = (int)(e3.x >> 16);
    float w0 = __uint_as_float(e0.y), w1 = __uint_as_float(e1.y);
    float w2 = __uint_as_float(e2.y), w3 = __uint_as_float(e3.y);
    a0 += q0[r0]*w0*u00 + q0[r1]*w1*u10 + q0[r2]*w2*u20 + q0[r3]*w3*u30;
    a1 += q1[r0]*w0*u01 + q1[r1]*w1*u11 + q1[r2]*w2*u21 + q1[r3]*w3*u31;
    a2 += q2[r0]*w0*u02 + q2[r1]*w1*u12 + q2[r2]*w2*u22 + q2[r3]*w3*u32;
  }
  if (h == 1){
    for (int i = beg + 4 * nq; i < end; ++i){
      uint2 e0 = ents[i];
      size_t s0 = (size_t)(e0.x & 0xFFFFu) * RB_;
      int r0 = (int)(e0.x >> 16);
      float w0 = __uint_as_float(e0.y);
      a0 += q0[r0] * w0 * ucur[s0 + b];
      a1 += q1[r0] * w0 * ucur[s0 + 32 + b];
      a2 += q2[r0] * w0 * ucur[s0 + 64 + b];
    }
  }
  a0 += __shfl_xor(a0, 32);
  a1 += __shfl_xor(a1, 32);
  a2 += __shfl_xor(a2, 32);
  if (h == 0 && (mk || cnt > 0)){
    unxt[nb + b]      = a0;
    unxt[nb + 32 + b] = a1;
    unxt[nb + 64 + b] = a2;
    atomicAdd(&red[b], a0);
    atomicAdd(&red[32 + b], a1);
    atomicAdd(&red[64 + b], a2);
  }
  __syncthreads();
  if (tid < RB_)
    atomicAdd(&partial[(blockIdx.x & (PSLOTS - 1)) * RB_ + tid], red[tid]);
}

// ---- finalize + transpose: dead rows (empty compact row & unmasked) are zero
// WITHOUT loading u (gather3 skipped writing them).
__global__ void fintrans_kernel(const float* __restrict__ u, const float* __restrict__ partial,
                                const int* __restrict__ rowptr, const int* __restrict__ cend,
                                const u8* __restrict__ mask,
                                float* __restrict__ out)
{
  __shared__ float sinv[RB_];
  __shared__ float t[B_][72];
  int tid = threadIdx.x;   // 256
  if (tid < RB_){
    float s = 0.f;
    #pragma unroll 8
    for (int k = 0; k < PSLOTS; ++k) s += partial[k * RB_ + tid];
    sinv[tid] = frcp(fmaxf(1e-20f, s));
  }
  __syncthreads();
  int n0 = blockIdx.x * 64;
  for (int i = tid; i < 64 * B_; i += 256){
    int nl = i >> 5, b = i & 31;
    int n = n0 + nl;
    float v = 0.f;
    if (n < N_ && (mask[n] || cend[n] > rowptr[n])){
      size_t nb = (size_t)n * RB_;
      v = u[nb + b] * sinv[b] + u[nb + 32 + b] * sinv[32 + b] + u[nb + 64 + b] * sinv[64 + b];
    }
    t[b][nl] = v;
  }
  __syncthreads();
  for (int i = tid; i < 64 * B_; i += 256){
    int b = i >> 6, nl = i & 63;
    int n = n0 + nl;
    if (n < N_) out[(size_t)b * N_ + n] = t[b][nl];
  }
}

extern "C" void kernel_launch(void* const* d_in, const int* in_sizes, int n_in,
                              void* d_out, int out_size, void* d_ws, size_t ws_size,
                              hipStream_t stream)
{
  const int*   queries = (const int*)d_in[0];
  const int*   heads   = (const int*)d_in[1];
  const int*   rels    = (const int*)d_in[2];
  const int*   t_heads = (const int*)d_in[3];
  const int*   t_tails = (const int*)d_in[4];
  const int*   edeg    = (const int*)d_in[5];
  const float* qemb    = (const float*)d_in[6];
  const float* eemb    = (const float*)d_in[7];
  const float* qWih    = (const float*)d_in[8];
  const float* qWhh    = (const float*)d_in[9];
  const float* qbih    = (const float*)d_in[10];
  const float* qbhh    = (const float*)d_in[11];
  const float* eWih    = (const float*)d_in[12];
  const float* eWhh    = (const float*)d_in[13];
  const float* ebih    = (const float*)d_in[14];
  const float* ebhh    = (const float*)d_in[15];
  const float* qlinW   = (const float*)d_in[16];
  const float* qlinb   = (const float*)d_in[17];
  const float* elinW   = (const float*)d_in[18];
  const float* elinb   = (const float*)d_in[19];
  float* out = (float*)d_out;

  char* ws = (char*)d_ws;
  size_t off = 0;
  auto alloc = [&](size_t bytes){ void* p = ws + off; off += (bytes + 255) & ~(size_t)255; return p; };
  // bigB (19.2 MB): attn (4.8 MB) during [elstm, csr_fill]; then u3 (gather3 out).
  char*  bigB  = (char*)alloc((size_t)N_ * RB_ * 4);
  float* attn  = (float*)bigB;
  float* u3    = (float*)bigB;
  uint2* ents       = (uint2*)alloc((size_t)2 * E_ * 8);              // in-CSR (compact-filled)
  float* u2         = (float*)alloc((size_t)N_ * RB_ * 4);            // 19.2 MB
  uint2* ents2      = (uint2*)alloc((size_t)2 * E_ * 8);              // out-CSR (compact-filled)
  float* query_attn = (float*)alloc((size_t)R_ * T_ * B_ * (OPS_ + 1) * 4);
  u16*   wtile      = (u16*)  alloc((size_t)2 * 32 * 4 * 64 * 8 * 2);
  u16*   wonehot    = (u16*)  alloc((size_t)2 * 32 * 64 * 8 * 2);
  u16*   etile      = (u16*)  alloc((size_t)2 * 8 * 64 * 8 * 2);      // 16 KB
  int*   counts     = (int*)  alloc((size_t)(N_ + 1) * 4);
  int*   rowptr     = (int*)  alloc((size_t)(N_ + 1) * 4);
  int*   cursor     = (int*)  alloc((size_t)(N_ + 1) * 4);
  int*   cursor2    = (int*)  alloc((size_t)(N_ + 1) * 4);
  u8*    hs1        = (u8*)   alloc((size_t)N_);
  u8*    mask       = (u8*)   alloc((size_t)N_);
  float* sumsP      = (float*)alloc((size_t)PSLOTS * RB_ * 4);
  // total ~52 MB

  // counts + hs1 must be zero BEFORE front (csr_count atomics / bfs1 marks ride it);
  // u2 / mask / sumsP are zeroed inside front (consumed only later).
  hipMemsetAsync(counts, 0, (size_t)(N_ + 1) * 4, stream);
  hipMemsetAsync(hs1, 0, (size_t)N_, stream);

  front_kernel<<<WB_ + CB_ + BF_ + ZU_ + ZM_ + ZS_ + EB_, 512, 0, stream>>>(
      eWhh, eemb, eWih, ebih, ebhh, wtile, wonehot,
      t_heads, t_tails, counts, heads, hs1, u2, (int*)mask, sumsP, elinW, etile);
  // MEGA: scan (blk 0) | bfs2 riders | qattn riders | elstm + attention epilogue
  elstm_kernel<<<RIDERS_ + SCANBLK_, 512, 0, stream>>>(
      edeg, wtile, wonehot, etile, elinb, attn,
      counts, rowptr, cursor, cursor2,
      t_heads, t_tails, hs1, mask,
      queries, qemb, qWih, qWhh, qbih, qbhh, qlinW, qlinb, query_attn);
  // compact CSR fill (cursor/cursor2 become compact row ends)
  csr_fill_kernel<<<(E_ + 255) / 256, 256, 0, stream>>>(rels, t_heads, t_tails, attn,
                                                        mask, hs1, cursor, cursor2,
                                                        ents, ents2);
  // fused t=0 + t=1 sparse propagation into u2
  t01_kernel<<<RB_, 64, 0, stream>>>(heads, query_attn, rowptr, cursor2, ents2, u2);
  // t=2: dense gather over compact in-CSR (attn dead; u3 overwrites bigB)
  gather3_kernel<<<N_ / 4, 256, 0, stream>>>(u2, u3, query_attn, 2, rowptr, cursor,
                                             ents, mask, sumsP);
  fintrans_kernel<<<(N_ + 63) / 64, 256, 0, stream>>>(u3, sumsP, rowptr, cursor,
                                                      mask, out);
}

// Round 12
// 442.814 us; speedup vs baseline: 2.2468x; 1.0169x over previous
//
#include <hip/hip_runtime.h>

#define R_ 3
#define T_ 3
#define N_ 50000
#define OPS_ 24
#define E_ 400000
#define B_ 32
#define MAXDEG_ 8
#define QD_ 128
#define ED_ 128
#define H_ 128
#define G4_ (4*H_)   /* 512 */
#define HPAD 168     /* padded LDS h-row (bf16): 128 h + 25 one-hot + pad, 336 B */
#define PSLOTS 64    /* partial row-sum slots */
#define RB_ 96       /* 3 rounds x 32 batch */

/* front fat-kernel block ranges (512-thread blocks) */
#define WB_ ((2*32*5*64*8 + 511) / 512)        /* 320  wbuild */
#define CB_ ((E_ + 511) / 512)                 /* 782  csr_count */
#define BF_ ((E_ + 511) / 512)                 /* 782  bfs1 (1-hop mark) */
#define ZU_ 586                                /* u2 zero: 4.8M floats / 8192 */
#define ZM_ 25                                 /* mask zero: 12500 ints / 512 */
#define ZS_ 12                                 /* sumsP zero: 6144 / 512 */
#define EB_ 16                                 /* etile build: 8192 / 512 */

/* elstm mega-grid layout: [qattn riders][elstm blocks][scan+bfs2 riders]
   qattn (96 medium blocks) FIRST: long poles, start early, small slot cost.
   scan/bfs2 (881 short blocks) LAST: backfill idle slots during elstm's
   final-generation drain instead of delaying its start (round-11 lesson:
   riders-first serialized +29us at the head of the grid). */
#define QB_ (R_ * B_)                          /* 96  qattn riders (first) */
#define SCANBLK_ ((N_ + 31) / 32)              /* 1563 elstm blocks */
#define BF2E_ ((E_ + 511) / 512)               /* 782 bfs2 edge riders */
#define BF2N_ ((N_ + 511) / 512)               /* 98  bfs2 node riders */
#define TAILR_ (1 + BF2E_ + BF2N_)             /* 881 tail riders: scan + bfs2 */

typedef unsigned short u16;
typedef unsigned char u8;
typedef __attribute__((ext_vector_type(8))) short bf16x8;     // 8 bf16 = 4 VGPRs
typedef __attribute__((ext_vector_type(8))) _Float16 f16x8;   // 8 f16  = 4 VGPRs
typedef __attribute__((ext_vector_type(4))) float f32x4;

#define BF16_ONE ((short)0x3F80)
#define LOG2E_  1.44269504f
#define LOG2E2_ 2.88539008f

__device__ __forceinline__ short f2bf(float f){
  union { float f; unsigned u; } v; v.f = f;
  unsigned r = v.u + 0x7fffu + ((v.u >> 16) & 1u);
  return (short)(r >> 16);
}
__device__ __forceinline__ float bf2f(u16 u){
  union { unsigned u; float f; } v; v.u = ((unsigned)u) << 16; return v.f;
}
__device__ __forceinline__ float frcp(float x){ return __builtin_amdgcn_rcpf(x); }
__device__ __forceinline__ float fsig(float x){ return frcp(1.0f + __expf(-x)); }
__device__ __forceinline__ float ftanh(float x){
  return __builtin_fmaf(2.0f, fsig(2.0f * x), -1.0f);
}
__device__ __forceinline__ float fexp2(float x){
#if __has_builtin(__builtin_amdgcn_exp2f)
  return __builtin_amdgcn_exp2f(x);
#else
  return __expf(x * 0.6931471806f);
#endif
}

// ------- query BiLSTM + attention: 512-thread body, dirs run concurrently -------
// Output consumed only AFTER the elstm mega-kernel -> safe to ride in its grid.
__device__ void qattn_body(int bid, const int* __restrict__ queries, const float* __restrict__ qemb,
    const float* __restrict__ qWih, const float* __restrict__ qWhh,
    const float* __restrict__ qbih, const float* __restrict__ qbhh,
    const float* __restrict__ qlinW, const float* __restrict__ qlinb,
    float* __restrict__ query_attn /* R,T,B,25 */)
{
  int r = bid / B_;
  int b = bid % B_;
  int tid = threadIdx.x;   // 512
  int d   = tid >> 8;      // direction
  int t2  = tid & 255;
  __shared__ float x[QD_];
  __shared__ float gx[2][G4_];
  __shared__ float h[2][H_], c[2][H_];
  __shared__ float gtmp[2][G4_];
  __shared__ float hh[2][T_][H_];
  __shared__ float lg[OPS_ + 1];

  int q = queries[b];
  if (tid < QD_) x[tid] = qemb[q * QD_ + tid];
  __syncthreads();

  const float* Wih = qWih + (size_t)(r * 2 + d) * G4_ * QD_;
  const float* Whh = qWhh + (size_t)(r * 2 + d) * G4_ * H_;
  const float* bih = qbih + (r * 2 + d) * G4_;
  const float* bhh = qbhh + (r * 2 + d) * G4_;
  for (int j = t2; j < G4_; j += 256){
    const float4* wr = (const float4*)(Wih + (size_t)j * QD_);
    float s = bih[j] + bhh[j];
    for (int k = 0; k < QD_ / 4; ++k){
      float4 wv = wr[k];
      s += wv.x * x[4*k] + wv.y * x[4*k+1] + wv.z * x[4*k+2] + wv.w * x[4*k+3];
    }
    gx[d][j] = s;
  }
  if (t2 < H_){ h[d][t2] = 0.f; c[d][t2] = 0.f; }
  __syncthreads();
  for (int t = 0; t < T_; ++t){
    for (int j = t2; j < G4_; j += 256){
      const float4* wr = (const float4*)(Whh + (size_t)j * H_);
      float s = 0.f;
      for (int k = 0; k < H_ / 4; ++k){
        float4 wv = wr[k];
        s += wv.x * h[d][4*k] + wv.y * h[d][4*k+1] + wv.z * h[d][4*k+2] + wv.w * h[d][4*k+3];
      }
      gtmp[d][j] = gx[d][j] + s;
    }
    __syncthreads();
    if (t2 < H_){
      float gi = gtmp[d][t2], gf = gtmp[d][t2 + H_], gg = gtmp[d][t2 + 2*H_], go = gtmp[d][t2 + 3*H_];
      float cn = fsig(gf) * c[d][t2] + fsig(gi) * ftanh(gg);
      float hn = fsig(go) * ftanh(cn);
      c[d][t2] = cn; h[d][t2] = hn;
      hh[d][t][t2] = hn;
    }
    __syncthreads();
  }

  for (int t = 0; t < T_; ++t){
    if (tid < OPS_ + 1){
      const float* wr = qlinW + tid * (2 * H_);
      float s = qlinb[tid];
      for (int k = 0; k < H_; ++k) s += wr[k] * hh[0][t][k];
      for (int k = 0; k < H_; ++k) s += wr[H_ + k] * hh[1][T_ - 1 - t][k];
      lg[tid] = s;
    }
    __syncthreads();
    if (tid == 0){
      float m = -1e30f;
      for (int o = 0; o < OPS_ + 1; ++o) m = fmaxf(m, lg[o]);
      float sum = 0.f;
      for (int o = 0; o < OPS_ + 1; ++o){ float e = __expf(lg[o] - m); lg[o] = e; sum += e; }
      float inv = frcp(sum);
      for (int o = 0; o < OPS_ + 1; ++o) lg[o] *= inv;
    }
    __syncthreads();
    if (tid < OPS_ + 1) query_attn[((size_t)(r * T_ + t) * B_ + b) * (OPS_ + 1) + tid] = lg[tid];
    __syncthreads();
  }
}

// ---- build B-operand buffers in MFMA-fragment order (eproj folded in) ----
__device__ void wbuild_body(int bid, const float* __restrict__ eWhh,
                            const float* __restrict__ eemb, const float* __restrict__ eWih,
                            const float* __restrict__ ebih, const float* __restrict__ ebhh,
                            u16* __restrict__ wtile, u16* __restrict__ wonehot)
{
  int idx = bid * 512 + threadIdx.x;    // 2*32*5*64*8 = 163840
  if (idx >= 2 * 32 * 5 * 64 * 8) return;
  int jj = idx & 7;
  int lane = (idx >> 3) & 63;
  int kc = (idx >> 9) % 5;
  int gtile = (idx / (8 * 64 * 5)) & 31;
  int dir = idx / (8 * 64 * 5 * 32);
  int row = lane >> 4, col = lane & 15;
  int j = gtile * 16 + col;
  float sc = ((gtile >> 3) == 2) ? LOG2E2_ : LOG2E_;   // gate g rows get 2*log2e
  if (kc < 4){
    int k = kc * 32 + row * 8 + jj;
    float v = eWhh[((size_t)dir * G4_ + j) * H_ + k] * sc;
    wtile[((((size_t)dir * 32 + gtile) * 4 + kc) * 64 + lane) * 8 + jj] = (u16)f2bf(v);
  } else {
    int vdeg = row * 8 + jj;   // 0..31
    float v = 0.f;
    if (vdeg <= OPS_){
      const float4* wr = (const float4*)(eWih + (size_t)(dir * G4_ + j) * ED_);
      const float4* er = (const float4*)(eemb + (size_t)vdeg * ED_);
      float s = ebih[dir * G4_ + j] + ebhh[dir * G4_ + j];
      for (int k = 0; k < ED_ / 4; ++k){
        float4 wv = wr[k], ev = er[k];
        s += wv.x * ev.x + wv.y * ev.y + wv.z * ev.z + wv.w * ev.w;
      }
      v = s * sc;
    }
    wonehot[(((size_t)dir * 32 + gtile) * 64 + lane) * 8 + jj] = (u16)f2bf(v);
  }
}

__device__ void csr_count_body(int bid, const int* __restrict__ theads,
                               const int* __restrict__ ttails, int* __restrict__ counts)
{
  int e = bid * 512 + threadIdx.x;
  if (e < E_){
    atomicAdd(&counts[ttails[e]], 1);
    atomicAdd(&counts[theads[e]], 1);
  }
}

// ---- bfs1: mark 1-hop neighborhood of heads (both edge roles) + heads selves.
__device__ void bfs1_body(int bid, const int* __restrict__ heads,
                          const int* __restrict__ theads, const int* __restrict__ ttails,
                          u8* __restrict__ hs1)
{
  if (bid == 0 && threadIdx.x < B_) hs1[heads[threadIdx.x]] = 1;
  int e = bid * 512 + threadIdx.x;
  if (e < E_){
    int a = theads[e], t = ttails[e];
    #pragma unroll 8
    for (int i = 0; i < B_; ++i){
      int hd = heads[i];             // uniform -> scalar loads
      if (a == hd) hs1[t] = 1;
      if (t == hd) hs1[a] = 1;
    }
  }
}

// ---- front fat-kernel: wbuild | csr_count | bfs1 | zero(u2,mask,sumsP) | etile
__global__ __launch_bounds__(512) void front_kernel(
    const float* eWhh, const float* eemb, const float* eWih,
    const float* ebih, const float* ebhh, u16* wtile, u16* wonehot,
    const int* theads, const int* ttails, int* counts,
    const int* heads, u8* hs1,
    float* u2, int* maski, float* sumsP,
    const float* elinW, u16* etile)
{
  int bid = blockIdx.x;
  int tid = threadIdx.x;
  if (bid < WB_){
    wbuild_body(bid, eWhh, eemb, eWih, ebih, ebhh, wtile, wonehot);
  } else if (bid < WB_ + CB_){
    csr_count_body(bid - WB_, theads, ttails, counts);
  } else if (bid < WB_ + CB_ + BF_){
    bfs1_body(bid - WB_ - CB_, heads, theads, ttails, hs1);
  } else if (bid < WB_ + CB_ + BF_ + ZU_){
    int zb = bid - WB_ - CB_ - BF_;
    float4 z = {0.f, 0.f, 0.f, 0.f};
    size_t base = (size_t)zb * 8192 + tid * 4;
    #pragma unroll
    for (int k = 0; k < 4; ++k){
      size_t idx = base + (size_t)k * 2048;
      if (idx < (size_t)N_ * RB_) *(float4*)&u2[idx] = z;
    }
  } else if (bid < WB_ + CB_ + BF_ + ZU_ + ZM_){
    int mi = (bid - WB_ - CB_ - BF_ - ZU_) * 512 + tid;
    if (mi < (N_ + 3) / 4) maski[mi] = 0;
  } else if (bid < WB_ + CB_ + BF_ + ZU_ + ZM_ + ZS_){
    int si = (bid - WB_ - CB_ - BF_ - ZU_ - ZM_) * 512 + tid;
    if (si < PSLOTS * RB_) sumsP[si] = 0.f;
  } else {
    // elinW -> f16 MFMA B-frags: [2 op-tiles][8 ksteps][64 lanes][8] (16 KB)
    int idx = (bid - (WB_ + CB_ + BF_ + ZU_ + ZM_ + ZS_)) * 512 + tid;   // 0..8191
    if (idx < 8192){
      int jj = idx & 7;
      int lane = (idx >> 3) & 63;
      int ks = (idx >> 9) & 7;
      int ot = idx >> 12;
      int op = ot * 16 + (lane & 15);
      int k  = ks * 32 + (lane >> 4) * 8 + jj;
      float v = (op < OPS_) ? elinW[(size_t)op * (2 * H_) + k] : 0.f;
      _Float16 hv = (_Float16)v;
      etile[idx] = *(const u16*)&hv;
    }
  }
}

// ---- bfs2 body: 2-hop closure. mask = hs1 U adj(hs1). Superset of u2's rows.
__device__ void bfs2_body(int bid, const int* __restrict__ theads,
                          const int* __restrict__ ttails,
                          const u8* __restrict__ hs1, u8* __restrict__ mask)
{
  if (bid < BF2E_){
    int e = bid * 512 + threadIdx.x;
    if (e < E_){
      int a = theads[e], t = ttails[e];
      if (hs1[a]) mask[t] = 1;
      if (hs1[t]) mask[a] = 1;
    }
  } else {
    int n = (bid - BF2E_) * 512 + threadIdx.x;
    if (n < N_ && hs1[n]) mask[n] = 1;
  }
}

// ---- coalesced tile scan (512 threads, tail rider of the elstm grid).
__device__ void scan_body(const int* __restrict__ counts, int* __restrict__ rowptr,
                          int* __restrict__ cursor, int* __restrict__ cursor2)
{
  __shared__ int wsum[8];
  int t = threadIdx.x;
  int lane = t & 63, wv = t >> 6;
  int carry = 0;   // live only in thread 0
  for (int base = 0; base < N_; base += 2048){
    int idx = base + t * 4;
    int c0 = 0, c1 = 0, c2 = 0, c3 = 0;
    if (idx + 3 < N_){
      int4 c = *(const int4*)&counts[idx];
      c0 = c.x; c1 = c.y; c2 = c.z; c3 = c.w;
    } else {
      if (idx     < N_) c0 = counts[idx];
      if (idx + 1 < N_) c1 = counts[idx + 1];
      if (idx + 2 < N_) c2 = counts[idx + 2];
      if (idx + 3 < N_) c3 = counts[idx + 3];
    }
    int s = c0 + c1 + c2 + c3;
    int sc = s;                          // inclusive wave scan
    #pragma unroll
    for (int off = 1; off < 64; off <<= 1){
      int v = __shfl_up(sc, off);
      if (lane >= off) sc += v;
    }
    if (lane == 63) wsum[wv] = sc;
    __syncthreads();
    if (t == 0){
      int acc = carry;
      #pragma unroll
      for (int w = 0; w < 8; ++w){ int v = wsum[w]; wsum[w] = acc; acc += v; }
      carry = acc;
    }
    __syncthreads();
    int excl = wsum[wv] + (sc - s);
    int r0 = excl, r1 = r0 + c0, r2 = r1 + c1, r3 = r2 + c2;
    if (idx + 3 < N_){
      int4 rv; rv.x = r0; rv.y = r1; rv.z = r2; rv.w = r3;
      *(int4*)&rowptr[idx]  = rv;
      *(int4*)&cursor[idx]  = rv;
      *(int4*)&cursor2[idx] = rv;
    } else {
      if (idx     < N_){ rowptr[idx]   = r0; cursor[idx]   = r0; cursor2[idx]   = r0; }
      if (idx + 1 < N_){ rowptr[idx+1] = r1; cursor[idx+1] = r1; cursor2[idx+1] = r1; }
      if (idx + 2 < N_){ rowptr[idx+2] = r2; cursor[idx+2] = r2; cursor2[idx+2] = r2; }
      if (idx + 3 < N_){ rowptr[idx+3] = r3; cursor[idx+3] = r3; cursor2[idx+3] = r3; }
    }
  }
  if (t == 0) rowptr[N_] = carry;
}

// ------ elstm MEGA-kernel, grid = [qattn 96][elstm 1563][scan+bfs2 881].
// qattn first (long poles, tiny slot cost); cheap riders LAST so they backfill
// the idle slots of elstm's final-generation drain (r11: riders-first cost +29us).
__global__ __launch_bounds__(512, 4) void elstm_kernel(
    const int* __restrict__ degs,
    const u16* __restrict__ wtile, const u16* __restrict__ wonehot,
    const u16* __restrict__ etile, const float* __restrict__ elinb,
    float* __restrict__ attn /* N,24 */,
    const int* __restrict__ counts, int* __restrict__ rowptr,
    int* __restrict__ cursor, int* __restrict__ cursor2,
    const int* __restrict__ theads, const int* __restrict__ ttails,
    const u8* __restrict__ hs1, u8* __restrict__ mask,
    const int* __restrict__ queries, const float* __restrict__ qemb,
    const float* __restrict__ qWih, const float* __restrict__ qWhh,
    const float* __restrict__ qbih, const float* __restrict__ qbhh,
    const float* __restrict__ qlinW, const float* __restrict__ qlinb,
    float* __restrict__ query_attn)
{
  int bid = blockIdx.x;
  if (bid < QB_){
    qattn_body(bid, queries, qemb, qWih, qWhh, qbih, qbhh, qlinW, qlinb, query_attn);
    return;
  }
  int eb = bid - QB_;
  if (eb >= SCANBLK_){
    int rid = eb - SCANBLK_;
    if (rid == 0) scan_body(counts, rowptr, cursor, cursor2);
    else          bfs2_body(rid - 1, theads, ttails, hs1, mask);
    return;
  }

  int tid = threadIdx.x;
  int lane = tid & 63;
  int w = tid >> 6;          // wave 0..7
  int wu = __builtin_amdgcn_readfirstlane(w);   // provably wave-uniform
  int row = lane >> 4, col = lane & 15;
  int ebase = eb * 32;

  __shared__ __align__(16) short hl[2][32 * HPAD];   // 2 x 10.5 KB ping-pong
  __shared__ __align__(16) short hfin[32 * 136];     // dir0 final h (8.5 KB)
  __shared__ float lgs[32][33];                      // epilogue logits (4.2 KB)

  int eg0 = ebase + tid; if (eg0 >= N_) eg0 = N_ - 1;   // valid for tid<32 use

  for (int i = tid; i < 2 * 32 * HPAD; i += 512) ((short*)hl)[i] = 0;
  __syncthreads();
  if (tid < 32) hl[0][tid * HPAD + H_ + degs[(size_t)eg0 * MAXDEG_ + 0]] = BF16_ONE;
  __syncthreads();

  int swzr = (col >> 2) & 3;   // read-side swizzle for entities col and 16+col

  for (int dir = 0; dir < 2; ++dir){
    const u16* Wt  = wtile   + (size_t)dir * 32 * 4 * 64 * 8;
    const u16* Woh = wonehot + (size_t)dir * 32 * 64 * 8;
    const u16* W0 = Wt + (size_t)((0 * 8 + wu) * 4 * 64) * 8;
    const u16* W1 = Wt + (size_t)((1 * 8 + wu) * 4 * 64) * 8;
    const u16* W2 = Wt + (size_t)((2 * 8 + wu) * 4 * 64) * 8;
    const u16* W3 = Wt + (size_t)((3 * 8 + wu) * 4 * 64) * 8;
    const u16* O0 = Woh + (size_t)((0 * 8 + wu) * 64) * 8;
    const u16* O1 = Woh + (size_t)((1 * 8 + wu) * 64) * 8;
    const u16* O2 = Woh + (size_t)((2 * 8 + wu) * 64) * 8;
    const u16* O3 = Woh + (size_t)((3 * 8 + wu) * 64) * 8;
    float cst[8];
    #pragma unroll
    for (int i = 0; i < 8; ++i) cst[i] = 0.f;

    for (int t = 0; t < MAXDEG_; ++t){
      const short* hb = hl[t & 1];          // holds h_t (+ one-hot for step t)
      short*       hw = hl[(t + 1) & 1];    // receives h_{t+1}
      f32x4 acc[8];
      #pragma unroll
      for (int i = 0; i < 8; ++i) acc[i] = (f32x4){0.f, 0.f, 0.f, 0.f};

      #pragma unroll 2
      for (int kc = 0; kc < 4; ++kc){
        bf16x8 af0 = *(const bf16x8*)&hb[(col) * HPAD + kc * 32 + (row ^ swzr) * 8];
        bf16x8 af1 = *(const bf16x8*)&hb[(16 + col) * HPAD + kc * 32 + (row ^ swzr) * 8];
        int lo = (kc * 64 + lane) * 8;
        bf16x8 b0 = *(const bf16x8*)(W0 + lo);
        bf16x8 b1 = *(const bf16x8*)(W1 + lo);
        bf16x8 b2 = *(const bf16x8*)(W2 + lo);
        bf16x8 b3 = *(const bf16x8*)(W3 + lo);
        acc[0] = __builtin_amdgcn_mfma_f32_16x16x32_bf16(af0, b0, acc[0], 0, 0, 0);
        acc[1] = __builtin_amdgcn_mfma_f32_16x16x32_bf16(af1, b0, acc[1], 0, 0, 0);
        acc[2] = __builtin_amdgcn_mfma_f32_16x16x32_bf16(af0, b1, acc[2], 0, 0, 0);
        acc[3] = __builtin_amdgcn_mfma_f32_16x16x32_bf16(af1, b1, acc[3], 0, 0, 0);
        acc[4] = __builtin_amdgcn_mfma_f32_16x16x32_bf16(af0, b2, acc[4], 0, 0, 0);
        acc[5] = __builtin_amdgcn_mfma_f32_16x16x32_bf16(af1, b2, acc[5], 0, 0, 0);
        acc[6] = __builtin_amdgcn_mfma_f32_16x16x32_bf16(af0, b3, acc[6], 0, 0, 0);
        acc[7] = __builtin_amdgcn_mfma_f32_16x16x32_bf16(af1, b3, acc[7], 0, 0, 0);
      }
      {
        bf16x8 af0 = *(const bf16x8*)&hb[(col) * HPAD + H_ + row * 8];
        bf16x8 af1 = *(const bf16x8*)&hb[(16 + col) * HPAD + H_ + row * 8];
        int lo = lane * 8;
        bf16x8 b0 = *(const bf16x8*)(O0 + lo);
        bf16x8 b1 = *(const bf16x8*)(O1 + lo);
        bf16x8 b2 = *(const bf16x8*)(O2 + lo);
        bf16x8 b3 = *(const bf16x8*)(O3 + lo);
        acc[0] = __builtin_amdgcn_mfma_f32_16x16x32_bf16(af0, b0, acc[0], 0, 0, 0);
        acc[1] = __builtin_amdgcn_mfma_f32_16x16x32_bf16(af1, b0, acc[1], 0, 0, 0);
        acc[2] = __builtin_amdgcn_mfma_f32_16x16x32_bf16(af0, b1, acc[2], 0, 0, 0);
        acc[3] = __builtin_amdgcn_mfma_f32_16x16x32_bf16(af1, b1, acc[3], 0, 0, 0);
        acc[4] = __builtin_amdgcn_mfma_f32_16x16x32_bf16(af0, b2, acc[4], 0, 0, 0);
        acc[5] = __builtin_amdgcn_mfma_f32_16x16x32_bf16(af1, b2, acc[5], 0, 0, 0);
        acc[6] = __builtin_amdgcn_mfma_f32_16x16x32_bf16(af0, b3, acc[6], 0, 0, 0);
        acc[7] = __builtin_amdgcn_mfma_f32_16x16x32_bf16(af1, b3, acc[7], 0, 0, 0);
      }

      #pragma unroll
      for (int mt = 0; mt < 2; ++mt){
        #pragma unroll
        for (int reg = 0; reg < 4; ++reg){
          int e = mt * 16 + row * 4 + reg;
          int jsw = (((wu * 2 + (col >> 3)) ^ row) * 8) + (col & 7);
          float Gi = acc[0 + mt][reg];
          float Gf = acc[2 + mt][reg];
          float Gg = acc[4 + mt][reg];
          float Go = acc[6 + mt][reg];
          int ci = mt * 4 + reg;
          float ea = fexp2(-Gi);
          float ef = fexp2(-Gf);
          float eb2 = fexp2(-Gg);
          float eo = fexp2(-Go);
          float t1 = 1.f + ef, t2 = 1.f + ea, t3 = 1.f + eb2;
          float p = t2 * t3;
          float num = __builtin_fmaf(cst[ci], p, (1.f - eb2) * t1);
          float cn = num * frcp(t1 * p);
          float ed = fexp2(cn * (-LOG2E2_));
          float hn = (1.f - ed) * frcp((1.f + eo) * (1.f + ed));
          cst[ci] = cn;
          hw[e * HPAD + jsw] = f2bf(hn);
        }
      }
      if (tid < 32){
        const int* dr = degs + (size_t)eg0 * MAXDEG_;
        if (t >= 1)
          hw[tid * HPAD + H_ + dr[dir ? (MAXDEG_ - t) : (t - 1)]] = 0;
        if (t < MAXDEG_ - 1)
          hw[tid * HPAD + H_ + dr[dir ? (MAXDEG_ - 2 - t) : (t + 1)]] = BF16_ONE;
      }
      __syncthreads();
    }

    if (dir == 0){
      for (int i = tid; i < 32 * 16; i += 512){
        int e = i >> 4, c = i & 15;
        int sz = (e >> 2) & 3;
        *(bf16x8*)&hfin[e * 136 + c * 8] =
            *(const bf16x8*)&hl[0][e * HPAD + ((c ^ sz) * 8)];
      }
      __syncthreads();
      for (int i = tid; i < 2 * 32 * HPAD; i += 512) ((short*)hl)[i] = 0;
      __syncthreads();
      if (tid < 32) hl[0][tid * HPAD + H_ + degs[(size_t)eg0 * MAXDEG_ + (MAXDEG_ - 1)]] = BF16_ONE;
      __syncthreads();
    }
  }

  // fused entity-attention epilogue
  if (wu < 4){
    int mt = wu >> 1, ot = wu & 1;
    int e2 = mt * 16 + col;
    f32x4 accL = (f32x4){0.f, 0.f, 0.f, 0.f};
    #pragma unroll
    for (int ks = 0; ks < 8; ++ks){
      bf16x8 ra;
      if (ks < 4) ra = *(const bf16x8*)&hfin[e2 * 136 + ks * 32 + row * 8];
      else        ra = *(const bf16x8*)&hl[0][e2 * HPAD + (ks - 4) * 32 + (row ^ swzr) * 8];
      f16x8 af;
      #pragma unroll
      for (int jj = 0; jj < 8; ++jj) af[jj] = (_Float16)bf2f((u16)ra[jj]);
      f16x8 bfr = *(const f16x8*)(etile + (((size_t)(ot * 8 + ks)) * 64 + lane) * 8);
      accL = __builtin_amdgcn_mfma_f32_16x16x32_f16(af, bfr, accL, 0, 0, 0);
    }
    #pragma unroll
    for (int reg = 0; reg < 4; ++reg){
      int ent = mt * 16 + (lane >> 4) * 4 + reg;
      int op  = ot * 16 + (lane & 15);
      float bb = (op < OPS_) ? elinb[op] : 0.f;
      lgs[ent][op] = accL[reg] + bb;
    }
  }
  __syncthreads();
  if (tid < 32){
    int n = ebase + tid;
    if (n < N_){
      float m = -1e30f;
      #pragma unroll
      for (int o = 0; o < OPS_; ++o) m = fmaxf(m, lgs[tid][o]);
      float s = 0.f;
      #pragma unroll
      for (int o = 0; o < OPS_; ++o) s += __expf(lgs[tid][o] - m);
      float inv = frcp(s);
      #pragma unroll
      for (int o = 0; o < OPS_; ++o)
        attn[(size_t)n * OPS_ + o] = __expf(lgs[tid][o] - m) * inv;
    }
  }
}

// ---- compact CSR fill (r10-exact) ----
__global__ void csr_fill_kernel(const int* __restrict__ rels, const int* __restrict__ theads,
                                const int* __restrict__ ttails, const float* __restrict__ attn,
                                const u8* __restrict__ mask, const u8* __restrict__ hs1,
                                int* __restrict__ cursor, int* __restrict__ cursor2,
                                uint2* __restrict__ ents, uint2* __restrict__ ents2)
{
  int e = blockIdx.x * 256 + threadIdx.x;
  if (e < E_){
    int hh = theads[e], tt = ttails[e];
    int mh = mask[hh], mt = mask[tt];
    if (!(mh | mt)) return;
    int rel = rels[e];
    unsigned wb = __float_as_uint(attn[(size_t)hh * OPS_ + rel]);
    if (mh){                         // fwd: src hh -> row tt
      uint2 v1; v1.x = (unsigned)hh | ((unsigned)rel << 16); v1.y = wb;
      ents[atomicAdd(&cursor[tt], 1)] = v1;
    }
    if (mt){                         // rev: src tt -> row hh
      uint2 v2; v2.x = (unsigned)tt | ((unsigned)(rel + OPS_/2) << 16); v2.y = wb;
      ents[atomicAdd(&cursor[hh], 1)] = v2;
    }
    if (hs1[hh]){                    // out-edge of hh
      uint2 w1; w1.x = (unsigned)tt | ((unsigned)rel << 16); w1.y = wb;
      ents2[atomicAdd(&cursor2[hh], 1)] = w1;
    }
    if (hs1[tt]){                    // out-edge of tt (reverse op)
      uint2 w2; w2.x = (unsigned)hh | ((unsigned)(rel + OPS_/2) << 16); w2.y = wb;
      ents2[atomicAdd(&cursor2[tt], 1)] = w2;
    }
  }
}

// ---- fused sparse t=0 + t=1 (r10-exact) ----
__global__ void t01_kernel(const int* __restrict__ heads, const float* __restrict__ query_attn,
                           const int* __restrict__ rowptr, const int* __restrict__ cend2,
                           const uint2* __restrict__ ents2, float* __restrict__ u2)
{
  __shared__ float qa0[OPS_ + 1], qa1[OPS_ + 1];
  int blk = blockIdx.x;   // 0..95
  int r = blk >> 5, b = blk & 31;
  int rb = r * 32 + b;
  int tid = threadIdx.x;  // 64
  if (tid < OPS_ + 1){
    qa0[tid] = query_attn[((size_t)(r * T_ + 0) * B_ + b) * (OPS_ + 1) + tid];
    qa1[tid] = query_attn[((size_t)(r * T_ + 1) * B_ + b) * (OPS_ + 1) + tid];
  }
  __syncthreads();
  int hd = heads[b];
  int beg = rowptr[hd], end = cend2[hd];
  float q024 = qa0[OPS_], q124 = qa1[OPS_];
  if (tid == 0) atomicAdd(&u2[(size_t)hd * RB_ + rb], q124 * q024);
  for (int i = beg + tid; i < end; i += 64){
    uint2 e1 = ents2[i];
    int s  = (int)(e1.x & 0xFFFFu);
    int r1 = (int)(e1.x >> 16);
    float w1 = __uint_as_float(e1.y);
    atomicAdd(&u2[(size_t)s * RB_ + rb], w1 * (q124 * qa0[r1] + qa1[r1] * q024));
    float v1 = qa0[r1] * w1;      // this path's share of u1[s]
    int b2 = rowptr[s], e2e = cend2[s];
    for (int jj = b2; jj < e2e; ++jj){
      uint2 e2 = ents2[jj];
      int d2 = (int)(e2.x & 0xFFFFu);
      int r2 = (int)(e2.x >> 16);
      atomicAdd(&u2[(size_t)d2 * RB_ + rb], qa1[r2] * __uint_as_float(e2.y) * v1);
    }
  }
}

// ---- dense gather (t=2), compact in-CSR + dead-row skipping ----
__global__ __launch_bounds__(256) void gather3_kernel(
    const float* __restrict__ ucur, float* __restrict__ unxt,
    const float* __restrict__ query_attn, int t,
    const int* __restrict__ rowptr, const int* __restrict__ cend,
    const uint2* __restrict__ ents, const u8* __restrict__ mask,
    float* __restrict__ partial /* PSLOTS x 96 */)
{
  __shared__ float qas[3 * B_ * (OPS_ + 1)];  // [r][b][o]
  __shared__ float red[RB_];
  int tid = threadIdx.x;
  int b  = tid & 31;
  int h  = (tid >> 5) & 1;              // half within wave
  int n = blockIdx.x * 4 + (tid >> 6);  // one wave per node; grid*4 == N_
  int beg = rowptr[n], end = cend[n];
  int mk = mask[n];
  int cnt = end - beg;
  if (__syncthreads_and(cnt == 0 && !mk)) return;   // all 4 nodes trivial

  for (int i = tid; i < 3 * B_ * (OPS_ + 1); i += 256){
    int r = i / (B_ * (OPS_ + 1));
    int rem = i - r * (B_ * (OPS_ + 1));
    qas[i] = query_attn[(size_t)(r * T_ + t) * B_ * (OPS_ + 1) + rem];
  }
  if (tid < RB_) red[tid] = 0.f;
  __syncthreads();
  const float* q0 = &qas[0 * 800 + b * (OPS_ + 1)];
  const float* q1 = &qas[1 * 800 + b * (OPS_ + 1)];
  const float* q2 = &qas[2 * 800 + b * (OPS_ + 1)];
  size_t nb = (size_t)n * RB_;
  float a0 = 0.f, a1 = 0.f, a2 = 0.f;
  if (h == 0 && mk){
    a0 = ucur[nb + b]      * q0[OPS_];
    a1 = ucur[nb + 32 + b] * q1[OPS_];
    a2 = ucur[nb + 64 + b] * q2[OPS_];
  }
  int nq = cnt >> 2;                 // full 4-edge chunks
  for (int c = h; c < nq; c += 2){
    int i0 = beg + 4 * c;
    uint2 e0 = ents[i0 + 0];
    uint2 e1 = ents[i0 + 1];
    uint2 e2 = ents[i0 + 2];
    uint2 e3 = ents[i0 + 3];
    size_t s0 = (size_t)(e0.x & 0xFFFFu) * RB_;
    size_t s1 = (size_t)(e1.x & 0xFFFFu) * RB_;
    size_t s2 = (size_t)(e2.x & 0xFFFFu) * RB_;
    size_t s3 = (size_t)(e3.x & 0xFFFFu) * RB_;
    float u00 = ucur[s0 + b], u01 = ucur[s0 + 32 + b], u02 = ucur[s0 + 64 + b];
    float u10 = ucur[s1 + b], u11 = ucur[s1 + 32 + b], u12 = ucur[s1 + 64 + b];
    float u20 = ucur[s2 + b], u21 = ucur[s2 + 32 + b], u22 = ucur[s2 + 64 + b];
    float u30 = ucur[s3 + b], u31 = ucur[s3 + 32 + b], u32 = ucur[s3 + 64 + b];
    int r0 = (int)(e0.x >> 16), r1 = (int)(e1.x >> 16);
    int r2 = (int)(e2.x >> 16), r3 = (int)(e3.x >> 16);
    float w0 = __uint_as_float(e0.y), w1 = __uint_as_float(e1.y);
    float w2 = __uint_as_float(e2.y), w3 = __uint_as_float(e3.y);
    a0 += q0[r0]*w0*u00 + q0[r1]*w1*u10 + q0[r2]*w2*u20 + q0[r3]*w3*u30;
    a1 += q1[r0]*w0*u01 + q1[r1]*w1*u11 + q1[r2]*w2*u21 + q1[r3]*w3*u31;
    a2 += q2[r0]*w0*u02 + q2[r1]*w1*u12 + q2[r2]*w2*u22 + q2[r3]*w3*u32;
  }
  if (h == 1){
    for (int i = beg + 4 * nq; i < end; ++i){
      uint2 e0 = ents[i];
      size_t s0 = (size_t)(e0.x & 0xFFFFu) * RB_;
      int r0 = (int)(e0.x >> 16);
      float w0 = __uint_as_float(e0.y);
      a0 += q0[r0] * w0 * ucur[s0 + b];
      a1 += q1[r0] * w0 * ucur[s0 + 32 + b];
      a2 += q2[r0] * w0 * ucur[s0 + 64 + b];
    }
  }
  a0 += __shfl_xor(a0, 32);
  a1 += __shfl_xor(a1, 32);
  a2 += __shfl_xor(a2, 32);
  if (h == 0 && (mk || cnt > 0)){
    unxt[nb + b]      = a0;
    unxt[nb + 32 + b] = a1;
    unxt[nb + 64 + b] = a2;
    atomicAdd(&red[b], a0);
    atomicAdd(&red[32 + b], a1);
    atomicAdd(&red[64 + b], a2);
  }
  __syncthreads();
  if (tid < RB_)
    atomicAdd(&partial[(blockIdx.x & (PSLOTS - 1)) * RB_ + tid], red[tid]);
}

// ---- finalize + transpose: dead rows zero-filled without loading u ----
__global__ void fintrans_kernel(const float* __restrict__ u, const float* __restrict__ partial,
                                const int* __restrict__ rowptr, const int* __restrict__ cend,
                                const u8* __restrict__ mask,
                                float* __restrict__ out)
{
  __shared__ float sinv[RB_];
  __shared__ float t[B_][72];
  int tid = threadIdx.x;   // 256
  if (tid < RB_){
    float s = 0.f;
    #pragma unroll 8
    for (int k = 0; k < PSLOTS; ++k) s += partial[k * RB_ + tid];
    sinv[tid] = frcp(fmaxf(1e-20f, s));
  }
  __syncthreads();
  int n0 = blockIdx.x * 64;
  for (int i = tid; i < 64 * B_; i += 256){
    int nl = i >> 5, b = i & 31;
    int n = n0 + nl;
    float v = 0.f;
    if (n < N_ && (mask[n] || cend[n] > rowptr[n])){
      size_t nb = (size_t)n * RB_;
      v = u[nb + b] * sinv[b] + u[nb + 32 + b] * sinv[32 + b] + u[nb + 64 + b] * sinv[64 + b];
    }
    t[b][nl] = v;
  }
  __syncthreads();
  for (int i = tid; i < 64 * B_; i += 256){
    int b = i >> 6, nl = i & 63;
    int n = n0 + nl;
    if (n < N_) out[(size_t)b * N_ + n] = t[b][nl];
  }
}

extern "C" void kernel_launch(void* const* d_in, const int* in_sizes, int n_in,
                              void* d_out, int out_size, void* d_ws, size_t ws_size,
                              hipStream_t stream)
{
  const int*   queries = (const int*)d_in[0];
  const int*   heads   = (const int*)d_in[1];
  const int*   rels    = (const int*)d_in[2];
  const int*   t_heads = (const int*)d_in[3];
  const int*   t_tails = (const int*)d_in[4];
  const int*   edeg    = (const int*)d_in[5];
  const float* qemb    = (const float*)d_in[6];
  const float* eemb    = (const float*)d_in[7];
  const float* qWih    = (const float*)d_in[8];
  const float* qWhh    = (const float*)d_in[9];
  const float* qbih    = (const float*)d_in[10];
  const float* qbhh    = (const float*)d_in[11];
  const float* eWih    = (const float*)d_in[12];
  const float* eWhh    = (const float*)d_in[13];
  const float* ebih    = (const float*)d_in[14];
  const float* ebhh    = (const float*)d_in[15];
  const float* qlinW   = (const float*)d_in[16];
  const float* qlinb   = (const float*)d_in[17];
  const float* elinW   = (const float*)d_in[18];
  const float* elinb   = (const float*)d_in[19];
  float* out = (float*)d_out;

  char* ws = (char*)d_ws;
  size_t off = 0;
  auto alloc = [&](size_t bytes){ void* p = ws + off; off += (bytes + 255) & ~(size_t)255; return p; };
  // bigB (19.2 MB): attn (4.8 MB) during [elstm, csr_fill]; then u3 (gather3 out).
  char*  bigB  = (char*)alloc((size_t)N_ * RB_ * 4);
  float* attn  = (float*)bigB;
  float* u3    = (float*)bigB;
  uint2* ents       = (uint2*)alloc((size_t)2 * E_ * 8);              // in-CSR (compact-filled)
  float* u2         = (float*)alloc((size_t)N_ * RB_ * 4);            // 19.2 MB
  uint2* ents2      = (uint2*)alloc((size_t)2 * E_ * 8);              // out-CSR (compact-filled)
  float* query_attn = (float*)alloc((size_t)R_ * T_ * B_ * (OPS_ + 1) * 4);
  u16*   wtile      = (u16*)  alloc((size_t)2 * 32 * 4 * 64 * 8 * 2);
  u16*   wonehot    = (u16*)  alloc((size_t)2 * 32 * 64 * 8 * 2);
  u16*   etile      = (u16*)  alloc((size_t)2 * 8 * 64 * 8 * 2);      // 16 KB
  int*   counts     = (int*)  alloc((size_t)(N_ + 1) * 4);
  int*   rowptr     = (int*)  alloc((size_t)(N_ + 1) * 4);
  int*   cursor     = (int*)  alloc((size_t)(N_ + 1) * 4);
  int*   cursor2    = (int*)  alloc((size_t)(N_ + 1) * 4);
  u8*    hs1        = (u8*)   alloc((size_t)N_);
  u8*    mask       = (u8*)   alloc((size_t)N_);
  float* sumsP      = (float*)alloc((size_t)PSLOTS * RB_ * 4);
  // total ~52 MB

  // counts + hs1 must be zero BEFORE front (csr_count atomics / bfs1 marks ride it);
  // u2 / mask / sumsP are zeroed inside front (consumed only later).
  hipMemsetAsync(counts, 0, (size_t)(N_ + 1) * 4, stream);
  hipMemsetAsync(hs1, 0, (size_t)N_, stream);

  front_kernel<<<WB_ + CB_ + BF_ + ZU_ + ZM_ + ZS_ + EB_, 512, 0, stream>>>(
      eWhh, eemb, eWih, ebih, ebhh, wtile, wonehot,
      t_heads, t_tails, counts, heads, hs1, u2, (int*)mask, sumsP, elinW, etile);
  // MEGA: [qattn 96][elstm 1563][scan + bfs2 riders 881 — backfill the drain]
  elstm_kernel<<<QB_ + SCANBLK_ + TAILR_, 512, 0, stream>>>(
      edeg, wtile, wonehot, etile, elinb, attn,
      counts, rowptr, cursor, cursor2,
      t_heads, t_tails, hs1, mask,
      queries, qemb, qWih, qWhh, qbih, qbhh, qlinW, qlinb, query_attn);
  // compact CSR fill (cursor/cursor2 become compact row ends)
  csr_fill_kernel<<<(E_ + 255) / 256, 256, 0, stream>>>(rels, t_heads, t_tails, attn,
                                                        mask, hs1, cursor, cursor2,
                                                        ents, ents2);
  // fused t=0 + t=1 sparse propagation into u2
  t01_kernel<<<RB_, 64, 0, stream>>>(heads, query_attn, rowptr, cursor2, ents2, u2);
  // t=2: dense gather over compact in-CSR (attn dead; u3 overwrites bigB)
  gather3_kernel<<<N_ / 4, 256, 0, stream>>>(u2, u3, query_attn, 2, rowptr, cursor,
                                             ents, mask, sumsP);
  fintrans_kernel<<<(N_ + 63) / 64, 256, 0, stream>>>(u3, sumsP, rowptr, cursor,
                                                      mask, out);
}